// Round 6
// baseline (967.706 us; speedup 1.0000x reference)
//
#include <hip/hip_runtime.h>
#include <math.h>

typedef unsigned int u32;
typedef unsigned long long u64;

#define BATCH 2
#define CH 128
#define NPTS 8192
#define KNB 16
#define GRP 8
#define EPSN 1e-5f

// ---- workspace layout (bytes), total ~10.8 MB ----
#define WS_A     0           // 8*128 f32   A' = s_g * (we_w1 @ pe_w2)
#define WS_PW1   4096        // 128 float4  folded pe_w1 + pe_bn (sx,sy,sz,bias)
#define WS_WE2   6144        // 64 f32      we_w2
#define WS_PTS   8192        // 16384 float4 {x,y,z,|p|^2}
#define WS_EQ    270336      // B*N*8 f32   t_g - s_g*eq
#define WS_EK    794624      // B*N*8 f32   s_g*ek
#define WS_IDX   1318912     // B*N*16 int
#define WS_VFT   2367488     // B*N*128 f32 v transposed (point-major)

__device__ __forceinline__ float d2f(float4 a, float4 b){
  #pragma clang fp contract(off)
  float dot = a.x*b.x + a.y*b.y + a.z*b.z;
  return (a.w + b.w) - 2.0f*dot;
}
__device__ __forceinline__ u64 shfl_xor_u64(u64 v, int m){
  int lo = __shfl_xor((int)(u32)v, m);
  int hi = __shfl_xor((int)(u32)(v >> 32), m);
  return (((u64)(u32)hi) << 32) | (u32)lo;
}

// ---------------- K0: tiny precompute ----------------
__global__ __launch_bounds__(256) void k0_precomp(
    const float* we_w1, const float* pe_w2, const float* pe_w1,
    const float* we_g, const float* we_v,
    const float* pe_g, const float* pe_b, const float* pe_m, const float* pe_v,
    const float* we_w2, float* wsA, float4* wsPW1, float* wsWE2){
  int t = threadIdx.x;
  for (int i = t; i < 1024; i += 256){
    int g = i >> 7, h = i & 127;
    float s = 0.f;
    for (int c = 0; c < 128; ++c) s = fmaf(we_w1[g*128+c], pe_w2[c*128+h], s);
    float sg = we_g[g] / sqrtf(we_v[g] + EPSN);
    wsA[i] = s * sg;
  }
  if (t < 128){
    float s = pe_g[t] / sqrtf(pe_v[t] + EPSN);
    float bb = pe_b[t] - pe_m[t] * s;
    wsPW1[t] = make_float4(s*pe_w1[t*3+0], s*pe_w1[t*3+1], s*pe_w1[t*3+2], bb);
  }
  if (t < 64) wsWE2[t] = we_w2[t];
}

// ---------------- K1: points + squared norms ----------------
__global__ __launch_bounds__(256) void k1_pts(const float* xyz, float4* pts){
  int id = blockIdx.x*256 + threadIdx.x;
  if (id >= BATCH*NPTS) return;
  int b = id >> 13, n = id & (NPTS-1);
  float x = xyz[(b*3+0)*NPTS + n];
  float y = xyz[(b*3+1)*NPTS + n];
  float z = xyz[(b*3+2)*NPTS + n];
  float sq;
  {
    #pragma clang fp contract(off)
    sq = (x*x + y*y) + z*z;
  }
  pts[id] = make_float4(x, y, z, sq);
}

// ---------------- K2: projections -> eqT, ekT, vfT ----------------
__global__ __launch_bounds__(256) void k2_proj(
    const float* x, const float* wq, const float* wk, const float* wv,
    const float* bnq_g, const float* bnq_b, const float* bnq_m, const float* bnq_v,
    const float* bnk_g, const float* bnk_b, const float* bnk_m, const float* bnk_v,
    const float* we_w1,
    const float* we_g, const float* we_b, const float* we_m, const float* we_v,
    float* eqT, float* ekT, float* vfT){
  __shared__ __align__(16) float qk[128][65];  // [channel][point]
  __shared__ float bnS[128], bnB[128];
  int t = threadIdx.x;
  int b = blockIdx.x >> 7;
  int n0 = (blockIdx.x & 127) * 64;
  int p = t & 63, og = t >> 6;
  const float* xp = x + (size_t)b*CH*NPTS + n0 + p;
  for (int mat = 0; mat < 3; ++mat){
    const float* W = (mat == 0) ? wq : ((mat == 1) ? wk : wv);
    if (mat < 2 && t < 128){
      const float* g_ = mat==0 ? bnq_g : bnk_g;
      const float* b_ = mat==0 ? bnq_b : bnk_b;
      const float* m_ = mat==0 ? bnq_m : bnk_m;
      const float* v_ = mat==0 ? bnq_v : bnk_v;
      float s = g_[t] / sqrtf(v_[t] + EPSN);
      bnS[t] = s;
      bnB[t] = b_[t] - m_[t] * s;
    }
    __syncthreads();   // also protects qk reuse across mats
    float acc[32];
    #pragma unroll
    for (int ii = 0; ii < 32; ++ii) acc[ii] = 0.f;
    for (int dd = 0; dd < 32; ++dd){
      float x0 = xp[(size_t)(4*dd+0)*NPTS];
      float x1 = xp[(size_t)(4*dd+1)*NPTS];
      float x2 = xp[(size_t)(4*dd+2)*NPTS];
      float x3 = xp[(size_t)(4*dd+3)*NPTS];
      #pragma unroll
      for (int ii = 0; ii < 32; ++ii){
        int o = og*32 + ii;
        float4 wu = *(const float4*)&W[o*128 + 4*dd];
        acc[ii] = fmaf(wu.x, x0, acc[ii]);
        acc[ii] = fmaf(wu.y, x1, acc[ii]);
        acc[ii] = fmaf(wu.z, x2, acc[ii]);
        acc[ii] = fmaf(wu.w, x3, acc[ii]);
      }
    }
    #pragma unroll
    for (int ii = 0; ii < 32; ++ii){
      int o = og*32 + ii;
      float v = acc[ii];
      if (mat < 2) v = fmaxf(fmaf(bnS[o], v, bnB[o]), 0.f);
      qk[o][p] = v;
    }
    __syncthreads();
    if (mat < 2){
      int g = t >> 5, pb = t & 31;
      float sg = we_g[g] / sqrtf(we_v[g] + EPSN);
      float tg = we_b[g] - we_m[g] * sg;
      #pragma unroll
      for (int half = 0; half < 2; ++half){
        int pp = pb + 32*half;
        float s = 0.f;
        for (int c = 0; c < 128; ++c) s = fmaf(we_w1[g*128+c], qk[c][pp], s);
        float val = (mat == 0) ? (tg - sg*s) : (sg*s);
        float* dst = (mat == 0) ? eqT : ekT;
        dst[(b*NPTS + n0 + pp)*8 + g] = val;
      }
    } else {
      for (int i = 0; i < 32; ++i){
        int f = t + 256*i;
        int c = f & 127, pp = f >> 7;
        vfT[((size_t)b*NPTS + n0 + pp)*CH + c] = qk[c][pp];
      }
    }
    __syncthreads();
  }
}

// ---------------- K3: exact KNN, 8 queries/wave, wave-independent ----------------
// Wave-private buffers (cleared first -> no garbage reads), no __syncthreads,
// every __ballot under uniform 64-lane control flow, idempotent re-sweeps,
// bisection threshold search (guaranteed convergence, no oscillation).
#define QB3  32    // queries per block (4 waves x 8)
#define CAP3 128   // candidate slots per query
__global__ __launch_bounds__(256) void k3_knn(const float4* pts, int* idxout){
  __shared__ u64 smBuf[4][8][CAP3];   // 32 KB, rows private to each wave
  int t = threadIdx.x;
  int wv = t >> 6, lane = t & 63;
  int b  = blockIdx.x / (NPTS/QB3);
  int q0 = (blockIdx.x % (NPTS/QB3)) * QB3 + wv*8;   // this wave's first query
  const float4* P = pts + b*NPTS;

  // clear this wave's buffer rows (8*128 u64 = 16 slots/lane), no barrier needed
  #pragma unroll
  for (int s = 0; s < 16; ++s){
    int f = s*64 + lane;               // 0..1023
    smBuf[wv][f >> 7][f & 127] = ~0ull;
  }

  float4 qp[8];
  #pragma unroll
  for (int i = 0; i < 8; ++i) qp[i] = P[q0 + i];

  // ---- pass 1: min positive d2 per query ----
  float mn[8];
  #pragma unroll
  for (int i = 0; i < 8; ++i) mn[i] = 3.402823466e38f;
  for (int base = 0; base < NPTS; base += 64){
    float4 c = P[base + lane];
    #pragma unroll
    for (int i = 0; i < 8; ++i){
      float d2 = d2f(qp[i], c);
      if (d2 > 0.f) mn[i] = fminf(mn[i], d2);
    }
  }
  #pragma unroll
  for (int i = 0; i < 8; ++i){
    #pragma unroll
    for (int msk = 1; msk <= 32; msk <<= 1) mn[i] = fminf(mn[i], __shfl_xor(mn[i], msk));
  }
  float T[8], Tlo[8], Thi[8]; int cnt[8];
  #pragma unroll
  for (int i = 0; i < 8; ++i){
    T[i] = (mn[i] < 3.0e38f) ? mn[i]*10.0f : 1.0f;
    if (!(T[i] > 0.f)) T[i] = 1e-12f;
    Tlo[i] = 0.f; Thi[i] = 3.0e38f;
    cnt[i] = 0;
  }

  // ---- threshold-collect, wave-local bisection retries, idempotent sweeps ----
  bool anybad = true;
  for (int att = 0; att < 24 && anybad; ++att){
    #pragma unroll
    for (int i = 0; i < 8; ++i) cnt[i] = 0;
    for (int base = 0; base < NPTS; base += 64){
      float4 c = P[base + lane];
      int m = base + lane;
      #pragma unroll
      for (int i = 0; i < 8; ++i){
        float d2 = d2f(qp[i], c);
        bool pred = d2 < T[i];
        u64 bm = __ballot(pred);
        int cc = __popcll(bm);
        if (pred && cnt[i] + cc <= CAP3){
          u32 lo = (u32)(bm & 0xFFFFFFFFull), hi = (u32)(bm >> 32);
          int pos = cnt[i] + (int)__builtin_amdgcn_mbcnt_hi(hi, __builtin_amdgcn_mbcnt_lo(lo, 0u));
          u32 db = __float_as_uint(d2);
          u32 key = (db & 0x80000000u) ? ~db : (db | 0x80000000u);  // monotone float->uint
          smBuf[wv][i][pos] = (((u64)key) << 32) | (u32)m;
        }
        cnt[i] += cc;
      }
    }
    anybad = false;
    #pragma unroll
    for (int i = 0; i < 8; ++i){
      if (cnt[i] > CAP3){
        Thi[i] = T[i];
        T[i] = (Tlo[i] > 0.f) ? 0.5f*(Tlo[i] + Thi[i]) : T[i]*0.5f;
        anybad = true;
      } else if (cnt[i] < 16){
        Tlo[i] = T[i];
        T[i] = (Thi[i] < 3.0e38f) ? 0.5f*(Tlo[i] + Thi[i]) : T[i]*4.0f;
        anybad = true;
      }
    }
  }

  // ---- extraction: 16 lexicographically-smallest (d2, idx) per query ----
  for (int i = 0; i < 8; ++i){
    int cq = cnt[i] < CAP3 ? cnt[i] : CAP3;
    int n = q0 + i;
    for (int r = 0; r < 16; ++r){
      u64 lm = ~0ull; int ls = -1;
      for (int s = lane; s < cq; s += 64){
        u64 v = smBuf[wv][i][s];
        if (v < lm){ lm = v; ls = s; }
      }
      u64 gm = lm;
      #pragma unroll
      for (int msk = 1; msk <= 32; msk <<= 1){
        u64 o = shfl_xor_u64(gm, msk);
        gm = (o < gm) ? o : gm;
      }
      if (lm == gm && ls >= 0) smBuf[wv][i][ls] = ~0ull;
      if (lane == 0){
        int sel = (gm == ~0ull) ? n : (int)(gm & (u32)(NPTS-1));
        idxout[(b*NPTS + n)*16 + r] = sel;
      }
    }
  }
}

// ---------------- K4: fused attention + output projection ----------------
#define HSTR 140
#define H2STR 136
__global__ __launch_bounds__(256) void k4_attn(
    const float4* pts, const float* eqT, const float* ekT, const int* idxw,
    const float* vfT, const float* wsA, const float4* wsPW1, const float* wsWE2,
    const float* pe_w2, const float* wo,
    const float* bno_g, const float* bno_b, const float* bno_m, const float* bno_v,
    float* out){
  __shared__ __align__(16) float smHid[4][16*HSTR];
  __shared__ __align__(16) float smH[4][8*H2STR];
  __shared__ float smw[4][16*8];
  __shared__ __align__(16) float4 smW1[128];
  __shared__ __align__(16) float smOutv[8][128];
  int t = threadIdx.x;
  int wv = t >> 6, lane = t & 63;
  int b = blockIdx.x >> 10;
  int n0 = (blockIdx.x & 1023) * 8;
  if (t < 128) smW1[t] = wsPW1[t];
  __syncthreads();
  int k = lane >> 2, q = lane & 3;
  for (int r = 0; r < 2; ++r){
    int pl = r*4 + wv;
    int n = n0 + pl;
    int gq = b*NPTS + n;
    float4 pn = pts[gq];
    float4 eqa = *(const float4*)&eqT[gq*8];
    float4 eqb = *(const float4*)&eqT[gq*8+4];
    int j = idxw[gq*16 + k] & (NPTS-1);   // clamp: faults impossible
    int gj = b*NPTS + j;
    float4 pj = pts[gj];
    float4 eka = *(const float4*)&ekT[gj*8];
    float4 ekb = *(const float4*)&ekT[gj*8+4];
    float rx = pj.x - pn.x, ry = pj.y - pn.y, rz = pj.z - pn.z;
    // ee: the (ek' + eq') affine term — added ONCE, after the q-lane reduction
    float ee[8] = {eka.x+eqa.x, eka.y+eqa.y, eka.z+eqa.z, eka.w+eqa.w,
                   ekb.x+eqb.x, ekb.y+eqb.y, ekb.z+eqb.z, ekb.w+eqb.w};
    float lp[8] = {0.f, 0.f, 0.f, 0.f, 0.f, 0.f, 0.f, 0.f};
    #pragma unroll
    for (int i = 0; i < 8; ++i){
      int hb = 4*q + 16*i;
      float hv0, hv1, hv2, hv3;
      {
        float4 w1;
        w1 = smW1[hb+0]; hv0 = fmaxf(fmaf(w1.x, rx, fmaf(w1.y, ry, fmaf(w1.z, rz, w1.w))), 0.f);
        w1 = smW1[hb+1]; hv1 = fmaxf(fmaf(w1.x, rx, fmaf(w1.y, ry, fmaf(w1.z, rz, w1.w))), 0.f);
        w1 = smW1[hb+2]; hv2 = fmaxf(fmaf(w1.x, rx, fmaf(w1.y, ry, fmaf(w1.z, rz, w1.w))), 0.f);
        w1 = smW1[hb+3]; hv3 = fmaxf(fmaf(w1.x, rx, fmaf(w1.y, ry, fmaf(w1.z, rz, w1.w))), 0.f);
      }
      *(float4*)&smHid[wv][k*HSTR + hb] = make_float4(hv0, hv1, hv2, hv3);
      #pragma unroll
      for (int g = 0; g < 8; ++g){
        float4 a4 = *(const float4*)&wsA[g*128 + hb];
        lp[g] = fmaf(a4.x, hv0, lp[g]);
        lp[g] = fmaf(a4.y, hv1, lp[g]);
        lp[g] = fmaf(a4.z, hv2, lp[g]);
        lp[g] = fmaf(a4.w, hv3, lp[g]);
      }
    }
    #pragma unroll
    for (int g = 0; g < 8; ++g){
      lp[g] += __shfl_xor(lp[g], 1);
      lp[g] += __shfl_xor(lp[g], 2);
      lp[g] = fmaxf(lp[g] + ee[g], 0.f);   // relu(bn(we_w1@rel)); ee added once
    }
    float lo0 = 0.f, lo1 = 0.f;
    #pragma unroll
    for (int g = 0; g < 8; ++g){
      lo0 = fmaf(wsWE2[(2*q+0)*8 + g], lp[g], lo0);
      lo1 = fmaf(wsWE2[(2*q+1)*8 + g], lp[g], lo1);
    }
    float m0 = lo0, m1 = lo1;
    #pragma unroll
    for (int msk = 4; msk <= 32; msk <<= 1){
      m0 = fmaxf(m0, __shfl_xor(m0, msk));
      m1 = fmaxf(m1, __shfl_xor(m1, msk));
    }
    float e0 = __expf(lo0 - m0), e1 = __expf(lo1 - m1);
    float s0 = e0, s1 = e1;
    #pragma unroll
    for (int msk = 4; msk <= 32; msk <<= 1){
      s0 += __shfl_xor(s0, msk);
      s1 += __shfl_xor(s1, msk);
    }
    float w0 = e0 / s0, w1 = e1 / s1;
    *(float2*)&smw[wv][k*8 + 2*q] = make_float2(w0, w1);
    __syncthreads();
    // H[g][h] = sum_k w[g,k] * hid[k][h]
    {
      int g3 = lane >> 3, hh = lane & 7;
      float wk16[16];
      #pragma unroll
      for (int kk = 0; kk < 16; ++kk) wk16[kk] = smw[wv][kk*8 + g3];
      #pragma unroll
      for (int ii = 0; ii < 4; ++ii){
        int hb = 4*hh + 32*ii;
        float ax = 0.f, ay = 0.f, az = 0.f, aw = 0.f;
        #pragma unroll
        for (int kk = 0; kk < 16; ++kk){
          float4 h4 = *(const float4*)&smHid[wv][kk*HSTR + hb];
          ax = fmaf(wk16[kk], h4.x, ax);
          ay = fmaf(wk16[kk], h4.y, ay);
          az = fmaf(wk16[kk], h4.z, az);
          aw = fmaf(wk16[kk], h4.w, aw);
        }
        *(float4*)&smH[wv][g3*H2STR + hb] = make_float4(ax, ay, az, aw);
      }
    }
    __syncthreads();
    // outv[c] = pe_w2[c,:]@H[g(c)] + sum_k w[g,k]*v[j_k][c]
    {
      int jj16[16];
      #pragma unroll
      for (int kk = 0; kk < 16; ++kk) jj16[kk] = idxw[gq*16 + kk] & (NPTS-1);
      #pragma unroll
      for (int half = 0; half < 2; ++half){
        int c = lane + 64*half;
        int g = c >> 4;
        float acc = 0.f;
        for (int i = 0; i < 32; ++i){
          float4 pw = *(const float4*)&pe_w2[c*128 + 4*i];
          float4 h4 = *(const float4*)&smH[wv][g*H2STR + 4*i];
          acc = fmaf(pw.x, h4.x, acc);
          acc = fmaf(pw.y, h4.y, acc);
          acc = fmaf(pw.z, h4.z, acc);
          acc = fmaf(pw.w, h4.w, acc);
        }
        #pragma unroll
        for (int kk = 0; kk < 16; ++kk){
          float wgk = smw[wv][kk*8 + g];
          acc = fmaf(wgk, vfT[((size_t)b*NPTS + jj16[kk])*CH + c], acc);
        }
        smOutv[pl][c] = acc;
      }
    }
    __syncthreads();
  }
  // phase B: final projection wo + bno, f32 store
  {
    int o = t & 127, ph = t >> 7;
    float so = bno_g[o] / sqrtf(bno_v[o] + EPSN);
    float bo = bno_b[o] - bno_m[o] * so;
    float fa[4] = {0.f, 0.f, 0.f, 0.f};
    for (int i = 0; i < 32; ++i){
      float4 pw = *(const float4*)&wo[o*128 + 4*i];
      #pragma unroll
      for (int p4 = 0; p4 < 4; ++p4){
        float4 h4 = *(const float4*)&smOutv[ph*4 + p4][4*i];
        fa[p4] = fmaf(pw.x, h4.x, fa[p4]);
        fa[p4] = fmaf(pw.y, h4.y, fa[p4]);
        fa[p4] = fmaf(pw.z, h4.z, fa[p4]);
        fa[p4] = fmaf(pw.w, h4.w, fa[p4]);
      }
    }
    float4 st;
    st.x = fmaf(so, fa[0], bo);
    st.y = fmaf(so, fa[1], bo);
    st.z = fmaf(so, fa[2], bo);
    st.w = fmaf(so, fa[3], bo);
    *(float4*)&out[((size_t)b*CH + o)*NPTS + n0 + ph*4] = st;
  }
}

extern "C" void kernel_launch(void* const* d_in, const int* in_sizes, int n_in,
                              void* d_out, int out_size, void* d_ws, size_t ws_size,
                              hipStream_t stream){
  const float* x     = (const float*)d_in[0];
  const float* xyz   = (const float*)d_in[1];
  const float* wq    = (const float*)d_in[2];
  const float* bnq_g = (const float*)d_in[3];
  const float* bnq_b = (const float*)d_in[4];
  const float* bnq_m = (const float*)d_in[5];
  const float* bnq_v = (const float*)d_in[6];
  const float* wk    = (const float*)d_in[7];
  const float* bnk_g = (const float*)d_in[8];
  const float* bnk_b = (const float*)d_in[9];
  const float* bnk_m = (const float*)d_in[10];
  const float* bnk_v = (const float*)d_in[11];
  const float* wv    = (const float*)d_in[12];
  const float* pe_w1 = (const float*)d_in[13];
  const float* pe_g  = (const float*)d_in[14];
  const float* pe_b  = (const float*)d_in[15];
  const float* pe_m  = (const float*)d_in[16];
  const float* pe_v  = (const float*)d_in[17];
  const float* pe_w2 = (const float*)d_in[18];
  const float* we_w1 = (const float*)d_in[19];
  const float* we_g  = (const float*)d_in[20];
  const float* we_b  = (const float*)d_in[21];
  const float* we_m  = (const float*)d_in[22];
  const float* we_v  = (const float*)d_in[23];
  const float* we_w2 = (const float*)d_in[24];
  const float* wo    = (const float*)d_in[25];
  const float* bno_g = (const float*)d_in[26];
  const float* bno_b = (const float*)d_in[27];
  const float* bno_m = (const float*)d_in[28];
  const float* bno_v = (const float*)d_in[29];

  char* ws = (char*)d_ws;
  float*  wsA   = (float*)(ws + WS_A);
  float4* wsPW1 = (float4*)(ws + WS_PW1);
  float*  wsWE2 = (float*)(ws + WS_WE2);
  float4* pts   = (float4*)(ws + WS_PTS);
  float*  eqT   = (float*)(ws + WS_EQ);
  float*  ekT   = (float*)(ws + WS_EK);
  int*    idxw  = (int*)(ws + WS_IDX);
  float*  vfT   = (float*)(ws + WS_VFT);
  float*  outp  = (float*)d_out;

  k0_precomp<<<dim3(1), dim3(256), 0, stream>>>(we_w1, pe_w2, pe_w1, we_g, we_v,
                                                pe_g, pe_b, pe_m, pe_v, we_w2,
                                                wsA, wsPW1, wsWE2);
  k1_pts<<<dim3(64), dim3(256), 0, stream>>>(xyz, pts);
  k2_proj<<<dim3(256), dim3(256), 0, stream>>>(x, wq, wk, wv,
                                               bnq_g, bnq_b, bnq_m, bnq_v,
                                               bnk_g, bnk_b, bnk_m, bnk_v,
                                               we_w1, we_g, we_b, we_m, we_v,
                                               eqT, ekT, vfT);
  k3_knn<<<dim3(BATCH*(NPTS/QB3)), dim3(256), 0, stream>>>(pts, idxw);
  k4_attn<<<dim3(2048), dim3(256), 0, stream>>>(pts, eqT, ekT, idxw, vfT,
                                                wsA, wsPW1, wsWE2, pe_w2, wo,
                                                bno_g, bno_b, bno_m, bno_v, outp);
}

// Round 7
// 723.577 us; speedup vs baseline: 1.3374x; 1.3374x over previous
//
#include <hip/hip_runtime.h>
#include <math.h>

typedef unsigned int u32;
typedef unsigned long long u64;

#define BATCH 2
#define CH 128
#define NPTS 8192
#define KNB 16
#define GRP 8
#define EPSN 1e-5f

// ---- workspace layout (bytes), total ~10.8 MB ----
#define WS_A     0           // 8*128 f32   A' = s_g * (we_w1 @ pe_w2)
#define WS_PW1   4096        // 128 float4  folded pe_w1 + pe_bn (sx,sy,sz,bias)
#define WS_WE2   6144        // 64 f32      we_w2
#define WS_PTS   8192        // 16384 float4 {x,y,z,|p|^2}
#define WS_EQ    270336      // B*N*8 f32   t_g - s_g*eq
#define WS_EK    794624      // B*N*8 f32   s_g*ek
#define WS_IDX   1318912     // B*N*16 int
#define WS_VFT   2367488     // B*N*128 f32 v transposed (point-major)

__device__ __forceinline__ float d2f(float4 a, float4 b){
  #pragma clang fp contract(off)
  float dot = a.x*b.x + a.y*b.y + a.z*b.z;
  return (a.w + b.w) - 2.0f*dot;
}
__device__ __forceinline__ u64 shfl_xor_u64(u64 v, int m){
  int lo = __shfl_xor((int)(u32)v, m);
  int hi = __shfl_xor((int)(u32)(v >> 32), m);
  return (((u64)(u32)hi) << 32) | (u32)lo;
}
__device__ __forceinline__ int mbcnt64(u64 bm){
  return (int)__builtin_amdgcn_mbcnt_hi((u32)(bm >> 32),
          __builtin_amdgcn_mbcnt_lo((u32)(bm & 0xFFFFFFFFull), 0u));
}
__device__ __forceinline__ u32 mono32(float d2){
  u32 db = __float_as_uint(d2);
  return (db & 0x80000000u) ? ~db : (db | 0x80000000u);  // monotone float->uint
}

// ---------------- K0: tiny precompute ----------------
__global__ __launch_bounds__(256) void k0_precomp(
    const float* we_w1, const float* pe_w2, const float* pe_w1,
    const float* we_g, const float* we_v,
    const float* pe_g, const float* pe_b, const float* pe_m, const float* pe_v,
    const float* we_w2, float* wsA, float4* wsPW1, float* wsWE2){
  int t = threadIdx.x;
  for (int i = t; i < 1024; i += 256){
    int g = i >> 7, h = i & 127;
    float s = 0.f;
    for (int c = 0; c < 128; ++c) s = fmaf(we_w1[g*128+c], pe_w2[c*128+h], s);
    float sg = we_g[g] / sqrtf(we_v[g] + EPSN);
    wsA[i] = s * sg;
  }
  if (t < 128){
    float s = pe_g[t] / sqrtf(pe_v[t] + EPSN);
    float bb = pe_b[t] - pe_m[t] * s;
    wsPW1[t] = make_float4(s*pe_w1[t*3+0], s*pe_w1[t*3+1], s*pe_w1[t*3+2], bb);
  }
  if (t < 64) wsWE2[t] = we_w2[t];
}

// ---------------- K1: points + squared norms ----------------
__global__ __launch_bounds__(256) void k1_pts(const float* xyz, float4* pts){
  int id = blockIdx.x*256 + threadIdx.x;
  if (id >= BATCH*NPTS) return;
  int b = id >> 13, n = id & (NPTS-1);
  float x = xyz[(b*3+0)*NPTS + n];
  float y = xyz[(b*3+1)*NPTS + n];
  float z = xyz[(b*3+2)*NPTS + n];
  float sq;
  {
    #pragma clang fp contract(off)
    sq = (x*x + y*y) + z*z;
  }
  pts[id] = make_float4(x, y, z, sq);
}

// ---------------- K2: projections -> eqT, ekT, vfT ----------------
__global__ __launch_bounds__(256) void k2_proj(
    const float* x, const float* wq, const float* wk, const float* wv,
    const float* bnq_g, const float* bnq_b, const float* bnq_m, const float* bnq_v,
    const float* bnk_g, const float* bnk_b, const float* bnk_m, const float* bnk_v,
    const float* we_w1,
    const float* we_g, const float* we_b, const float* we_m, const float* we_v,
    float* eqT, float* ekT, float* vfT){
  __shared__ __align__(16) float qk[128][65];  // [channel][point]
  __shared__ float bnS[128], bnB[128];
  int t = threadIdx.x;
  int b = blockIdx.x >> 7;
  int n0 = (blockIdx.x & 127) * 64;
  int p = t & 63, og = t >> 6;
  const float* xp = x + (size_t)b*CH*NPTS + n0 + p;
  for (int mat = 0; mat < 3; ++mat){
    const float* W = (mat == 0) ? wq : ((mat == 1) ? wk : wv);
    if (mat < 2 && t < 128){
      const float* g_ = mat==0 ? bnq_g : bnk_g;
      const float* b_ = mat==0 ? bnq_b : bnk_b;
      const float* m_ = mat==0 ? bnq_m : bnk_m;
      const float* v_ = mat==0 ? bnq_v : bnk_v;
      float s = g_[t] / sqrtf(v_[t] + EPSN);
      bnS[t] = s;
      bnB[t] = b_[t] - m_[t] * s;
    }
    __syncthreads();   // also protects qk reuse across mats
    float acc[32];
    #pragma unroll
    for (int ii = 0; ii < 32; ++ii) acc[ii] = 0.f;
    for (int dd = 0; dd < 32; ++dd){
      float x0 = xp[(size_t)(4*dd+0)*NPTS];
      float x1 = xp[(size_t)(4*dd+1)*NPTS];
      float x2 = xp[(size_t)(4*dd+2)*NPTS];
      float x3 = xp[(size_t)(4*dd+3)*NPTS];
      #pragma unroll
      for (int ii = 0; ii < 32; ++ii){
        int o = og*32 + ii;
        float4 wu = *(const float4*)&W[o*128 + 4*dd];
        acc[ii] = fmaf(wu.x, x0, acc[ii]);
        acc[ii] = fmaf(wu.y, x1, acc[ii]);
        acc[ii] = fmaf(wu.z, x2, acc[ii]);
        acc[ii] = fmaf(wu.w, x3, acc[ii]);
      }
    }
    #pragma unroll
    for (int ii = 0; ii < 32; ++ii){
      int o = og*32 + ii;
      float v = acc[ii];
      if (mat < 2) v = fmaxf(fmaf(bnS[o], v, bnB[o]), 0.f);
      qk[o][p] = v;
    }
    __syncthreads();
    if (mat < 2){
      int g = t >> 5, pb = t & 31;
      float sg = we_g[g] / sqrtf(we_v[g] + EPSN);
      float tg = we_b[g] - we_m[g] * sg;
      #pragma unroll
      for (int half = 0; half < 2; ++half){
        int pp = pb + 32*half;
        float s = 0.f;
        for (int c = 0; c < 128; ++c) s = fmaf(we_w1[g*128+c], qk[c][pp], s);
        float val = (mat == 0) ? (tg - sg*s) : (sg*s);
        float* dst = (mat == 0) ? eqT : ekT;
        dst[(b*NPTS + n0 + pp)*8 + g] = val;
      }
    } else {
      for (int i = 0; i < 32; ++i){
        int f = t + 256*i;
        int c = f & 127, pp = f >> 7;
        vfT[((size_t)b*NPTS + n0 + pp)*CH + c] = qk[c][pp];
      }
    }
    __syncthreads();
  }
}

// ---------------- K3: exact KNN, sampled threshold (>=16 guaranteed) ----------------
// 4 queries/wave (4x candidate-stream amortization), 4096 waves (vs 2048 in r6).
// T(q) = 16th-smallest d2 among first 512 candidates: since those 16 sampled
// values are <= T, the full-set count at T is ALWAYS >= 16 -> no underflow
// retries, no mn pre-pass. E[count]=256, P(count>CAP=384)~4% -> E[sweeps]~1.16.
// Wave-private LDS rows, no __syncthreads, ballots under uniform control flow.
#define QW   4     // queries per wave
#define QPB  16    // queries per block (4 waves x 4)
#define CAPQ 384   // candidate slots per query
__global__ __launch_bounds__(256) void k3_knn(const float4* pts, int* idxout){
  __shared__ u64 smBuf[4][QW][CAPQ];   // 48 KB, rows private per wave
  int t = threadIdx.x;
  int wv = t >> 6, lane = t & 63;
  int b  = blockIdx.x / (NPTS/QPB);
  int q0 = (blockIdx.x % (NPTS/QPB)) * QPB + wv*QW;
  const float4* P = pts + b*NPTS;

  // clear wave-private rows (give-up-path safety); QW*CAPQ/64 = 24 slots/lane
  #pragma unroll
  for (int s = 0; s < QW*CAPQ/64; ++s){
    int f = s*64 + lane;
    smBuf[wv][f / CAPQ][f % CAPQ] = ~0ull;
  }

  float4 qp[QW];
  #pragma unroll
  for (int i = 0; i < QW; ++i) qp[i] = P[q0 + i];

  // ---- sample phase: T[i] = (>= true) 16th-smallest d2 among candidates 0..511 ----
  float T[QW];
  #pragma unroll
  for (int i = 0; i < QW; ++i){
    float s_[8];
    #pragma unroll
    for (int j = 0; j < 8; ++j){
      float4 c = P[lane + 64*j];
      s_[j] = d2f(qp[i], c);
    }
    // bubble sorting network (28 CEs), ascending — trivially correct
    #pragma unroll
    for (int a = 0; a < 8; ++a){
      #pragma unroll
      for (int e = 0; e < 7; ++e){
        if (e < 7 - a){
          float lo = fminf(s_[e], s_[e+1]);
          float hi = fmaxf(s_[e], s_[e+1]);
          s_[e] = lo; s_[e+1] = hi;
        }
      }
    }
    float Tq = s_[0];
    #pragma unroll
    for (int r = 0; r < 16; ++r){
      float m = s_[0];
      #pragma unroll
      for (int msk = 1; msk <= 32; msk <<= 1) m = fminf(m, __shfl_xor(m, msk));
      if (s_[0] == m){   // pop head; tie-popping only biases T upward (safe)
        s_[0]=s_[1]; s_[1]=s_[2]; s_[2]=s_[3]; s_[3]=s_[4];
        s_[4]=s_[5]; s_[5]=s_[6]; s_[6]=s_[7]; s_[7]=3.402823466e38f;
      }
      Tq = m;
    }
    T[i] = Tq;
  }

  // ---- collect sweeps: guaranteed cnt>=16 at initial T; bisect only on overflow ----
  float Tlo[QW], Thi[QW]; int cnt[QW];
  #pragma unroll
  for (int i = 0; i < QW; ++i){ Tlo[i] = -3.0e38f; Thi[i] = 3.0e38f; cnt[i] = 0; }
  bool anybad = true;
  for (int att = 0; att < 16 && anybad; ++att){
    #pragma unroll
    for (int i = 0; i < QW; ++i) cnt[i] = 0;
    for (int base = 0; base < NPTS; base += 64){
      float4 c = P[base + lane];
      u32 m = base + lane;
      #pragma unroll
      for (int i = 0; i < QW; ++i){
        float d2 = d2f(qp[i], c);
        bool pred = d2 <= T[i];
        u64 bm = __ballot(pred);
        int cc = __popcll(bm);
        if (pred && cnt[i] + cc <= CAPQ){
          int pos = cnt[i] + mbcnt64(bm);
          smBuf[wv][i][pos] = (((u64)mono32(d2)) << 32) | m;
        }
        cnt[i] += cc;
      }
    }
    anybad = false;
    #pragma unroll
    for (int i = 0; i < QW; ++i){
      if (cnt[i] > CAPQ){
        Thi[i] = T[i];
        T[i] = (Tlo[i] > -3.0e38f) ? 0.5f*(Tlo[i] + Thi[i])
                                   : ((T[i] > 0.f) ? T[i]*0.5f : T[i]*2.0f - 1.0f);
        anybad = true;
      } else if (cnt[i] < 16){   // only reachable after an overflow-shrink
        Tlo[i] = T[i];
        T[i] = 0.5f*(Tlo[i] + Thi[i]);
        anybad = true;
      }
    }
  }

  // ---- extraction: 16 lexicographically-smallest (d2, idx) per query ----
  for (int i = 0; i < QW; ++i){
    int cq = cnt[i] < CAPQ ? cnt[i] : CAPQ;
    int n = q0 + i;
    for (int r = 0; r < 16; ++r){
      u64 lm = ~0ull; int ls = -1;
      for (int s = lane; s < cq; s += 64){
        u64 v = smBuf[wv][i][s];
        if (v < lm){ lm = v; ls = s; }
      }
      u64 gm = lm;
      #pragma unroll
      for (int msk = 1; msk <= 32; msk <<= 1){
        u64 o = shfl_xor_u64(gm, msk);
        gm = (o < gm) ? o : gm;
      }
      if (lm == gm && ls >= 0) smBuf[wv][i][ls] = ~0ull;
      if (lane == 0){
        int sel = (gm == ~0ull) ? n : (int)(gm & (u32)(NPTS-1));
        idxout[(b*NPTS + n)*16 + r] = sel;
      }
    }
  }
}

// ---------------- K4: fused attention + output projection ----------------
#define HSTR 140
#define H2STR 136
__global__ __launch_bounds__(256) void k4_attn(
    const float4* pts, const float* eqT, const float* ekT, const int* idxw,
    const float* vfT, const float* wsA, const float4* wsPW1, const float* wsWE2,
    const float* pe_w2, const float* wo,
    const float* bno_g, const float* bno_b, const float* bno_m, const float* bno_v,
    float* out){
  __shared__ __align__(16) float smHid[4][16*HSTR];
  __shared__ __align__(16) float smH[4][8*H2STR];
  __shared__ float smw[4][16*8];
  __shared__ __align__(16) float4 smW1[128];
  __shared__ __align__(16) float smOutv[8][128];
  int t = threadIdx.x;
  int wv = t >> 6, lane = t & 63;
  int b = blockIdx.x >> 10;
  int n0 = (blockIdx.x & 1023) * 8;
  if (t < 128) smW1[t] = wsPW1[t];
  __syncthreads();
  int k = lane >> 2, q = lane & 3;
  for (int r = 0; r < 2; ++r){
    int pl = r*4 + wv;
    int n = n0 + pl;
    int gq = b*NPTS + n;
    float4 pn = pts[gq];
    float4 eqa = *(const float4*)&eqT[gq*8];
    float4 eqb = *(const float4*)&eqT[gq*8+4];
    int j = idxw[gq*16 + k] & (NPTS-1);   // clamp: faults impossible
    int gj = b*NPTS + j;
    float4 pj = pts[gj];
    float4 eka = *(const float4*)&ekT[gj*8];
    float4 ekb = *(const float4*)&ekT[gj*8+4];
    float rx = pj.x - pn.x, ry = pj.y - pn.y, rz = pj.z - pn.z;
    // ee: the (ek' + eq') affine term — added ONCE, after the q-lane reduction
    float ee[8] = {eka.x+eqa.x, eka.y+eqa.y, eka.z+eqa.z, eka.w+eqa.w,
                   ekb.x+eqb.x, ekb.y+eqb.y, ekb.z+eqb.z, ekb.w+eqb.w};
    float lp[8] = {0.f, 0.f, 0.f, 0.f, 0.f, 0.f, 0.f, 0.f};
    #pragma unroll
    for (int i = 0; i < 8; ++i){
      int hb = 4*q + 16*i;
      float hv0, hv1, hv2, hv3;
      {
        float4 w1;
        w1 = smW1[hb+0]; hv0 = fmaxf(fmaf(w1.x, rx, fmaf(w1.y, ry, fmaf(w1.z, rz, w1.w))), 0.f);
        w1 = smW1[hb+1]; hv1 = fmaxf(fmaf(w1.x, rx, fmaf(w1.y, ry, fmaf(w1.z, rz, w1.w))), 0.f);
        w1 = smW1[hb+2]; hv2 = fmaxf(fmaf(w1.x, rx, fmaf(w1.y, ry, fmaf(w1.z, rz, w1.w))), 0.f);
        w1 = smW1[hb+3]; hv3 = fmaxf(fmaf(w1.x, rx, fmaf(w1.y, ry, fmaf(w1.z, rz, w1.w))), 0.f);
      }
      *(float4*)&smHid[wv][k*HSTR + hb] = make_float4(hv0, hv1, hv2, hv3);
      #pragma unroll
      for (int g = 0; g < 8; ++g){
        float4 a4 = *(const float4*)&wsA[g*128 + hb];
        lp[g] = fmaf(a4.x, hv0, lp[g]);
        lp[g] = fmaf(a4.y, hv1, lp[g]);
        lp[g] = fmaf(a4.z, hv2, lp[g]);
        lp[g] = fmaf(a4.w, hv3, lp[g]);
      }
    }
    #pragma unroll
    for (int g = 0; g < 8; ++g){
      lp[g] += __shfl_xor(lp[g], 1);
      lp[g] += __shfl_xor(lp[g], 2);
      lp[g] = fmaxf(lp[g] + ee[g], 0.f);   // relu(bn(we_w1@rel)); ee added once
    }
    float lo0 = 0.f, lo1 = 0.f;
    #pragma unroll
    for (int g = 0; g < 8; ++g){
      lo0 = fmaf(wsWE2[(2*q+0)*8 + g], lp[g], lo0);
      lo1 = fmaf(wsWE2[(2*q+1)*8 + g], lp[g], lo1);
    }
    float m0 = lo0, m1 = lo1;
    #pragma unroll
    for (int msk = 4; msk <= 32; msk <<= 1){
      m0 = fmaxf(m0, __shfl_xor(m0, msk));
      m1 = fmaxf(m1, __shfl_xor(m1, msk));
    }
    float e0 = __expf(lo0 - m0), e1 = __expf(lo1 - m1);
    float s0 = e0, s1 = e1;
    #pragma unroll
    for (int msk = 4; msk <= 32; msk <<= 1){
      s0 += __shfl_xor(s0, msk);
      s1 += __shfl_xor(s1, msk);
    }
    float w0 = e0 / s0, w1 = e1 / s1;
    *(float2*)&smw[wv][k*8 + 2*q] = make_float2(w0, w1);
    __syncthreads();
    // H[g][h] = sum_k w[g,k] * hid[k][h]
    {
      int g3 = lane >> 3, hh = lane & 7;
      float wk16[16];
      #pragma unroll
      for (int kk = 0; kk < 16; ++kk) wk16[kk] = smw[wv][kk*8 + g3];
      #pragma unroll
      for (int ii = 0; ii < 4; ++ii){
        int hb = 4*hh + 32*ii;
        float ax = 0.f, ay = 0.f, az = 0.f, aw = 0.f;
        #pragma unroll
        for (int kk = 0; kk < 16; ++kk){
          float4 h4 = *(const float4*)&smHid[wv][kk*HSTR + hb];
          ax = fmaf(wk16[kk], h4.x, ax);
          ay = fmaf(wk16[kk], h4.y, ay);
          az = fmaf(wk16[kk], h4.z, az);
          aw = fmaf(wk16[kk], h4.w, aw);
        }
        *(float4*)&smH[wv][g3*H2STR + hb] = make_float4(ax, ay, az, aw);
      }
    }
    __syncthreads();
    // outv[c] = pe_w2[c,:]@H[g(c)] + sum_k w[g,k]*v[j_k][c]
    {
      int jj16[16];
      #pragma unroll
      for (int kk = 0; kk < 16; ++kk) jj16[kk] = idxw[gq*16 + kk] & (NPTS-1);
      #pragma unroll
      for (int half = 0; half < 2; ++half){
        int c = lane + 64*half;
        int g = c >> 4;
        float acc = 0.f;
        for (int i = 0; i < 32; ++i){
          float4 pw = *(const float4*)&pe_w2[c*128 + 4*i];
          float4 h4 = *(const float4*)&smH[wv][g*H2STR + 4*i];
          acc = fmaf(pw.x, h4.x, acc);
          acc = fmaf(pw.y, h4.y, acc);
          acc = fmaf(pw.z, h4.z, acc);
          acc = fmaf(pw.w, h4.w, acc);
        }
        #pragma unroll
        for (int kk = 0; kk < 16; ++kk){
          float wgk = smw[wv][kk*8 + g];
          acc = fmaf(wgk, vfT[((size_t)b*NPTS + jj16[kk])*CH + c], acc);
        }
        smOutv[pl][c] = acc;
      }
    }
    __syncthreads();
  }
  // phase B: final projection wo + bno, f32 store
  {
    int o = t & 127, ph = t >> 7;
    float so = bno_g[o] / sqrtf(bno_v[o] + EPSN);
    float bo = bno_b[o] - bno_m[o] * so;
    float fa[4] = {0.f, 0.f, 0.f, 0.f};
    for (int i = 0; i < 32; ++i){
      float4 pw = *(const float4*)&wo[o*128 + 4*i];
      #pragma unroll
      for (int p4 = 0; p4 < 4; ++p4){
        float4 h4 = *(const float4*)&smOutv[ph*4 + p4][4*i];
        fa[p4] = fmaf(pw.x, h4.x, fa[p4]);
        fa[p4] = fmaf(pw.y, h4.y, fa[p4]);
        fa[p4] = fmaf(pw.z, h4.z, fa[p4]);
        fa[p4] = fmaf(pw.w, h4.w, fa[p4]);
      }
    }
    float4 st;
    st.x = fmaf(so, fa[0], bo);
    st.y = fmaf(so, fa[1], bo);
    st.z = fmaf(so, fa[2], bo);
    st.w = fmaf(so, fa[3], bo);
    *(float4*)&out[((size_t)b*CH + o)*NPTS + n0 + ph*4] = st;
  }
}

extern "C" void kernel_launch(void* const* d_in, const int* in_sizes, int n_in,
                              void* d_out, int out_size, void* d_ws, size_t ws_size,
                              hipStream_t stream){
  const float* x     = (const float*)d_in[0];
  const float* xyz   = (const float*)d_in[1];
  const float* wq    = (const float*)d_in[2];
  const float* bnq_g = (const float*)d_in[3];
  const float* bnq_b = (const float*)d_in[4];
  const float* bnq_m = (const float*)d_in[5];
  const float* bnq_v = (const float*)d_in[6];
  const float* wk    = (const float*)d_in[7];
  const float* bnk_g = (const float*)d_in[8];
  const float* bnk_b = (const float*)d_in[9];
  const float* bnk_m = (const float*)d_in[10];
  const float* bnk_v = (const float*)d_in[11];
  const float* wv    = (const float*)d_in[12];
  const float* pe_w1 = (const float*)d_in[13];
  const float* pe_g  = (const float*)d_in[14];
  const float* pe_b  = (const float*)d_in[15];
  const float* pe_m  = (const float*)d_in[16];
  const float* pe_v  = (const float*)d_in[17];
  const float* pe_w2 = (const float*)d_in[18];
  const float* we_w1 = (const float*)d_in[19];
  const float* we_g  = (const float*)d_in[20];
  const float* we_b  = (const float*)d_in[21];
  const float* we_m  = (const float*)d_in[22];
  const float* we_v  = (const float*)d_in[23];
  const float* we_w2 = (const float*)d_in[24];
  const float* wo    = (const float*)d_in[25];
  const float* bno_g = (const float*)d_in[26];
  const float* bno_b = (const float*)d_in[27];
  const float* bno_m = (const float*)d_in[28];
  const float* bno_v = (const float*)d_in[29];

  char* ws = (char*)d_ws;
  float*  wsA   = (float*)(ws + WS_A);
  float4* wsPW1 = (float4*)(ws + WS_PW1);
  float*  wsWE2 = (float*)(ws + WS_WE2);
  float4* pts   = (float4*)(ws + WS_PTS);
  float*  eqT   = (float*)(ws + WS_EQ);
  float*  ekT   = (float*)(ws + WS_EK);
  int*    idxw  = (int*)(ws + WS_IDX);
  float*  vfT   = (float*)(ws + WS_VFT);
  float*  outp  = (float*)d_out;

  k0_precomp<<<dim3(1), dim3(256), 0, stream>>>(we_w1, pe_w2, pe_w1, we_g, we_v,
                                                pe_g, pe_b, pe_m, pe_v, we_w2,
                                                wsA, wsPW1, wsWE2);
  k1_pts<<<dim3(64), dim3(256), 0, stream>>>(xyz, pts);
  k2_proj<<<dim3(256), dim3(256), 0, stream>>>(x, wq, wk, wv,
                                               bnq_g, bnq_b, bnq_m, bnq_v,
                                               bnk_g, bnk_b, bnk_m, bnk_v,
                                               we_w1, we_g, we_b, we_m, we_v,
                                               eqT, ekT, vfT);
  k3_knn<<<dim3(BATCH*(NPTS/QPB)), dim3(256), 0, stream>>>(pts, idxw);
  k4_attn<<<dim3(2048), dim3(256), 0, stream>>>(pts, eqT, ekT, idxw, vfT,
                                                wsA, wsPW1, wsWE2, pe_w2, wo,
                                                bno_g, bno_b, bno_m, bno_v, outp);
}

// Round 8
// 672.920 us; speedup vs baseline: 1.4381x; 1.0753x over previous
//
#include <hip/hip_runtime.h>
#include <math.h>

typedef unsigned int u32;
typedef unsigned long long u64;

#define BATCH 2
#define CH 128
#define NPTS 8192
#define KNB 16
#define GRP 8
#define EPSN 1e-5f

// ---- workspace layout (bytes), total ~10.8 MB ----
#define WS_A     0           // 8*128 f32   A' = s_g * (we_w1 @ pe_w2)
#define WS_PW1   4096        // 128 float4  folded pe_w1 + pe_bn (sx,sy,sz,bias)
#define WS_WE2   6144        // 64 f32      we_w2
#define WS_PTS   8192        // 16384 float4 {x,y,z,|p|^2}
#define WS_EQ    270336      // B*N*8 f32   t_g - s_g*eq
#define WS_EK    794624      // B*N*8 f32   s_g*ek
#define WS_IDX   1318912     // B*N*16 int
#define WS_VFT   2367488     // B*N*128 f32 v transposed (point-major)

__device__ __forceinline__ float d2f(float4 a, float4 b){
  #pragma clang fp contract(off)
  float dot = a.x*b.x + a.y*b.y + a.z*b.z;
  return (a.w + b.w) - 2.0f*dot;
}
__device__ __forceinline__ u64 shfl_xor_u64(u64 v, int m){
  int lo = __shfl_xor((int)(u32)v, m);
  int hi = __shfl_xor((int)(u32)(v >> 32), m);
  return (((u64)(u32)hi) << 32) | (u32)lo;
}
__device__ __forceinline__ int mbcnt64(u64 bm){
  return (int)__builtin_amdgcn_mbcnt_hi((u32)(bm >> 32),
          __builtin_amdgcn_mbcnt_lo((u32)(bm & 0xFFFFFFFFull), 0u));
}
__device__ __forceinline__ u32 mono32(float d2){
  u32 db = __float_as_uint(d2);
  return (db & 0x80000000u) ? ~db : (db | 0x80000000u);  // monotone float->uint
}
__device__ __forceinline__ void sort8(float* s_){
  #pragma unroll
  for (int a = 0; a < 8; ++a){
    #pragma unroll
    for (int e = 0; e < 7; ++e){
      if (e < 7 - a){
        float lo = fminf(s_[e], s_[e+1]);
        float hi = fmaxf(s_[e], s_[e+1]);
        s_[e] = lo; s_[e+1] = hi;
      }
    }
  }
}

// ---------------- K0: tiny precompute ----------------
__global__ __launch_bounds__(256) void k0_precomp(
    const float* we_w1, const float* pe_w2, const float* pe_w1,
    const float* we_g, const float* we_v,
    const float* pe_g, const float* pe_b, const float* pe_m, const float* pe_v,
    const float* we_w2, float* wsA, float4* wsPW1, float* wsWE2){
  int t = threadIdx.x;
  for (int i = t; i < 1024; i += 256){
    int g = i >> 7, h = i & 127;
    float s = 0.f;
    for (int c = 0; c < 128; ++c) s = fmaf(we_w1[g*128+c], pe_w2[c*128+h], s);
    float sg = we_g[g] / sqrtf(we_v[g] + EPSN);
    wsA[i] = s * sg;
  }
  if (t < 128){
    float s = pe_g[t] / sqrtf(pe_v[t] + EPSN);
    float bb = pe_b[t] - pe_m[t] * s;
    wsPW1[t] = make_float4(s*pe_w1[t*3+0], s*pe_w1[t*3+1], s*pe_w1[t*3+2], bb);
  }
  if (t < 64) wsWE2[t] = we_w2[t];
}

// ---------------- K1: points + squared norms ----------------
__global__ __launch_bounds__(256) void k1_pts(const float* xyz, float4* pts){
  int id = blockIdx.x*256 + threadIdx.x;
  if (id >= BATCH*NPTS) return;
  int b = id >> 13, n = id & (NPTS-1);
  float x = xyz[(b*3+0)*NPTS + n];
  float y = xyz[(b*3+1)*NPTS + n];
  float z = xyz[(b*3+2)*NPTS + n];
  float sq;
  {
    #pragma clang fp contract(off)
    sq = (x*x + y*y) + z*z;
  }
  pts[id] = make_float4(x, y, z, sq);
}

// ---------------- K2: projections -> eqT, ekT, vfT ----------------
__global__ __launch_bounds__(256) void k2_proj(
    const float* x, const float* wq, const float* wk, const float* wv,
    const float* bnq_g, const float* bnq_b, const float* bnq_m, const float* bnq_v,
    const float* bnk_g, const float* bnk_b, const float* bnk_m, const float* bnk_v,
    const float* we_w1,
    const float* we_g, const float* we_b, const float* we_m, const float* we_v,
    float* eqT, float* ekT, float* vfT){
  __shared__ __align__(16) float qk[128][65];  // [channel][point]
  __shared__ float bnS[128], bnB[128];
  int t = threadIdx.x;
  int b = blockIdx.x >> 7;
  int n0 = (blockIdx.x & 127) * 64;
  int p = t & 63, og = t >> 6;
  const float* xp = x + (size_t)b*CH*NPTS + n0 + p;
  for (int mat = 0; mat < 3; ++mat){
    const float* W = (mat == 0) ? wq : ((mat == 1) ? wk : wv);
    if (mat < 2 && t < 128){
      const float* g_ = mat==0 ? bnq_g : bnk_g;
      const float* b_ = mat==0 ? bnq_b : bnk_b;
      const float* m_ = mat==0 ? bnq_m : bnk_m;
      const float* v_ = mat==0 ? bnq_v : bnk_v;
      float s = g_[t] / sqrtf(v_[t] + EPSN);
      bnS[t] = s;
      bnB[t] = b_[t] - m_[t] * s;
    }
    __syncthreads();   // also protects qk reuse across mats
    float acc[32];
    #pragma unroll
    for (int ii = 0; ii < 32; ++ii) acc[ii] = 0.f;
    for (int dd = 0; dd < 32; ++dd){
      float x0 = xp[(size_t)(4*dd+0)*NPTS];
      float x1 = xp[(size_t)(4*dd+1)*NPTS];
      float x2 = xp[(size_t)(4*dd+2)*NPTS];
      float x3 = xp[(size_t)(4*dd+3)*NPTS];
      #pragma unroll
      for (int ii = 0; ii < 32; ++ii){
        int o = og*32 + ii;
        float4 wu = *(const float4*)&W[o*128 + 4*dd];
        acc[ii] = fmaf(wu.x, x0, acc[ii]);
        acc[ii] = fmaf(wu.y, x1, acc[ii]);
        acc[ii] = fmaf(wu.z, x2, acc[ii]);
        acc[ii] = fmaf(wu.w, x3, acc[ii]);
      }
    }
    #pragma unroll
    for (int ii = 0; ii < 32; ++ii){
      int o = og*32 + ii;
      float v = acc[ii];
      if (mat < 2) v = fmaxf(fmaf(bnS[o], v, bnB[o]), 0.f);
      qk[o][p] = v;
    }
    __syncthreads();
    if (mat < 2){
      int g = t >> 5, pb = t & 31;
      float sg = we_g[g] / sqrtf(we_v[g] + EPSN);
      float tg = we_b[g] - we_m[g] * sg;
      #pragma unroll
      for (int half = 0; half < 2; ++half){
        int pp = pb + 32*half;
        float s = 0.f;
        for (int c = 0; c < 128; ++c) s = fmaf(we_w1[g*128+c], qk[c][pp], s);
        float val = (mat == 0) ? (tg - sg*s) : (sg*s);
        float* dst = (mat == 0) ? eqT : ekT;
        dst[(b*NPTS + n0 + pp)*8 + g] = val;
      }
    } else {
      for (int i = 0; i < 32; ++i){
        int f = t + 256*i;
        int c = f & 127, pp = f >> 7;
        vfT[((size_t)b*NPTS + n0 + pp)*CH + c] = qk[c][pp];
      }
    }
    __syncthreads();
  }
}

// ---------------- K3: exact KNN, 1024-sample threshold, low-LDS, unrolled ----------------
// T(q) = (upward-biased) 16th-smallest d2 among first 1024 candidates ->
// full-set count >= 16 GUARANTEED (sampled values are full-set members;
// every bias here is upward which only risks overflow, handled by bisection).
// E[count]=128, CAP=192 -> P(overflow)~2%. LDS 24KB/block -> ~6 blocks/CU.
// Collect loop unrolled x2 for memory-level parallelism.
#define QW   4     // queries per wave
#define QPB  16    // queries per block (4 waves x 4)
#define CAPQ 192   // candidate slots per query
__global__ __launch_bounds__(256) void k3_knn(const float4* pts, int* idxout){
  __shared__ u64 smBuf[4][QW][CAPQ];   // 24 KB, rows private per wave
  int t = threadIdx.x;
  int wv = t >> 6, lane = t & 63;
  int b  = blockIdx.x / (NPTS/QPB);
  int q0 = (blockIdx.x % (NPTS/QPB)) * QPB + wv*QW;
  const float4* P = pts + b*NPTS;

  // clear wave-private rows (give-up-path safety); QW*CAPQ/64 = 12 slots/lane
  #pragma unroll
  for (int s = 0; s < QW*CAPQ/64; ++s){
    int f = s*64 + lane;
    smBuf[wv][f / CAPQ][f % CAPQ] = ~0ull;
  }

  float4 qp[QW];
  #pragma unroll
  for (int i = 0; i < QW; ++i) qp[i] = P[q0 + i];

  // ---- sample phase: T[i] >= 16th-smallest d2 among candidates 0..1023 ----
  float T[QW];
  #pragma unroll
  for (int i = 0; i < QW; ++i){
    float sA[8], sB[8];
    #pragma unroll
    for (int j = 0; j < 8; ++j) sA[j] = d2f(qp[i], P[lane + 64*j]);
    sort8(sA);
    #pragma unroll
    for (int j = 0; j < 8; ++j) sB[j] = d2f(qp[i], P[512 + lane + 64*j]);
    sort8(sB);
    // lower-half bitonic merge: lane's smallest 8 of its 16 samples
    float u_[8];
    #pragma unroll
    for (int e = 0; e < 8; ++e) u_[e] = fminf(sA[e], sB[7-e]);
    sort8(u_);
    // pop 16 wave-global minima; tie-pops only bias T upward (safe)
    float Tq = u_[0];
    #pragma unroll
    for (int r = 0; r < 16; ++r){
      float m = u_[0];
      #pragma unroll
      for (int msk = 1; msk <= 32; msk <<= 1) m = fminf(m, __shfl_xor(m, msk));
      if (u_[0] == m){
        u_[0]=u_[1]; u_[1]=u_[2]; u_[2]=u_[3]; u_[3]=u_[4];
        u_[4]=u_[5]; u_[5]=u_[6]; u_[6]=u_[7]; u_[7]=3.402823466e38f;
      }
      Tq = m;
    }
    T[i] = Tq;
  }

  // ---- collect sweeps: cnt>=16 guaranteed at initial T; bisect on overflow ----
  float Tlo[QW], Thi[QW]; int cnt[QW];
  #pragma unroll
  for (int i = 0; i < QW; ++i){ Tlo[i] = -3.0e38f; Thi[i] = 3.0e38f; cnt[i] = 0; }
  bool anybad = true;
  for (int att = 0; att < 16 && anybad; ++att){
    #pragma unroll
    for (int i = 0; i < QW; ++i) cnt[i] = 0;
    for (int base = 0; base < NPTS; base += 128){
      float4 c0 = P[base + lane];
      float4 c1 = P[base + 64 + lane];
      #pragma unroll
      for (int i = 0; i < QW; ++i){
        float d0 = d2f(qp[i], c0);
        bool p0 = d0 <= T[i];
        u64 b0 = __ballot(p0);
        int cc0 = __popcll(b0);
        if (p0 && cnt[i] + cc0 <= CAPQ){
          int pos = cnt[i] + mbcnt64(b0);
          smBuf[wv][i][pos] = (((u64)mono32(d0)) << 32) | (u32)(base + lane);
        }
        cnt[i] += cc0;
        float d1 = d2f(qp[i], c1);
        bool p1 = d1 <= T[i];
        u64 b1 = __ballot(p1);
        int cc1 = __popcll(b1);
        if (p1 && cnt[i] + cc1 <= CAPQ){
          int pos = cnt[i] + mbcnt64(b1);
          smBuf[wv][i][pos] = (((u64)mono32(d1)) << 32) | (u32)(base + 64 + lane);
        }
        cnt[i] += cc1;
      }
    }
    anybad = false;
    #pragma unroll
    for (int i = 0; i < QW; ++i){
      if (cnt[i] > CAPQ){
        Thi[i] = T[i];
        T[i] = (Tlo[i] > -3.0e38f) ? 0.5f*(Tlo[i] + Thi[i])
                                   : ((T[i] > 0.f) ? T[i]*0.5f : T[i]*2.0f - 1.0f);
        anybad = true;
      } else if (cnt[i] < 16){   // only reachable after an overflow-shrink
        Tlo[i] = T[i];
        T[i] = 0.5f*(Tlo[i] + Thi[i]);
        anybad = true;
      }
    }
  }

  // ---- extraction: 16 lexicographically-smallest (d2, idx) per query ----
  for (int i = 0; i < QW; ++i){
    int cq = cnt[i] < CAPQ ? cnt[i] : CAPQ;
    int n = q0 + i;
    for (int r = 0; r < 16; ++r){
      u64 lm = ~0ull; int ls = -1;
      for (int s = lane; s < cq; s += 64){
        u64 v = smBuf[wv][i][s];
        if (v < lm){ lm = v; ls = s; }
      }
      u64 gm = lm;
      #pragma unroll
      for (int msk = 1; msk <= 32; msk <<= 1){
        u64 o = shfl_xor_u64(gm, msk);
        gm = (o < gm) ? o : gm;
      }
      if (lm == gm && ls >= 0) smBuf[wv][i][ls] = ~0ull;
      if (lane == 0){
        int sel = (gm == ~0ull) ? n : (int)(gm & (u32)(NPTS-1));
        idxout[(b*NPTS + n)*16 + r] = sel;
      }
    }
  }
}

// ---------------- K4: fused attention + output projection ----------------
#define HSTR 140
#define H2STR 136
__global__ __launch_bounds__(256) void k4_attn(
    const float4* pts, const float* eqT, const float* ekT, const int* idxw,
    const float* vfT, const float* wsA, const float4* wsPW1, const float* wsWE2,
    const float* pe_w2, const float* wo,
    const float* bno_g, const float* bno_b, const float* bno_m, const float* bno_v,
    float* out){
  __shared__ __align__(16) float smHid[4][16*HSTR];
  __shared__ __align__(16) float smH[4][8*H2STR];
  __shared__ float smw[4][16*8];
  __shared__ __align__(16) float4 smW1[128];
  __shared__ __align__(16) float smOutv[8][128];
  int t = threadIdx.x;
  int wv = t >> 6, lane = t & 63;
  int b = blockIdx.x >> 10;
  int n0 = (blockIdx.x & 1023) * 8;
  if (t < 128) smW1[t] = wsPW1[t];
  __syncthreads();
  int k = lane >> 2, q = lane & 3;
  for (int r = 0; r < 2; ++r){
    int pl = r*4 + wv;
    int n = n0 + pl;
    int gq = b*NPTS + n;
    float4 pn = pts[gq];
    float4 eqa = *(const float4*)&eqT[gq*8];
    float4 eqb = *(const float4*)&eqT[gq*8+4];
    int j = idxw[gq*16 + k] & (NPTS-1);   // clamp: faults impossible
    int gj = b*NPTS + j;
    float4 pj = pts[gj];
    float4 eka = *(const float4*)&ekT[gj*8];
    float4 ekb = *(const float4*)&ekT[gj*8+4];
    float rx = pj.x - pn.x, ry = pj.y - pn.y, rz = pj.z - pn.z;
    // ee: the (ek' + eq') affine term — added ONCE, after the q-lane reduction
    float ee[8] = {eka.x+eqa.x, eka.y+eqa.y, eka.z+eqa.z, eka.w+eqa.w,
                   ekb.x+eqb.x, ekb.y+eqb.y, ekb.z+eqb.z, ekb.w+eqb.w};
    float lp[8] = {0.f, 0.f, 0.f, 0.f, 0.f, 0.f, 0.f, 0.f};
    #pragma unroll
    for (int i = 0; i < 8; ++i){
      int hb = 4*q + 16*i;
      float hv0, hv1, hv2, hv3;
      {
        float4 w1;
        w1 = smW1[hb+0]; hv0 = fmaxf(fmaf(w1.x, rx, fmaf(w1.y, ry, fmaf(w1.z, rz, w1.w))), 0.f);
        w1 = smW1[hb+1]; hv1 = fmaxf(fmaf(w1.x, rx, fmaf(w1.y, ry, fmaf(w1.z, rz, w1.w))), 0.f);
        w1 = smW1[hb+2]; hv2 = fmaxf(fmaf(w1.x, rx, fmaf(w1.y, ry, fmaf(w1.z, rz, w1.w))), 0.f);
        w1 = smW1[hb+3]; hv3 = fmaxf(fmaf(w1.x, rx, fmaf(w1.y, ry, fmaf(w1.z, rz, w1.w))), 0.f);
      }
      *(float4*)&smHid[wv][k*HSTR + hb] = make_float4(hv0, hv1, hv2, hv3);
      #pragma unroll
      for (int g = 0; g < 8; ++g){
        float4 a4 = *(const float4*)&wsA[g*128 + hb];
        lp[g] = fmaf(a4.x, hv0, lp[g]);
        lp[g] = fmaf(a4.y, hv1, lp[g]);
        lp[g] = fmaf(a4.z, hv2, lp[g]);
        lp[g] = fmaf(a4.w, hv3, lp[g]);
      }
    }
    #pragma unroll
    for (int g = 0; g < 8; ++g){
      lp[g] += __shfl_xor(lp[g], 1);
      lp[g] += __shfl_xor(lp[g], 2);
      lp[g] = fmaxf(lp[g] + ee[g], 0.f);   // relu(bn(we_w1@rel)); ee added once
    }
    float lo0 = 0.f, lo1 = 0.f;
    #pragma unroll
    for (int g = 0; g < 8; ++g){
      lo0 = fmaf(wsWE2[(2*q+0)*8 + g], lp[g], lo0);
      lo1 = fmaf(wsWE2[(2*q+1)*8 + g], lp[g], lo1);
    }
    float m0 = lo0, m1 = lo1;
    #pragma unroll
    for (int msk = 4; msk <= 32; msk <<= 1){
      m0 = fmaxf(m0, __shfl_xor(m0, msk));
      m1 = fmaxf(m1, __shfl_xor(m1, msk));
    }
    float e0 = __expf(lo0 - m0), e1 = __expf(lo1 - m1);
    float s0 = e0, s1 = e1;
    #pragma unroll
    for (int msk = 4; msk <= 32; msk <<= 1){
      s0 += __shfl_xor(s0, msk);
      s1 += __shfl_xor(s1, msk);
    }
    float w0 = e0 / s0, w1 = e1 / s1;
    *(float2*)&smw[wv][k*8 + 2*q] = make_float2(w0, w1);
    __syncthreads();
    // H[g][h] = sum_k w[g,k] * hid[k][h]
    {
      int g3 = lane >> 3, hh = lane & 7;
      float wk16[16];
      #pragma unroll
      for (int kk = 0; kk < 16; ++kk) wk16[kk] = smw[wv][kk*8 + g3];
      #pragma unroll
      for (int ii = 0; ii < 4; ++ii){
        int hb = 4*hh + 32*ii;
        float ax = 0.f, ay = 0.f, az = 0.f, aw = 0.f;
        #pragma unroll
        for (int kk = 0; kk < 16; ++kk){
          float4 h4 = *(const float4*)&smHid[wv][kk*HSTR + hb];
          ax = fmaf(wk16[kk], h4.x, ax);
          ay = fmaf(wk16[kk], h4.y, ay);
          az = fmaf(wk16[kk], h4.z, az);
          aw = fmaf(wk16[kk], h4.w, aw);
        }
        *(float4*)&smH[wv][g3*H2STR + hb] = make_float4(ax, ay, az, aw);
      }
    }
    __syncthreads();
    // outv[c] = pe_w2[c,:]@H[g(c)] + sum_k w[g,k]*v[j_k][c]
    {
      int jj16[16];
      #pragma unroll
      for (int kk = 0; kk < 16; ++kk) jj16[kk] = idxw[gq*16 + kk] & (NPTS-1);
      #pragma unroll
      for (int half = 0; half < 2; ++half){
        int c = lane + 64*half;
        int g = c >> 4;
        float acc = 0.f;
        for (int i = 0; i < 32; ++i){
          float4 pw = *(const float4*)&pe_w2[c*128 + 4*i];
          float4 h4 = *(const float4*)&smH[wv][g*H2STR + 4*i];
          acc = fmaf(pw.x, h4.x, acc);
          acc = fmaf(pw.y, h4.y, acc);
          acc = fmaf(pw.z, h4.z, acc);
          acc = fmaf(pw.w, h4.w, acc);
        }
        #pragma unroll
        for (int kk = 0; kk < 16; ++kk){
          float wgk = smw[wv][kk*8 + g];
          acc = fmaf(wgk, vfT[((size_t)b*NPTS + jj16[kk])*CH + c], acc);
        }
        smOutv[pl][c] = acc;
      }
    }
    __syncthreads();
  }
  // phase B: final projection wo + bno, f32 store
  {
    int o = t & 127, ph = t >> 7;
    float so = bno_g[o] / sqrtf(bno_v[o] + EPSN);
    float bo = bno_b[o] - bno_m[o] * so;
    float fa[4] = {0.f, 0.f, 0.f, 0.f};
    for (int i = 0; i < 32; ++i){
      float4 pw = *(const float4*)&wo[o*128 + 4*i];
      #pragma unroll
      for (int p4 = 0; p4 < 4; ++p4){
        float4 h4 = *(const float4*)&smOutv[ph*4 + p4][4*i];
        fa[p4] = fmaf(pw.x, h4.x, fa[p4]);
        fa[p4] = fmaf(pw.y, h4.y, fa[p4]);
        fa[p4] = fmaf(pw.z, h4.z, fa[p4]);
        fa[p4] = fmaf(pw.w, h4.w, fa[p4]);
      }
    }
    float4 st;
    st.x = fmaf(so, fa[0], bo);
    st.y = fmaf(so, fa[1], bo);
    st.z = fmaf(so, fa[2], bo);
    st.w = fmaf(so, fa[3], bo);
    *(float4*)&out[((size_t)b*CH + o)*NPTS + n0 + ph*4] = st;
  }
}

extern "C" void kernel_launch(void* const* d_in, const int* in_sizes, int n_in,
                              void* d_out, int out_size, void* d_ws, size_t ws_size,
                              hipStream_t stream){
  const float* x     = (const float*)d_in[0];
  const float* xyz   = (const float*)d_in[1];
  const float* wq    = (const float*)d_in[2];
  const float* bnq_g = (const float*)d_in[3];
  const float* bnq_b = (const float*)d_in[4];
  const float* bnq_m = (const float*)d_in[5];
  const float* bnq_v = (const float*)d_in[6];
  const float* wk    = (const float*)d_in[7];
  const float* bnk_g = (const float*)d_in[8];
  const float* bnk_b = (const float*)d_in[9];
  const float* bnk_m = (const float*)d_in[10];
  const float* bnk_v = (const float*)d_in[11];
  const float* wv    = (const float*)d_in[12];
  const float* pe_w1 = (const float*)d_in[13];
  const float* pe_g  = (const float*)d_in[14];
  const float* pe_b  = (const float*)d_in[15];
  const float* pe_m  = (const float*)d_in[16];
  const float* pe_v  = (const float*)d_in[17];
  const float* pe_w2 = (const float*)d_in[18];
  const float* we_w1 = (const float*)d_in[19];
  const float* we_g  = (const float*)d_in[20];
  const float* we_b  = (const float*)d_in[21];
  const float* we_m  = (const float*)d_in[22];
  const float* we_v  = (const float*)d_in[23];
  const float* we_w2 = (const float*)d_in[24];
  const float* wo    = (const float*)d_in[25];
  const float* bno_g = (const float*)d_in[26];
  const float* bno_b = (const float*)d_in[27];
  const float* bno_m = (const float*)d_in[28];
  const float* bno_v = (const float*)d_in[29];

  char* ws = (char*)d_ws;
  float*  wsA   = (float*)(ws + WS_A);
  float4* wsPW1 = (float4*)(ws + WS_PW1);
  float*  wsWE2 = (float*)(ws + WS_WE2);
  float4* pts   = (float4*)(ws + WS_PTS);
  float*  eqT   = (float*)(ws + WS_EQ);
  float*  ekT   = (float*)(ws + WS_EK);
  int*    idxw  = (int*)(ws + WS_IDX);
  float*  vfT   = (float*)(ws + WS_VFT);
  float*  outp  = (float*)d_out;

  k0_precomp<<<dim3(1), dim3(256), 0, stream>>>(we_w1, pe_w2, pe_w1, we_g, we_v,
                                                pe_g, pe_b, pe_m, pe_v, we_w2,
                                                wsA, wsPW1, wsWE2);
  k1_pts<<<dim3(64), dim3(256), 0, stream>>>(xyz, pts);
  k2_proj<<<dim3(256), dim3(256), 0, stream>>>(x, wq, wk, wv,
                                               bnq_g, bnq_b, bnq_m, bnq_v,
                                               bnk_g, bnk_b, bnk_m, bnk_v,
                                               we_w1, we_g, we_b, we_m, we_v,
                                               eqT, ekT, vfT);
  k3_knn<<<dim3(BATCH*(NPTS/QPB)), dim3(256), 0, stream>>>(pts, idxw);
  k4_attn<<<dim3(2048), dim3(256), 0, stream>>>(pts, eqT, ekT, idxw, vfT,
                                                wsA, wsPW1, wsWE2, pe_w2, wo,
                                                bno_g, bno_b, bno_m, bno_v, outp);
}

// Round 9
// 508.250 us; speedup vs baseline: 1.9040x; 1.3240x over previous
//
#include <hip/hip_runtime.h>
#include <math.h>

typedef unsigned int u32;
typedef unsigned long long u64;

#define BATCH 2
#define CH 128
#define NPTS 8192
#define KNB 16
#define GRP 8
#define EPSN 1e-5f

// ---- workspace layout (bytes), total ~10.8 MB ----
#define WS_A     0           // 8*128 f32   A' = s_g * (we_w1 @ pe_w2)
#define WS_PW1   4096        // 128 float4  folded pe_w1 + pe_bn (sx,sy,sz,bias)
#define WS_WE2   6144        // 64 f32      we_w2
#define WS_PTS   8192        // 16384 float4 {x,y,z,|p|^2}
#define WS_EQ    270336      // B*N*8 f32   t_g - s_g*eq
#define WS_EK    794624      // B*N*8 f32   s_g*ek
#define WS_IDX   1318912     // B*N*16 int
#define WS_VFT   2367488     // B*N*128 f32 v transposed (point-major)

__device__ __forceinline__ float d2f(float4 a, float4 b){
  #pragma clang fp contract(off)
  float dot = a.x*b.x + a.y*b.y + a.z*b.z;
  return (a.w + b.w) - 2.0f*dot;
}
__device__ __forceinline__ u64 shfl_xor_u64(u64 v, int m){
  int lo = __shfl_xor((int)(u32)v, m);
  int hi = __shfl_xor((int)(u32)(v >> 32), m);
  return (((u64)(u32)hi) << 32) | (u32)lo;
}
__device__ __forceinline__ int mbcnt64(u64 bm){
  return (int)__builtin_amdgcn_mbcnt_hi((u32)(bm >> 32),
          __builtin_amdgcn_mbcnt_lo((u32)(bm & 0xFFFFFFFFull), 0u));
}
__device__ __forceinline__ u32 mono32(float d2){
  u32 db = __float_as_uint(d2);
  return (db & 0x80000000u) ? ~db : (db | 0x80000000u);  // monotone float->uint
}
__device__ __forceinline__ void sort8(float* s_){
  #pragma unroll
  for (int a = 0; a < 8; ++a){
    #pragma unroll
    for (int e = 0; e < 7; ++e){
      if (e < 7 - a){
        float lo = fminf(s_[e], s_[e+1]);
        float hi = fmaxf(s_[e], s_[e+1]);
        s_[e] = lo; s_[e+1] = hi;
      }
    }
  }
}

// ---------------- K0: tiny precompute ----------------
__global__ __launch_bounds__(256) void k0_precomp(
    const float* we_w1, const float* pe_w2, const float* pe_w1,
    const float* we_g, const float* we_v,
    const float* pe_g, const float* pe_b, const float* pe_m, const float* pe_v,
    const float* we_w2, float* wsA, float4* wsPW1, float* wsWE2){
  int t = threadIdx.x;
  for (int i = t; i < 1024; i += 256){
    int g = i >> 7, h = i & 127;
    float s = 0.f;
    for (int c = 0; c < 128; ++c) s = fmaf(we_w1[g*128+c], pe_w2[c*128+h], s);
    float sg = we_g[g] / sqrtf(we_v[g] + EPSN);
    wsA[i] = s * sg;
  }
  if (t < 128){
    float s = pe_g[t] / sqrtf(pe_v[t] + EPSN);
    float bb = pe_b[t] - pe_m[t] * s;
    wsPW1[t] = make_float4(s*pe_w1[t*3+0], s*pe_w1[t*3+1], s*pe_w1[t*3+2], bb);
  }
  if (t < 64) wsWE2[t] = we_w2[t];
}

// ---------------- K1: points + squared norms ----------------
__global__ __launch_bounds__(256) void k1_pts(const float* xyz, float4* pts){
  int id = blockIdx.x*256 + threadIdx.x;
  if (id >= BATCH*NPTS) return;
  int b = id >> 13, n = id & (NPTS-1);
  float x = xyz[(b*3+0)*NPTS + n];
  float y = xyz[(b*3+1)*NPTS + n];
  float z = xyz[(b*3+2)*NPTS + n];
  float sq;
  {
    #pragma clang fp contract(off)
    sq = (x*x + y*y) + z*z;
  }
  pts[id] = make_float4(x, y, z, sq);
}

// ---------------- K2: projections -> eqT, ekT, vfT ----------------
__global__ __launch_bounds__(256) void k2_proj(
    const float* x, const float* wq, const float* wk, const float* wv,
    const float* bnq_g, const float* bnq_b, const float* bnq_m, const float* bnq_v,
    const float* bnk_g, const float* bnk_b, const float* bnk_m, const float* bnk_v,
    const float* we_w1,
    const float* we_g, const float* we_b, const float* we_m, const float* we_v,
    float* eqT, float* ekT, float* vfT){
  __shared__ __align__(16) float qk[128][65];  // [channel][point]
  __shared__ float bnS[128], bnB[128];
  int t = threadIdx.x;
  int b = blockIdx.x >> 7;
  int n0 = (blockIdx.x & 127) * 64;
  int p = t & 63, og = t >> 6;
  const float* xp = x + (size_t)b*CH*NPTS + n0 + p;
  for (int mat = 0; mat < 3; ++mat){
    const float* W = (mat == 0) ? wq : ((mat == 1) ? wk : wv);
    if (mat < 2 && t < 128){
      const float* g_ = mat==0 ? bnq_g : bnk_g;
      const float* b_ = mat==0 ? bnq_b : bnk_b;
      const float* m_ = mat==0 ? bnq_m : bnk_m;
      const float* v_ = mat==0 ? bnq_v : bnk_v;
      float s = g_[t] / sqrtf(v_[t] + EPSN);
      bnS[t] = s;
      bnB[t] = b_[t] - m_[t] * s;
    }
    __syncthreads();   // also protects qk reuse across mats
    float acc[32];
    #pragma unroll
    for (int ii = 0; ii < 32; ++ii) acc[ii] = 0.f;
    for (int dd = 0; dd < 32; ++dd){
      float x0 = xp[(size_t)(4*dd+0)*NPTS];
      float x1 = xp[(size_t)(4*dd+1)*NPTS];
      float x2 = xp[(size_t)(4*dd+2)*NPTS];
      float x3 = xp[(size_t)(4*dd+3)*NPTS];
      #pragma unroll
      for (int ii = 0; ii < 32; ++ii){
        int o = og*32 + ii;
        float4 wu = *(const float4*)&W[o*128 + 4*dd];
        acc[ii] = fmaf(wu.x, x0, acc[ii]);
        acc[ii] = fmaf(wu.y, x1, acc[ii]);
        acc[ii] = fmaf(wu.z, x2, acc[ii]);
        acc[ii] = fmaf(wu.w, x3, acc[ii]);
      }
    }
    #pragma unroll
    for (int ii = 0; ii < 32; ++ii){
      int o = og*32 + ii;
      float v = acc[ii];
      if (mat < 2) v = fmaxf(fmaf(bnS[o], v, bnB[o]), 0.f);
      qk[o][p] = v;
    }
    __syncthreads();
    if (mat < 2){
      int g = t >> 5, pb = t & 31;
      float sg = we_g[g] / sqrtf(we_v[g] + EPSN);
      float tg = we_b[g] - we_m[g] * sg;
      #pragma unroll
      for (int half = 0; half < 2; ++half){
        int pp = pb + 32*half;
        float s = 0.f;
        for (int c = 0; c < 128; ++c) s = fmaf(we_w1[g*128+c], qk[c][pp], s);
        float val = (mat == 0) ? (tg - sg*s) : (sg*s);
        float* dst = (mat == 0) ? eqT : ekT;
        dst[(b*NPTS + n0 + pp)*8 + g] = val;
      }
    } else {
      for (int i = 0; i < 32; ++i){
        int f = t + 256*i;
        int c = f & 127, pp = f >> 7;
        vfT[((size_t)b*NPTS + n0 + pp)*CH + c] = qk[c][pp];
      }
    }
    __syncthreads();
  }
}

// ---------------- K3: exact KNN, 1024-sample threshold, reg-extraction ----------------
// T(q) = (upward-biased) 16th-smallest d2 among first 1024 candidates ->
// full-set count >= 16 GUARANTEED. Overflow (P~2%) handled by bisection.
// Collect unrolled x4 (memory-level parallelism). Extraction is pure-register:
// each lane holds its <=3 slots sorted; 16 shfl-min pop rounds (no LDS chain).
#define QW   4     // queries per wave
#define QPB  16    // queries per block (4 waves x 4)
#define CAPQ 192   // candidate slots per query (= 3*64)
__global__ __launch_bounds__(256) void k3_knn(const float4* pts, int* idxout){
  __shared__ u64 smBuf[4][QW][CAPQ];   // 24 KB, rows private per wave
  int t = threadIdx.x;
  int wv = t >> 6, lane = t & 63;
  int b  = blockIdx.x / (NPTS/QPB);
  int q0 = (blockIdx.x % (NPTS/QPB)) * QPB + wv*QW;
  const float4* P = pts + b*NPTS;

  // clear wave-private rows (stale-slot safety across failed attempts)
  #pragma unroll
  for (int s = 0; s < QW*CAPQ/64; ++s){
    int f = s*64 + lane;
    smBuf[wv][f / CAPQ][f % CAPQ] = ~0ull;
  }

  float4 qp[QW];
  #pragma unroll
  for (int i = 0; i < QW; ++i) qp[i] = P[q0 + i];

  // ---- sample phase: T[i] >= 16th-smallest d2 among candidates 0..1023 ----
  float T[QW];
  #pragma unroll
  for (int i = 0; i < QW; ++i){
    float sA[8], sB[8];
    #pragma unroll
    for (int j = 0; j < 8; ++j) sA[j] = d2f(qp[i], P[lane + 64*j]);
    sort8(sA);
    #pragma unroll
    for (int j = 0; j < 8; ++j) sB[j] = d2f(qp[i], P[512 + lane + 64*j]);
    sort8(sB);
    float u_[8];
    #pragma unroll
    for (int e = 0; e < 8; ++e) u_[e] = fminf(sA[e], sB[7-e]);
    sort8(u_);
    float Tq = u_[0];
    #pragma unroll
    for (int r = 0; r < 16; ++r){
      float m = u_[0];
      #pragma unroll
      for (int msk = 1; msk <= 32; msk <<= 1) m = fminf(m, __shfl_xor(m, msk));
      if (u_[0] == m){
        u_[0]=u_[1]; u_[1]=u_[2]; u_[2]=u_[3]; u_[3]=u_[4];
        u_[4]=u_[5]; u_[5]=u_[6]; u_[6]=u_[7]; u_[7]=3.402823466e38f;
      }
      Tq = m;
    }
    T[i] = Tq;
  }

  // ---- collect sweeps: cnt>=16 guaranteed at initial T; bisect on overflow ----
  float Tlo[QW], Thi[QW]; int cnt[QW];
  #pragma unroll
  for (int i = 0; i < QW; ++i){ Tlo[i] = -3.0e38f; Thi[i] = 3.0e38f; cnt[i] = 0; }
  auto step = [&](float4 c, u32 m, int i){
    float d2 = d2f(qp[i], c);
    bool pred = d2 <= T[i];
    u64 bm = __ballot(pred);
    int cc = __popcll(bm);
    if (pred && cnt[i] + cc <= CAPQ){
      int pos = cnt[i] + mbcnt64(bm);
      smBuf[wv][i][pos] = (((u64)mono32(d2)) << 32) | m;
    }
    cnt[i] += cc;
  };
  bool anybad = true;
  for (int att = 0; att < 16 && anybad; ++att){
    #pragma unroll
    for (int i = 0; i < QW; ++i) cnt[i] = 0;
    for (int base = 0; base < NPTS; base += 256){
      float4 c0 = P[base       + lane];
      float4 c1 = P[base +  64 + lane];
      float4 c2 = P[base + 128 + lane];
      float4 c3 = P[base + 192 + lane];
      #pragma unroll
      for (int i = 0; i < QW; ++i){
        step(c0, (u32)(base       + lane), i);
        step(c1, (u32)(base +  64 + lane), i);
        step(c2, (u32)(base + 128 + lane), i);
        step(c3, (u32)(base + 192 + lane), i);
      }
    }
    anybad = false;
    #pragma unroll
    for (int i = 0; i < QW; ++i){
      if (cnt[i] > CAPQ){
        Thi[i] = T[i];
        T[i] = (Tlo[i] > -3.0e38f) ? 0.5f*(Tlo[i] + Thi[i])
                                   : ((T[i] > 0.f) ? T[i]*0.5f : T[i]*2.0f - 1.0f);
        anybad = true;
      } else if (cnt[i] < 16){   // only reachable after an overflow-shrink
        Tlo[i] = T[i];
        T[i] = 0.5f*(Tlo[i] + Thi[i]);
        anybad = true;
      }
    }
  }

  // ---- extraction: register-resident 16-min pops (keys unique via idx bits) ----
  for (int i = 0; i < QW; ++i){
    int cq = cnt[i] < CAPQ ? cnt[i] : CAPQ;
    int n = q0 + i;
    u64 a  = (lane       < cq) ? smBuf[wv][i][lane      ] : ~0ull;
    u64 b_ = (lane +  64 < cq) ? smBuf[wv][i][lane +  64] : ~0ull;
    u64 c_ = (lane + 128 < cq) ? smBuf[wv][i][lane + 128] : ~0ull;
    if (b_ < a ){ u64 tm = a;  a  = b_; b_ = tm; }
    if (c_ < b_){ u64 tm = b_; b_ = c_; c_ = tm; }
    if (b_ < a ){ u64 tm = a;  a  = b_; b_ = tm; }
    #pragma unroll
    for (int r = 0; r < 16; ++r){
      u64 gm = a;
      #pragma unroll
      for (int msk = 1; msk <= 32; msk <<= 1){
        u64 o = shfl_xor_u64(gm, msk);
        gm = (o < gm) ? o : gm;
      }
      if (a == gm){ a = b_; b_ = c_; c_ = ~0ull; }
      if (lane == 0){
        int sel = (gm == ~0ull) ? n : (int)(gm & (u32)(NPTS-1));
        idxout[(b*NPTS + n)*16 + r] = sel;
      }
    }
  }
}

// ---------------- K4: fused attention, 1 wave/point, low-LDS ----------------
// No smHid: hidden recomputed in per-wave phase C (VALU is cheap, LDS is not).
// Per-block pe_w2/wo rows read once for 4 points. Only 3 __syncthreads.
#define H2S 136
__global__ __launch_bounds__(256) void k4_attn(
    const float4* pts, const float* eqT, const float* ekT, const int* idxw,
    const float* vfT, const float* wsA, const float4* wsPW1, const float* wsWE2,
    const float* pe_w2, const float* wo,
    const float* bno_g, const float* bno_b, const float* bno_m, const float* bno_v,
    float* out){
  __shared__ __align__(16) float4 smW1[128];      // 2 KB
  __shared__ __align__(16) float4 smP[4][16];     // 1 KB  r-vectors per wave
  __shared__ int   smJ[4][16];                    // 256 B neighbor indices
  __shared__ float smw[4][16][8];                 // 2 KB  weights [k][g]
  __shared__ __align__(16) float smH[4][8][H2S];  // 17.4 KB
  __shared__ __align__(16) float smOutv[4][128];  // 2 KB
  int t = threadIdx.x;
  int wv = t >> 6, lane = t & 63;
  int b  = blockIdx.x >> 11;          // NPTS/4 = 2048 blocks per batch
  int n0 = (blockIdx.x & 2047) * 4;
  if (t < 128) smW1[t] = wsPW1[t];
  __syncthreads();

  int n = n0 + wv;
  int gq = b*NPTS + n;
  int k = lane >> 2, q = lane & 3;

  // ---- phase A (wave-local): logits + softmax weights ----
  {
    float4 pn  = pts[gq];
    float4 eqa = *(const float4*)&eqT[gq*8];
    float4 eqb = *(const float4*)&eqT[gq*8+4];
    int j = idxw[gq*16 + k] & (NPTS-1);
    int gj = b*NPTS + j;
    float4 pj  = pts[gj];
    float4 eka = *(const float4*)&ekT[gj*8];
    float4 ekb = *(const float4*)&ekT[gj*8+4];
    float rx = pj.x - pn.x, ry = pj.y - pn.y, rz = pj.z - pn.z;
    if (q == 0){
      smP[wv][k] = make_float4(rx, ry, rz, 0.f);
      smJ[wv][k] = j;
    }
    // ee added ONCE after the q-lane reduction
    float ee[8] = {eka.x+eqa.x, eka.y+eqa.y, eka.z+eqa.z, eka.w+eqa.w,
                   ekb.x+eqb.x, ekb.y+eqb.y, ekb.z+eqb.z, ekb.w+eqb.w};
    float lp[8] = {0.f,0.f,0.f,0.f,0.f,0.f,0.f,0.f};
    #pragma unroll
    for (int i = 0; i < 8; ++i){
      int hb = 4*q + 16*i;
      float4 w1;
      w1 = smW1[hb+0]; float hv0 = fmaxf(fmaf(w1.x, rx, fmaf(w1.y, ry, fmaf(w1.z, rz, w1.w))), 0.f);
      w1 = smW1[hb+1]; float hv1 = fmaxf(fmaf(w1.x, rx, fmaf(w1.y, ry, fmaf(w1.z, rz, w1.w))), 0.f);
      w1 = smW1[hb+2]; float hv2 = fmaxf(fmaf(w1.x, rx, fmaf(w1.y, ry, fmaf(w1.z, rz, w1.w))), 0.f);
      w1 = smW1[hb+3]; float hv3 = fmaxf(fmaf(w1.x, rx, fmaf(w1.y, ry, fmaf(w1.z, rz, w1.w))), 0.f);
      #pragma unroll
      for (int g = 0; g < 8; ++g){
        float4 a4 = *(const float4*)&wsA[g*128 + hb];
        lp[g] = fmaf(a4.x, hv0, lp[g]);
        lp[g] = fmaf(a4.y, hv1, lp[g]);
        lp[g] = fmaf(a4.z, hv2, lp[g]);
        lp[g] = fmaf(a4.w, hv3, lp[g]);
      }
    }
    #pragma unroll
    for (int g = 0; g < 8; ++g){
      lp[g] += __shfl_xor(lp[g], 1);
      lp[g] += __shfl_xor(lp[g], 2);
      lp[g] = fmaxf(lp[g] + ee[g], 0.f);
    }
    float lo0 = 0.f, lo1 = 0.f;
    #pragma unroll
    for (int g = 0; g < 8; ++g){
      lo0 = fmaf(wsWE2[(2*q+0)*8 + g], lp[g], lo0);
      lo1 = fmaf(wsWE2[(2*q+1)*8 + g], lp[g], lo1);
    }
    float m0 = lo0, m1 = lo1;
    #pragma unroll
    for (int msk = 4; msk <= 32; msk <<= 1){
      m0 = fmaxf(m0, __shfl_xor(m0, msk));
      m1 = fmaxf(m1, __shfl_xor(m1, msk));
    }
    float e0 = __expf(lo0 - m0), e1 = __expf(lo1 - m1);
    float s0 = e0, s1 = e1;
    #pragma unroll
    for (int msk = 4; msk <= 32; msk <<= 1){
      s0 += __shfl_xor(s0, msk);
      s1 += __shfl_xor(s1, msk);
    }
    smw[wv][k][2*q+0] = e0 / s0;
    smw[wv][k][2*q+1] = e1 / s1;
  }

  // ---- phase C (wave-local): H[g][h] = sum_k w[g,k]*relu(W1[h].r_k) ----
  {
    int g3 = lane >> 3, hh = lane & 7;
    float4 H4[4];
    #pragma unroll
    for (int ii = 0; ii < 4; ++ii) H4[ii] = make_float4(0.f,0.f,0.f,0.f);
    for (int kk = 0; kk < 16; ++kk){
      float4 r4 = smP[wv][kk];
      float wg  = smw[wv][kk][g3];
      #pragma unroll
      for (int ii = 0; ii < 4; ++ii){
        int hb = 4*hh + 32*ii;
        float4 w1;
        w1 = smW1[hb+0]; float hv0 = fmaxf(fmaf(w1.x, r4.x, fmaf(w1.y, r4.y, fmaf(w1.z, r4.z, w1.w))), 0.f);
        w1 = smW1[hb+1]; float hv1 = fmaxf(fmaf(w1.x, r4.x, fmaf(w1.y, r4.y, fmaf(w1.z, r4.z, w1.w))), 0.f);
        w1 = smW1[hb+2]; float hv2 = fmaxf(fmaf(w1.x, r4.x, fmaf(w1.y, r4.y, fmaf(w1.z, r4.z, w1.w))), 0.f);
        w1 = smW1[hb+3]; float hv3 = fmaxf(fmaf(w1.x, r4.x, fmaf(w1.y, r4.y, fmaf(w1.z, r4.z, w1.w))), 0.f);
        H4[ii].x = fmaf(wg, hv0, H4[ii].x);
        H4[ii].y = fmaf(wg, hv1, H4[ii].y);
        H4[ii].z = fmaf(wg, hv2, H4[ii].z);
        H4[ii].w = fmaf(wg, hv3, H4[ii].w);
      }
    }
    #pragma unroll
    for (int ii = 0; ii < 4; ++ii)
      *(float4*)&smH[wv][g3][4*hh + 32*ii] = H4[ii];
  }
  __syncthreads();   // all waves' smH/smw/smJ visible block-wide

  // ---- phase D (block-wide, t<128): outv for all 4 points; pe_w2 rows read once ----
  if (t < 128){
    int c = t, g = c >> 4;
    float acc[4] = {0.f, 0.f, 0.f, 0.f};
    for (int i = 0; i < 32; ++i){
      float4 pw = *(const float4*)&pe_w2[c*128 + 4*i];
      #pragma unroll
      for (int pt = 0; pt < 4; ++pt){
        float4 h4 = *(const float4*)&smH[pt][g][4*i];
        acc[pt] = fmaf(pw.x, h4.x, acc[pt]);
        acc[pt] = fmaf(pw.y, h4.y, acc[pt]);
        acc[pt] = fmaf(pw.z, h4.z, acc[pt]);
        acc[pt] = fmaf(pw.w, h4.w, acc[pt]);
      }
    }
    #pragma unroll
    for (int pt = 0; pt < 4; ++pt){
      #pragma unroll
      for (int kk = 0; kk < 16; ++kk){
        int jj = smJ[pt][kk];
        float wgk = smw[pt][kk][g];
        acc[pt] = fmaf(wgk, vfT[((size_t)b*NPTS + jj)*CH + c], acc[pt]);
      }
      smOutv[pt][c] = acc[pt];
    }
  }
  __syncthreads();

  // ---- phase E (t<128): out[o][n0..n0+3] = bno(wo @ outv), float4 store ----
  if (t < 128){
    int o = t;
    float so = bno_g[o] / sqrtf(bno_v[o] + EPSN);
    float bo = bno_b[o] - bno_m[o] * so;
    float fa[4] = {0.f, 0.f, 0.f, 0.f};
    for (int i = 0; i < 32; ++i){
      float4 pw = *(const float4*)&wo[o*128 + 4*i];
      #pragma unroll
      for (int pt = 0; pt < 4; ++pt){
        float4 h4 = *(const float4*)&smOutv[pt][4*i];
        fa[pt] = fmaf(pw.x, h4.x, fa[pt]);
        fa[pt] = fmaf(pw.y, h4.y, fa[pt]);
        fa[pt] = fmaf(pw.z, h4.z, fa[pt]);
        fa[pt] = fmaf(pw.w, h4.w, fa[pt]);
      }
    }
    float4 st;
    st.x = fmaf(so, fa[0], bo);
    st.y = fmaf(so, fa[1], bo);
    st.z = fmaf(so, fa[2], bo);
    st.w = fmaf(so, fa[3], bo);
    *(float4*)&out[((size_t)b*CH + o)*NPTS + n0] = st;
  }
}

extern "C" void kernel_launch(void* const* d_in, const int* in_sizes, int n_in,
                              void* d_out, int out_size, void* d_ws, size_t ws_size,
                              hipStream_t stream){
  const float* x     = (const float*)d_in[0];
  const float* xyz   = (const float*)d_in[1];
  const float* wq    = (const float*)d_in[2];
  const float* bnq_g = (const float*)d_in[3];
  const float* bnq_b = (const float*)d_in[4];
  const float* bnq_m = (const float*)d_in[5];
  const float* bnq_v = (const float*)d_in[6];
  const float* wk    = (const float*)d_in[7];
  const float* bnk_g = (const float*)d_in[8];
  const float* bnk_b = (const float*)d_in[9];
  const float* bnk_m = (const float*)d_in[10];
  const float* bnk_v = (const float*)d_in[11];
  const float* wv    = (const float*)d_in[12];
  const float* pe_w1 = (const float*)d_in[13];
  const float* pe_g  = (const float*)d_in[14];
  const float* pe_b  = (const float*)d_in[15];
  const float* pe_m  = (const float*)d_in[16];
  const float* pe_v  = (const float*)d_in[17];
  const float* pe_w2 = (const float*)d_in[18];
  const float* we_w1 = (const float*)d_in[19];
  const float* we_g  = (const float*)d_in[20];
  const float* we_b  = (const float*)d_in[21];
  const float* we_m  = (const float*)d_in[22];
  const float* we_v  = (const float*)d_in[23];
  const float* we_w2 = (const float*)d_in[24];
  const float* wo    = (const float*)d_in[25];
  const float* bno_g = (const float*)d_in[26];
  const float* bno_b = (const float*)d_in[27];
  const float* bno_m = (const float*)d_in[28];
  const float* bno_v = (const float*)d_in[29];

  char* ws = (char*)d_ws;
  float*  wsA   = (float*)(ws + WS_A);
  float4* wsPW1 = (float4*)(ws + WS_PW1);
  float*  wsWE2 = (float*)(ws + WS_WE2);
  float4* pts   = (float4*)(ws + WS_PTS);
  float*  eqT   = (float*)(ws + WS_EQ);
  float*  ekT   = (float*)(ws + WS_EK);
  int*    idxw  = (int*)(ws + WS_IDX);
  float*  vfT   = (float*)(ws + WS_VFT);
  float*  outp  = (float*)d_out;

  k0_precomp<<<dim3(1), dim3(256), 0, stream>>>(we_w1, pe_w2, pe_w1, we_g, we_v,
                                                pe_g, pe_b, pe_m, pe_v, we_w2,
                                                wsA, wsPW1, wsWE2);
  k1_pts<<<dim3(64), dim3(256), 0, stream>>>(xyz, pts);
  k2_proj<<<dim3(256), dim3(256), 0, stream>>>(x, wq, wk, wv,
                                               bnq_g, bnq_b, bnq_m, bnq_v,
                                               bnk_g, bnk_b, bnk_m, bnk_v,
                                               we_w1, we_g, we_b, we_m, we_v,
                                               eqT, ekT, vfT);
  k3_knn<<<dim3(BATCH*(NPTS/QPB)), dim3(256), 0, stream>>>(pts, idxw);
  k4_attn<<<dim3(BATCH*(NPTS/4)), dim3(256), 0, stream>>>(pts, eqT, ekT, idxw, vfT,
                                                wsA, wsPW1, wsWE2, pe_w2, wo,
                                                bno_g, bno_b, bno_m, bno_v, outp);
}

// Round 10
// 445.799 us; speedup vs baseline: 2.1707x; 1.1401x over previous
//
#include <hip/hip_runtime.h>
#include <math.h>

typedef unsigned int u32;
typedef unsigned long long u64;

#define BATCH 2
#define CH 128
#define NPTS 8192
#define KNB 16
#define GRP 8
#define EPSN 1e-5f

// ---- workspace layout (bytes), total ~10.8 MB ----
#define WS_A     0           // 8*128 f32   A' = s_g * (we_w1 @ pe_w2)
#define WS_PW1   4096        // 128 float4  folded pe_w1 + pe_bn (sx,sy,sz,bias)
#define WS_WE2   6144        // 64 f32      we_w2
#define WS_PTS   8192        // 16384 float4 {x,y,z,|p|^2}
#define WS_EQ    270336      // B*N*8 f32   t_g - s_g*eq
#define WS_EK    794624      // B*N*8 f32   s_g*ek
#define WS_IDX   1318912     // B*N*16 int
#define WS_VFT   2367488     // B*N*128 f32 v transposed (point-major)

__device__ __forceinline__ float d2f(float4 a, float4 b){
  #pragma clang fp contract(off)
  float dot = a.x*b.x + a.y*b.y + a.z*b.z;
  return (a.w + b.w) - 2.0f*dot;
}
__device__ __forceinline__ u64 shfl_xor_u64(u64 v, int m){
  int lo = __shfl_xor((int)(u32)v, m);
  int hi = __shfl_xor((int)(u32)(v >> 32), m);
  return (((u64)(u32)hi) << 32) | (u32)lo;
}
__device__ __forceinline__ int mbcnt64(u64 bm){
  return (int)__builtin_amdgcn_mbcnt_hi((u32)(bm >> 32),
          __builtin_amdgcn_mbcnt_lo((u32)(bm & 0xFFFFFFFFull), 0u));
}
__device__ __forceinline__ u32 mono32(float d2){
  u32 db = __float_as_uint(d2);
  return (db & 0x80000000u) ? ~db : (db | 0x80000000u);  // monotone float->uint
}
__device__ __forceinline__ void sort8(float* s_){
  #pragma unroll
  for (int a = 0; a < 8; ++a){
    #pragma unroll
    for (int e = 0; e < 7; ++e){
      if (e < 7 - a){
        float lo = fminf(s_[e], s_[e+1]);
        float hi = fmaxf(s_[e], s_[e+1]);
        s_[e] = lo; s_[e+1] = hi;
      }
    }
  }
}

// ---------------- K0: tiny precompute ----------------
__global__ __launch_bounds__(256) void k0_precomp(
    const float* we_w1, const float* pe_w2, const float* pe_w1,
    const float* we_g, const float* we_v,
    const float* pe_g, const float* pe_b, const float* pe_m, const float* pe_v,
    const float* we_w2, float* wsA, float4* wsPW1, float* wsWE2){
  int t = threadIdx.x;
  for (int i = t; i < 1024; i += 256){
    int g = i >> 7, h = i & 127;
    float s = 0.f;
    for (int c = 0; c < 128; ++c) s = fmaf(we_w1[g*128+c], pe_w2[c*128+h], s);
    float sg = we_g[g] / sqrtf(we_v[g] + EPSN);
    wsA[i] = s * sg;
  }
  if (t < 128){
    float s = pe_g[t] / sqrtf(pe_v[t] + EPSN);
    float bb = pe_b[t] - pe_m[t] * s;
    wsPW1[t] = make_float4(s*pe_w1[t*3+0], s*pe_w1[t*3+1], s*pe_w1[t*3+2], bb);
  }
  if (t < 64) wsWE2[t] = we_w2[t];
}

// ---------------- K1: points + squared norms ----------------
__global__ __launch_bounds__(256) void k1_pts(const float* xyz, float4* pts){
  int id = blockIdx.x*256 + threadIdx.x;
  if (id >= BATCH*NPTS) return;
  int b = id >> 13, n = id & (NPTS-1);
  float x = xyz[(b*3+0)*NPTS + n];
  float y = xyz[(b*3+1)*NPTS + n];
  float z = xyz[(b*3+2)*NPTS + n];
  float sq;
  {
    #pragma clang fp contract(off)
    sq = (x*x + y*y) + z*z;
  }
  pts[id] = make_float4(x, y, z, sq);
}

// ---------------- K2: projections -> eqT, ekT, vfT ----------------
__global__ __launch_bounds__(256) void k2_proj(
    const float* x, const float* wq, const float* wk, const float* wv,
    const float* bnq_g, const float* bnq_b, const float* bnq_m, const float* bnq_v,
    const float* bnk_g, const float* bnk_b, const float* bnk_m, const float* bnk_v,
    const float* we_w1,
    const float* we_g, const float* we_b, const float* we_m, const float* we_v,
    float* eqT, float* ekT, float* vfT){
  __shared__ __align__(16) float qk[128][65];  // [channel][point]
  __shared__ float bnS[128], bnB[128];
  int t = threadIdx.x;
  int b = blockIdx.x >> 7;
  int n0 = (blockIdx.x & 127) * 64;
  int p = t & 63, og = t >> 6;
  const float* xp = x + (size_t)b*CH*NPTS + n0 + p;
  for (int mat = 0; mat < 3; ++mat){
    const float* W = (mat == 0) ? wq : ((mat == 1) ? wk : wv);
    if (mat < 2 && t < 128){
      const float* g_ = mat==0 ? bnq_g : bnk_g;
      const float* b_ = mat==0 ? bnq_b : bnk_b;
      const float* m_ = mat==0 ? bnq_m : bnk_m;
      const float* v_ = mat==0 ? bnq_v : bnk_v;
      float s = g_[t] / sqrtf(v_[t] + EPSN);
      bnS[t] = s;
      bnB[t] = b_[t] - m_[t] * s;
    }
    __syncthreads();   // also protects qk reuse across mats
    float acc[32];
    #pragma unroll
    for (int ii = 0; ii < 32; ++ii) acc[ii] = 0.f;
    for (int dd = 0; dd < 32; ++dd){
      float x0 = xp[(size_t)(4*dd+0)*NPTS];
      float x1 = xp[(size_t)(4*dd+1)*NPTS];
      float x2 = xp[(size_t)(4*dd+2)*NPTS];
      float x3 = xp[(size_t)(4*dd+3)*NPTS];
      #pragma unroll
      for (int ii = 0; ii < 32; ++ii){
        int o = og*32 + ii;
        float4 wu = *(const float4*)&W[o*128 + 4*dd];
        acc[ii] = fmaf(wu.x, x0, acc[ii]);
        acc[ii] = fmaf(wu.y, x1, acc[ii]);
        acc[ii] = fmaf(wu.z, x2, acc[ii]);
        acc[ii] = fmaf(wu.w, x3, acc[ii]);
      }
    }
    #pragma unroll
    for (int ii = 0; ii < 32; ++ii){
      int o = og*32 + ii;
      float v = acc[ii];
      if (mat < 2) v = fmaxf(fmaf(bnS[o], v, bnB[o]), 0.f);
      qk[o][p] = v;
    }
    __syncthreads();
    if (mat < 2){
      int g = t >> 5, pb = t & 31;
      float sg = we_g[g] / sqrtf(we_v[g] + EPSN);
      float tg = we_b[g] - we_m[g] * sg;
      #pragma unroll
      for (int half = 0; half < 2; ++half){
        int pp = pb + 32*half;
        float s = 0.f;
        for (int c = 0; c < 128; ++c) s = fmaf(we_w1[g*128+c], qk[c][pp], s);
        float val = (mat == 0) ? (tg - sg*s) : (sg*s);
        float* dst = (mat == 0) ? eqT : ekT;
        dst[(b*NPTS + n0 + pp)*8 + g] = val;
      }
    } else {
      for (int i = 0; i < 32; ++i){
        int f = t + 256*i;
        int c = f & 127, pp = f >> 7;
        vfT[((size_t)b*NPTS + n0 + pp)*CH + c] = qk[c][pp];
      }
    }
    __syncthreads();
  }
}

// ---------------- K3: exact KNN, 1024-sample threshold, reg-extraction ----------------
// QW=2 queries/wave -> grid 2048 blocks (8 blocks/CU, 32 waves/CU theoretical):
// total pair-work is invariant in QW, so doubling resident waves at constant
// work halves latency-exposed time. LDS 12 KB/block. Logic identical to the
// verified round-9 kernel (sample -> guaranteed cnt>=16 -> bisect overflow ->
// register-resident 16-min extraction).
#define QW   2     // queries per wave
#define QPB  8     // queries per block (4 waves x 2)
#define CAPQ 192   // candidate slots per query (= 3*64)
__global__ __launch_bounds__(256) void k3_knn(const float4* pts, int* idxout){
  __shared__ u64 smBuf[4][QW][CAPQ];   // 12 KB, rows private per wave
  int t = threadIdx.x;
  int wv = t >> 6, lane = t & 63;
  int b  = blockIdx.x / (NPTS/QPB);
  int q0 = (blockIdx.x % (NPTS/QPB)) * QPB + wv*QW;
  const float4* P = pts + b*NPTS;

  // clear wave-private rows (stale-slot safety across failed attempts)
  #pragma unroll
  for (int s = 0; s < QW*CAPQ/64; ++s){
    int f = s*64 + lane;
    smBuf[wv][f / CAPQ][f % CAPQ] = ~0ull;
  }

  float4 qp[QW];
  #pragma unroll
  for (int i = 0; i < QW; ++i) qp[i] = P[q0 + i];

  // ---- sample phase: T[i] >= 16th-smallest d2 among candidates 0..1023 ----
  float T[QW];
  #pragma unroll
  for (int i = 0; i < QW; ++i){
    float sA[8], sB[8];
    #pragma unroll
    for (int j = 0; j < 8; ++j) sA[j] = d2f(qp[i], P[lane + 64*j]);
    sort8(sA);
    #pragma unroll
    for (int j = 0; j < 8; ++j) sB[j] = d2f(qp[i], P[512 + lane + 64*j]);
    sort8(sB);
    float u_[8];
    #pragma unroll
    for (int e = 0; e < 8; ++e) u_[e] = fminf(sA[e], sB[7-e]);
    sort8(u_);
    float Tq = u_[0];
    #pragma unroll
    for (int r = 0; r < 16; ++r){
      float m = u_[0];
      #pragma unroll
      for (int msk = 1; msk <= 32; msk <<= 1) m = fminf(m, __shfl_xor(m, msk));
      if (u_[0] == m){
        u_[0]=u_[1]; u_[1]=u_[2]; u_[2]=u_[3]; u_[3]=u_[4];
        u_[4]=u_[5]; u_[5]=u_[6]; u_[6]=u_[7]; u_[7]=3.402823466e38f;
      }
      Tq = m;
    }
    T[i] = Tq;
  }

  // ---- collect sweeps: cnt>=16 guaranteed at initial T; bisect on overflow ----
  float Tlo[QW], Thi[QW]; int cnt[QW];
  #pragma unroll
  for (int i = 0; i < QW; ++i){ Tlo[i] = -3.0e38f; Thi[i] = 3.0e38f; cnt[i] = 0; }
  auto step = [&](float4 c, u32 m, int i){
    float d2 = d2f(qp[i], c);
    bool pred = d2 <= T[i];
    u64 bm = __ballot(pred);
    int cc = __popcll(bm);
    if (pred && cnt[i] + cc <= CAPQ){
      int pos = cnt[i] + mbcnt64(bm);
      smBuf[wv][i][pos] = (((u64)mono32(d2)) << 32) | m;
    }
    cnt[i] += cc;
  };
  bool anybad = true;
  for (int att = 0; att < 16 && anybad; ++att){
    #pragma unroll
    for (int i = 0; i < QW; ++i) cnt[i] = 0;
    for (int base = 0; base < NPTS; base += 256){
      float4 c0 = P[base       + lane];
      float4 c1 = P[base +  64 + lane];
      float4 c2 = P[base + 128 + lane];
      float4 c3 = P[base + 192 + lane];
      #pragma unroll
      for (int i = 0; i < QW; ++i){
        step(c0, (u32)(base       + lane), i);
        step(c1, (u32)(base +  64 + lane), i);
        step(c2, (u32)(base + 128 + lane), i);
        step(c3, (u32)(base + 192 + lane), i);
      }
    }
    anybad = false;
    #pragma unroll
    for (int i = 0; i < QW; ++i){
      if (cnt[i] > CAPQ){
        Thi[i] = T[i];
        T[i] = (Tlo[i] > -3.0e38f) ? 0.5f*(Tlo[i] + Thi[i])
                                   : ((T[i] > 0.f) ? T[i]*0.5f : T[i]*2.0f - 1.0f);
        anybad = true;
      } else if (cnt[i] < 16){   // only reachable after an overflow-shrink
        Tlo[i] = T[i];
        T[i] = 0.5f*(Tlo[i] + Thi[i]);
        anybad = true;
      }
    }
  }

  // ---- extraction: register-resident 16-min pops (keys unique via idx bits) ----
  for (int i = 0; i < QW; ++i){
    int cq = cnt[i] < CAPQ ? cnt[i] : CAPQ;
    int n = q0 + i;
    u64 a  = (lane       < cq) ? smBuf[wv][i][lane      ] : ~0ull;
    u64 b_ = (lane +  64 < cq) ? smBuf[wv][i][lane +  64] : ~0ull;
    u64 c_ = (lane + 128 < cq) ? smBuf[wv][i][lane + 128] : ~0ull;
    if (b_ < a ){ u64 tm = a;  a  = b_; b_ = tm; }
    if (c_ < b_){ u64 tm = b_; b_ = c_; c_ = tm; }
    if (b_ < a ){ u64 tm = a;  a  = b_; b_ = tm; }
    #pragma unroll
    for (int r = 0; r < 16; ++r){
      u64 gm = a;
      #pragma unroll
      for (int msk = 1; msk <= 32; msk <<= 1){
        u64 o = shfl_xor_u64(gm, msk);
        gm = (o < gm) ? o : gm;
      }
      if (a == gm){ a = b_; b_ = c_; c_ = ~0ull; }
      if (lane == 0){
        int sel = (gm == ~0ull) ? n : (int)(gm & (u32)(NPTS-1));
        idxout[(b*NPTS + n)*16 + r] = sel;
      }
    }
  }
}

// ---------------- K4: fused attention, 1 wave/point, low-LDS ----------------
// No smHid: hidden recomputed in per-wave phase C (VALU is cheap, LDS is not).
// Per-block pe_w2/wo rows read once for 4 points. Only 3 __syncthreads.
#define H2S 136
__global__ __launch_bounds__(256) void k4_attn(
    const float4* pts, const float* eqT, const float* ekT, const int* idxw,
    const float* vfT, const float* wsA, const float4* wsPW1, const float* wsWE2,
    const float* pe_w2, const float* wo,
    const float* bno_g, const float* bno_b, const float* bno_m, const float* bno_v,
    float* out){
  __shared__ __align__(16) float4 smW1[128];      // 2 KB
  __shared__ __align__(16) float4 smP[4][16];     // 1 KB  r-vectors per wave
  __shared__ int   smJ[4][16];                    // 256 B neighbor indices
  __shared__ float smw[4][16][8];                 // 2 KB  weights [k][g]
  __shared__ __align__(16) float smH[4][8][H2S];  // 17.4 KB
  __shared__ __align__(16) float smOutv[4][128];  // 2 KB
  int t = threadIdx.x;
  int wv = t >> 6, lane = t & 63;
  int b  = blockIdx.x >> 11;          // NPTS/4 = 2048 blocks per batch
  int n0 = (blockIdx.x & 2047) * 4;
  if (t < 128) smW1[t] = wsPW1[t];
  __syncthreads();

  int n = n0 + wv;
  int gq = b*NPTS + n;
  int k = lane >> 2, q = lane & 3;

  // ---- phase A (wave-local): logits + softmax weights ----
  {
    float4 pn  = pts[gq];
    float4 eqa = *(const float4*)&eqT[gq*8];
    float4 eqb = *(const float4*)&eqT[gq*8+4];
    int j = idxw[gq*16 + k] & (NPTS-1);
    int gj = b*NPTS + j;
    float4 pj  = pts[gj];
    float4 eka = *(const float4*)&ekT[gj*8];
    float4 ekb = *(const float4*)&ekT[gj*8+4];
    float rx = pj.x - pn.x, ry = pj.y - pn.y, rz = pj.z - pn.z;
    if (q == 0){
      smP[wv][k] = make_float4(rx, ry, rz, 0.f);
      smJ[wv][k] = j;
    }
    // ee added ONCE after the q-lane reduction
    float ee[8] = {eka.x+eqa.x, eka.y+eqa.y, eka.z+eqa.z, eka.w+eqa.w,
                   ekb.x+eqb.x, ekb.y+eqb.y, ekb.z+eqb.z, ekb.w+eqb.w};
    float lp[8] = {0.f,0.f,0.f,0.f,0.f,0.f,0.f,0.f};
    #pragma unroll
    for (int i = 0; i < 8; ++i){
      int hb = 4*q + 16*i;
      float4 w1;
      w1 = smW1[hb+0]; float hv0 = fmaxf(fmaf(w1.x, rx, fmaf(w1.y, ry, fmaf(w1.z, rz, w1.w))), 0.f);
      w1 = smW1[hb+1]; float hv1 = fmaxf(fmaf(w1.x, rx, fmaf(w1.y, ry, fmaf(w1.z, rz, w1.w))), 0.f);
      w1 = smW1[hb+2]; float hv2 = fmaxf(fmaf(w1.x, rx, fmaf(w1.y, ry, fmaf(w1.z, rz, w1.w))), 0.f);
      w1 = smW1[hb+3]; float hv3 = fmaxf(fmaf(w1.x, rx, fmaf(w1.y, ry, fmaf(w1.z, rz, w1.w))), 0.f);
      #pragma unroll
      for (int g = 0; g < 8; ++g){
        float4 a4 = *(const float4*)&wsA[g*128 + hb];
        lp[g] = fmaf(a4.x, hv0, lp[g]);
        lp[g] = fmaf(a4.y, hv1, lp[g]);
        lp[g] = fmaf(a4.z, hv2, lp[g]);
        lp[g] = fmaf(a4.w, hv3, lp[g]);
      }
    }
    #pragma unroll
    for (int g = 0; g < 8; ++g){
      lp[g] += __shfl_xor(lp[g], 1);
      lp[g] += __shfl_xor(lp[g], 2);
      lp[g] = fmaxf(lp[g] + ee[g], 0.f);
    }
    float lo0 = 0.f, lo1 = 0.f;
    #pragma unroll
    for (int g = 0; g < 8; ++g){
      lo0 = fmaf(wsWE2[(2*q+0)*8 + g], lp[g], lo0);
      lo1 = fmaf(wsWE2[(2*q+1)*8 + g], lp[g], lo1);
    }
    float m0 = lo0, m1 = lo1;
    #pragma unroll
    for (int msk = 4; msk <= 32; msk <<= 1){
      m0 = fmaxf(m0, __shfl_xor(m0, msk));
      m1 = fmaxf(m1, __shfl_xor(m1, msk));
    }
    float e0 = __expf(lo0 - m0), e1 = __expf(lo1 - m1);
    float s0 = e0, s1 = e1;
    #pragma unroll
    for (int msk = 4; msk <= 32; msk <<= 1){
      s0 += __shfl_xor(s0, msk);
      s1 += __shfl_xor(s1, msk);
    }
    smw[wv][k][2*q+0] = e0 / s0;
    smw[wv][k][2*q+1] = e1 / s1;
  }

  // ---- phase C (wave-local): H[g][h] = sum_k w[g,k]*relu(W1[h].r_k) ----
  {
    int g3 = lane >> 3, hh = lane & 7;
    float4 H4[4];
    #pragma unroll
    for (int ii = 0; ii < 4; ++ii) H4[ii] = make_float4(0.f,0.f,0.f,0.f);
    for (int kk = 0; kk < 16; ++kk){
      float4 r4 = smP[wv][kk];
      float wg  = smw[wv][kk][g3];
      #pragma unroll
      for (int ii = 0; ii < 4; ++ii){
        int hb = 4*hh + 32*ii;
        float4 w1;
        w1 = smW1[hb+0]; float hv0 = fmaxf(fmaf(w1.x, r4.x, fmaf(w1.y, r4.y, fmaf(w1.z, r4.z, w1.w))), 0.f);
        w1 = smW1[hb+1]; float hv1 = fmaxf(fmaf(w1.x, r4.x, fmaf(w1.y, r4.y, fmaf(w1.z, r4.z, w1.w))), 0.f);
        w1 = smW1[hb+2]; float hv2 = fmaxf(fmaf(w1.x, r4.x, fmaf(w1.y, r4.y, fmaf(w1.z, r4.z, w1.w))), 0.f);
        w1 = smW1[hb+3]; float hv3 = fmaxf(fmaf(w1.x, r4.x, fmaf(w1.y, r4.y, fmaf(w1.z, r4.z, w1.w))), 0.f);
        H4[ii].x = fmaf(wg, hv0, H4[ii].x);
        H4[ii].y = fmaf(wg, hv1, H4[ii].y);
        H4[ii].z = fmaf(wg, hv2, H4[ii].z);
        H4[ii].w = fmaf(wg, hv3, H4[ii].w);
      }
    }
    #pragma unroll
    for (int ii = 0; ii < 4; ++ii)
      *(float4*)&smH[wv][g3][4*hh + 32*ii] = H4[ii];
  }
  __syncthreads();   // all waves' smH/smw/smJ visible block-wide

  // ---- phase D (block-wide, t<128): outv for all 4 points; pe_w2 rows read once ----
  if (t < 128){
    int c = t, g = c >> 4;
    float acc[4] = {0.f, 0.f, 0.f, 0.f};
    for (int i = 0; i < 32; ++i){
      float4 pw = *(const float4*)&pe_w2[c*128 + 4*i];
      #pragma unroll
      for (int pt = 0; pt < 4; ++pt){
        float4 h4 = *(const float4*)&smH[pt][g][4*i];
        acc[pt] = fmaf(pw.x, h4.x, acc[pt]);
        acc[pt] = fmaf(pw.y, h4.y, acc[pt]);
        acc[pt] = fmaf(pw.z, h4.z, acc[pt]);
        acc[pt] = fmaf(pw.w, h4.w, acc[pt]);
      }
    }
    #pragma unroll
    for (int pt = 0; pt < 4; ++pt){
      #pragma unroll
      for (int kk = 0; kk < 16; ++kk){
        int jj = smJ[pt][kk];
        float wgk = smw[pt][kk][g];
        acc[pt] = fmaf(wgk, vfT[((size_t)b*NPTS + jj)*CH + c], acc[pt]);
      }
      smOutv[pt][c] = acc[pt];
    }
  }
  __syncthreads();

  // ---- phase E (t<128): out[o][n0..n0+3] = bno(wo @ outv), float4 store ----
  if (t < 128){
    int o = t;
    float so = bno_g[o] / sqrtf(bno_v[o] + EPSN);
    float bo = bno_b[o] - bno_m[o] * so;
    float fa[4] = {0.f, 0.f, 0.f, 0.f};
    for (int i = 0; i < 32; ++i){
      float4 pw = *(const float4*)&wo[o*128 + 4*i];
      #pragma unroll
      for (int pt = 0; pt < 4; ++pt){
        float4 h4 = *(const float4*)&smOutv[pt][4*i];
        fa[pt] = fmaf(pw.x, h4.x, fa[pt]);
        fa[pt] = fmaf(pw.y, h4.y, fa[pt]);
        fa[pt] = fmaf(pw.z, h4.z, fa[pt]);
        fa[pt] = fmaf(pw.w, h4.w, fa[pt]);
      }
    }
    float4 st;
    st.x = fmaf(so, fa[0], bo);
    st.y = fmaf(so, fa[1], bo);
    st.z = fmaf(so, fa[2], bo);
    st.w = fmaf(so, fa[3], bo);
    *(float4*)&out[((size_t)b*CH + o)*NPTS + n0] = st;
  }
}

extern "C" void kernel_launch(void* const* d_in, const int* in_sizes, int n_in,
                              void* d_out, int out_size, void* d_ws, size_t ws_size,
                              hipStream_t stream){
  const float* x     = (const float*)d_in[0];
  const float* xyz   = (const float*)d_in[1];
  const float* wq    = (const float*)d_in[2];
  const float* bnq_g = (const float*)d_in[3];
  const float* bnq_b = (const float*)d_in[4];
  const float* bnq_m = (const float*)d_in[5];
  const float* bnq_v = (const float*)d_in[6];
  const float* wk    = (const float*)d_in[7];
  const float* bnk_g = (const float*)d_in[8];
  const float* bnk_b = (const float*)d_in[9];
  const float* bnk_m = (const float*)d_in[10];
  const float* bnk_v = (const float*)d_in[11];
  const float* wv    = (const float*)d_in[12];
  const float* pe_w1 = (const float*)d_in[13];
  const float* pe_g  = (const float*)d_in[14];
  const float* pe_b  = (const float*)d_in[15];
  const float* pe_m  = (const float*)d_in[16];
  const float* pe_v  = (const float*)d_in[17];
  const float* pe_w2 = (const float*)d_in[18];
  const float* we_w1 = (const float*)d_in[19];
  const float* we_g  = (const float*)d_in[20];
  const float* we_b  = (const float*)d_in[21];
  const float* we_m  = (const float*)d_in[22];
  const float* we_v  = (const float*)d_in[23];
  const float* we_w2 = (const float*)d_in[24];
  const float* wo    = (const float*)d_in[25];
  const float* bno_g = (const float*)d_in[26];
  const float* bno_b = (const float*)d_in[27];
  const float* bno_m = (const float*)d_in[28];
  const float* bno_v = (const float*)d_in[29];

  char* ws = (char*)d_ws;
  float*  wsA   = (float*)(ws + WS_A);
  float4* wsPW1 = (float4*)(ws + WS_PW1);
  float*  wsWE2 = (float*)(ws + WS_WE2);
  float4* pts   = (float4*)(ws + WS_PTS);
  float*  eqT   = (float*)(ws + WS_EQ);
  float*  ekT   = (float*)(ws + WS_EK);
  int*    idxw  = (int*)(ws + WS_IDX);
  float*  vfT   = (float*)(ws + WS_VFT);
  float*  outp  = (float*)d_out;

  k0_precomp<<<dim3(1), dim3(256), 0, stream>>>(we_w1, pe_w2, pe_w1, we_g, we_v,
                                                pe_g, pe_b, pe_m, pe_v, we_w2,
                                                wsA, wsPW1, wsWE2);
  k1_pts<<<dim3(64), dim3(256), 0, stream>>>(xyz, pts);
  k2_proj<<<dim3(256), dim3(256), 0, stream>>>(x, wq, wk, wv,
                                               bnq_g, bnq_b, bnq_m, bnq_v,
                                               bnk_g, bnk_b, bnk_m, bnk_v,
                                               we_w1, we_g, we_b, we_m, we_v,
                                               eqT, ekT, vfT);
  k3_knn<<<dim3(BATCH*(NPTS/QPB)), dim3(256), 0, stream>>>(pts, idxw);
  k4_attn<<<dim3(BATCH*(NPTS/4)), dim3(256), 0, stream>>>(pts, eqT, ekT, idxw, vfT,
                                                wsA, wsPW1, wsWE2, pe_w2, wo,
                                                bno_g, bno_b, bno_m, bno_v, outp);
}

// Round 11
// 370.108 us; speedup vs baseline: 2.6147x; 1.2045x over previous
//
#include <hip/hip_runtime.h>
#include <math.h>

typedef unsigned int u32;
typedef unsigned long long u64;

#define BATCH 2
#define CH 128
#define NPTS 8192
#define KNB 16
#define GRP 8
#define EPSN 1e-5f

// ---- workspace layout (bytes), total ~10.8 MB ----
#define WS_A     0           // 8*128 f32   A' = s_g * (we_w1 @ pe_w2)
#define WS_PW1   4096        // 128 float4  folded pe_w1 + pe_bn (sx,sy,sz,bias)
#define WS_WE2   6144        // 64 f32      we_w2
#define WS_PTS   8192        // 16384 float4 {x,y,z,|p|^2}
#define WS_EQ    270336      // B*N*8 f32   t_g - s_g*eq
#define WS_EK    794624      // B*N*8 f32   s_g*ek
#define WS_IDX   1318912     // B*N*16 int
#define WS_VFT   2367488     // B*N*128 f32 v transposed (point-major)

__device__ __forceinline__ float d2f(float4 a, float4 b){
  #pragma clang fp contract(off)
  float dot = a.x*b.x + a.y*b.y + a.z*b.z;
  return (a.w + b.w) - 2.0f*dot;
}
__device__ __forceinline__ u64 shfl_xor_u64(u64 v, int m){
  int lo = __shfl_xor((int)(u32)v, m);
  int hi = __shfl_xor((int)(u32)(v >> 32), m);
  return (((u64)(u32)hi) << 32) | (u32)lo;
}
__device__ __forceinline__ int mbcnt64(u64 bm){
  return (int)__builtin_amdgcn_mbcnt_hi((u32)(bm >> 32),
          __builtin_amdgcn_mbcnt_lo((u32)(bm & 0xFFFFFFFFull), 0u));
}
__device__ __forceinline__ u32 mono32(float d2){
  u32 db = __float_as_uint(d2);
  return (db & 0x80000000u) ? ~db : (db | 0x80000000u);  // monotone float->uint
}
__device__ __forceinline__ void sort8(float* s_){
  #pragma unroll
  for (int a = 0; a < 8; ++a){
    #pragma unroll
    for (int e = 0; e < 7; ++e){
      if (e < 7 - a){
        float lo = fminf(s_[e], s_[e+1]);
        float hi = fmaxf(s_[e], s_[e+1]);
        s_[e] = lo; s_[e+1] = hi;
      }
    }
  }
}

// ---------------- K0: tiny precompute ----------------
__global__ __launch_bounds__(256) void k0_precomp(
    const float* we_w1, const float* pe_w2, const float* pe_w1,
    const float* we_g, const float* we_v,
    const float* pe_g, const float* pe_b, const float* pe_m, const float* pe_v,
    const float* we_w2, float* wsA, float4* wsPW1, float* wsWE2){
  int t = threadIdx.x;
  for (int i = t; i < 1024; i += 256){
    int g = i >> 7, h = i & 127;
    float s = 0.f;
    for (int c = 0; c < 128; ++c) s = fmaf(we_w1[g*128+c], pe_w2[c*128+h], s);
    float sg = we_g[g] / sqrtf(we_v[g] + EPSN);
    wsA[i] = s * sg;
  }
  if (t < 128){
    float s = pe_g[t] / sqrtf(pe_v[t] + EPSN);
    float bb = pe_b[t] - pe_m[t] * s;
    wsPW1[t] = make_float4(s*pe_w1[t*3+0], s*pe_w1[t*3+1], s*pe_w1[t*3+2], bb);
  }
  if (t < 64) wsWE2[t] = we_w2[t];
}

// ---------------- K1: points + squared norms ----------------
__global__ __launch_bounds__(256) void k1_pts(const float* xyz, float4* pts){
  int id = blockIdx.x*256 + threadIdx.x;
  if (id >= BATCH*NPTS) return;
  int b = id >> 13, n = id & (NPTS-1);
  float x = xyz[(b*3+0)*NPTS + n];
  float y = xyz[(b*3+1)*NPTS + n];
  float z = xyz[(b*3+2)*NPTS + n];
  float sq;
  {
    #pragma clang fp contract(off)
    sq = (x*x + y*y) + z*z;
  }
  pts[id] = make_float4(x, y, z, sq);
}

// ---------------- K2: projections, mat-split grid, 32-pt tiles ----------------
// Grid = BATCH * (NPTS/32) * 3 = 1536 blocks (6/CU, ~24 waves/CU vs old 1 block/CU).
// LDS tile point-major qk2[32][129]: conflict-free writes, bank-stride-1 reads
// for the we_w1 dot, float4 reads + coalesced float4 stores for vfT.
#define K2PTS 32
__global__ __launch_bounds__(256) void k2_proj(
    const float* x, const float* wq, const float* wk, const float* wv,
    const float* bnq_g, const float* bnq_b, const float* bnq_m, const float* bnq_v,
    const float* bnk_g, const float* bnk_b, const float* bnk_m, const float* bnk_v,
    const float* we_w1,
    const float* we_g, const float* we_b, const float* we_m, const float* we_v,
    float* eqT, float* ekT, float* vfT){
  __shared__ __align__(16) float qk2[K2PTS][129];  // [point][channel], 16.5 KB
  __shared__ float bnS[128], bnB[128];
  int t = threadIdx.x;
  int mat = blockIdx.x % 3;
  int tmp = blockIdx.x / 3;
  int b   = tmp / (NPTS/K2PTS);
  int n0  = (tmp % (NPTS/K2PTS)) * K2PTS;
  int p = t & 31, og = t >> 5;          // og in 0..7, 16 output channels each
  const float* xp = x + (size_t)b*CH*NPTS + n0 + p;
  const float* W = (mat == 0) ? wq : ((mat == 1) ? wk : wv);
  if (mat < 2 && t < 128){
    const float* g_ = mat==0 ? bnq_g : bnk_g;
    const float* b_ = mat==0 ? bnq_b : bnk_b;
    const float* m_ = mat==0 ? bnq_m : bnk_m;
    const float* v_ = mat==0 ? bnq_v : bnk_v;
    float s = g_[t] / sqrtf(v_[t] + EPSN);
    bnS[t] = s;
    bnB[t] = b_[t] - m_[t] * s;
  }
  __syncthreads();
  float acc[16];
  #pragma unroll
  for (int ii = 0; ii < 16; ++ii) acc[ii] = 0.f;
  for (int dd = 0; dd < 32; ++dd){
    float x0 = xp[(size_t)(4*dd+0)*NPTS];
    float x1 = xp[(size_t)(4*dd+1)*NPTS];
    float x2 = xp[(size_t)(4*dd+2)*NPTS];
    float x3 = xp[(size_t)(4*dd+3)*NPTS];
    #pragma unroll
    for (int ii = 0; ii < 16; ++ii){
      int o = og*16 + ii;
      float4 wu = *(const float4*)&W[o*128 + 4*dd];
      acc[ii] = fmaf(wu.x, x0, acc[ii]);
      acc[ii] = fmaf(wu.y, x1, acc[ii]);
      acc[ii] = fmaf(wu.z, x2, acc[ii]);
      acc[ii] = fmaf(wu.w, x3, acc[ii]);
    }
  }
  #pragma unroll
  for (int ii = 0; ii < 16; ++ii){
    int o = og*16 + ii;
    float v = acc[ii];
    if (mat < 2) v = fmaxf(fmaf(bnS[o], v, bnB[o]), 0.f);
    qk2[p][o] = v;
  }
  __syncthreads();
  if (mat < 2){
    int g = t >> 5, pp = t & 31;
    float sg = we_g[g] / sqrtf(we_v[g] + EPSN);
    float tg = we_b[g] - we_m[g] * sg;
    float s = 0.f;
    for (int c4 = 0; c4 < 32; ++c4){
      float4 wv4 = *(const float4*)&we_w1[g*128 + 4*c4];
      float4 qv4 = *(const float4*)&qk2[pp][4*c4];
      s = fmaf(wv4.x, qv4.x, s);
      s = fmaf(wv4.y, qv4.y, s);
      s = fmaf(wv4.z, qv4.z, s);
      s = fmaf(wv4.w, qv4.w, s);
    }
    float val = (mat == 0) ? (tg - sg*s) : (sg*s);
    float* dst = (mat == 0) ? eqT : ekT;
    dst[(b*NPTS + n0 + pp)*8 + g] = val;
  } else {
    #pragma unroll
    for (int i = 0; i < 4; ++i){
      int f = t + 256*i;        // 0..1023 float4 units (32 pts x 32 float4)
      int pp = f >> 5, c4 = (f & 31)*4;
      float4 v = *(const float4*)&qk2[pp][c4];
      *(float4*)&vfT[((size_t)b*NPTS + n0 + pp)*CH + c4] = v;
    }
  }
}

// ---------------- K3: exact KNN, 1024-sample threshold, reg-extraction ----------------
#define QW   2     // queries per wave
#define QPB  8     // queries per block (4 waves x 2)
#define CAPQ 192   // candidate slots per query (= 3*64)
__global__ __launch_bounds__(256) void k3_knn(const float4* pts, int* idxout){
  __shared__ u64 smBuf[4][QW][CAPQ];   // 12 KB, rows private per wave
  int t = threadIdx.x;
  int wv = t >> 6, lane = t & 63;
  int b  = blockIdx.x / (NPTS/QPB);
  int q0 = (blockIdx.x % (NPTS/QPB)) * QPB + wv*QW;
  const float4* P = pts + b*NPTS;

  #pragma unroll
  for (int s = 0; s < QW*CAPQ/64; ++s){
    int f = s*64 + lane;
    smBuf[wv][f / CAPQ][f % CAPQ] = ~0ull;
  }

  float4 qp[QW];
  #pragma unroll
  for (int i = 0; i < QW; ++i) qp[i] = P[q0 + i];

  // ---- sample phase: T[i] >= 16th-smallest d2 among candidates 0..1023 ----
  float T[QW];
  #pragma unroll
  for (int i = 0; i < QW; ++i){
    float sA[8], sB[8];
    #pragma unroll
    for (int j = 0; j < 8; ++j) sA[j] = d2f(qp[i], P[lane + 64*j]);
    sort8(sA);
    #pragma unroll
    for (int j = 0; j < 8; ++j) sB[j] = d2f(qp[i], P[512 + lane + 64*j]);
    sort8(sB);
    float u_[8];
    #pragma unroll
    for (int e = 0; e < 8; ++e) u_[e] = fminf(sA[e], sB[7-e]);
    sort8(u_);
    float Tq = u_[0];
    #pragma unroll
    for (int r = 0; r < 16; ++r){
      float m = u_[0];
      #pragma unroll
      for (int msk = 1; msk <= 32; msk <<= 1) m = fminf(m, __shfl_xor(m, msk));
      if (u_[0] == m){
        u_[0]=u_[1]; u_[1]=u_[2]; u_[2]=u_[3]; u_[3]=u_[4];
        u_[4]=u_[5]; u_[5]=u_[6]; u_[6]=u_[7]; u_[7]=3.402823466e38f;
      }
      Tq = m;
    }
    T[i] = Tq;
  }

  // ---- collect sweeps: cnt>=16 guaranteed at initial T; bisect on overflow ----
  float Tlo[QW], Thi[QW]; int cnt[QW];
  #pragma unroll
  for (int i = 0; i < QW; ++i){ Tlo[i] = -3.0e38f; Thi[i] = 3.0e38f; cnt[i] = 0; }
  auto step = [&](float4 c, u32 m, int i){
    float d2 = d2f(qp[i], c);
    bool pred = d2 <= T[i];
    u64 bm = __ballot(pred);
    int cc = __popcll(bm);
    if (pred && cnt[i] + cc <= CAPQ){
      int pos = cnt[i] + mbcnt64(bm);
      smBuf[wv][i][pos] = (((u64)mono32(d2)) << 32) | m;
    }
    cnt[i] += cc;
  };
  bool anybad = true;
  for (int att = 0; att < 16 && anybad; ++att){
    #pragma unroll
    for (int i = 0; i < QW; ++i) cnt[i] = 0;
    for (int base = 0; base < NPTS; base += 256){
      float4 c0 = P[base       + lane];
      float4 c1 = P[base +  64 + lane];
      float4 c2 = P[base + 128 + lane];
      float4 c3 = P[base + 192 + lane];
      #pragma unroll
      for (int i = 0; i < QW; ++i){
        step(c0, (u32)(base       + lane), i);
        step(c1, (u32)(base +  64 + lane), i);
        step(c2, (u32)(base + 128 + lane), i);
        step(c3, (u32)(base + 192 + lane), i);
      }
    }
    anybad = false;
    #pragma unroll
    for (int i = 0; i < QW; ++i){
      if (cnt[i] > CAPQ){
        Thi[i] = T[i];
        T[i] = (Tlo[i] > -3.0e38f) ? 0.5f*(Tlo[i] + Thi[i])
                                   : ((T[i] > 0.f) ? T[i]*0.5f : T[i]*2.0f - 1.0f);
        anybad = true;
      } else if (cnt[i] < 16){   // only reachable after an overflow-shrink
        Tlo[i] = T[i];
        T[i] = 0.5f*(Tlo[i] + Thi[i]);
        anybad = true;
      }
    }
  }

  // ---- extraction: register-resident 16-min pops (keys unique via idx bits) ----
  for (int i = 0; i < QW; ++i){
    int cq = cnt[i] < CAPQ ? cnt[i] : CAPQ;
    int n = q0 + i;
    u64 a  = (lane       < cq) ? smBuf[wv][i][lane      ] : ~0ull;
    u64 b_ = (lane +  64 < cq) ? smBuf[wv][i][lane +  64] : ~0ull;
    u64 c_ = (lane + 128 < cq) ? smBuf[wv][i][lane + 128] : ~0ull;
    if (b_ < a ){ u64 tm = a;  a  = b_; b_ = tm; }
    if (c_ < b_){ u64 tm = b_; b_ = c_; c_ = tm; }
    if (b_ < a ){ u64 tm = a;  a  = b_; b_ = tm; }
    #pragma unroll
    for (int r = 0; r < 16; ++r){
      u64 gm = a;
      #pragma unroll
      for (int msk = 1; msk <= 32; msk <<= 1){
        u64 o = shfl_xor_u64(gm, msk);
        gm = (o < gm) ? o : gm;
      }
      if (a == gm){ a = b_; b_ = c_; c_ = ~0ull; }
      if (lane == 0){
        int sel = (gm == ~0ull) ? n : (int)(gm & (u32)(NPTS-1));
        idxout[(b*NPTS + n)*16 + r] = sel;
      }
    }
  }
}

// ---------------- K4: fused attention, 1 wave/point, low-LDS ----------------
#define H2S 136
__global__ __launch_bounds__(256) void k4_attn(
    const float4* pts, const float* eqT, const float* ekT, const int* idxw,
    const float* vfT, const float* wsA, const float4* wsPW1, const float* wsWE2,
    const float* pe_w2, const float* wo,
    const float* bno_g, const float* bno_b, const float* bno_m, const float* bno_v,
    float* out){
  __shared__ __align__(16) float4 smW1[128];      // 2 KB
  __shared__ __align__(16) float4 smP[4][16];     // 1 KB  r-vectors per wave
  __shared__ int   smJ[4][16];                    // 256 B neighbor indices
  __shared__ float smw[4][16][8];                 // 2 KB  weights [k][g]
  __shared__ __align__(16) float smH[4][8][H2S];  // 17.4 KB
  __shared__ __align__(16) float smOutv[4][128];  // 2 KB
  int t = threadIdx.x;
  int wv = t >> 6, lane = t & 63;
  int b  = blockIdx.x >> 11;          // NPTS/4 = 2048 blocks per batch
  int n0 = (blockIdx.x & 2047) * 4;
  if (t < 128) smW1[t] = wsPW1[t];
  __syncthreads();

  int n = n0 + wv;
  int gq = b*NPTS + n;
  int k = lane >> 2, q = lane & 3;

  // ---- phase A (wave-local): logits + softmax weights ----
  {
    float4 pn  = pts[gq];
    float4 eqa = *(const float4*)&eqT[gq*8];
    float4 eqb = *(const float4*)&eqT[gq*8+4];
    int j = idxw[gq*16 + k] & (NPTS-1);
    int gj = b*NPTS + j;
    float4 pj  = pts[gj];
    float4 eka = *(const float4*)&ekT[gj*8];
    float4 ekb = *(const float4*)&ekT[gj*8+4];
    float rx = pj.x - pn.x, ry = pj.y - pn.y, rz = pj.z - pn.z;
    if (q == 0){
      smP[wv][k] = make_float4(rx, ry, rz, 0.f);
      smJ[wv][k] = j;
    }
    // ee added ONCE after the q-lane reduction
    float ee[8] = {eka.x+eqa.x, eka.y+eqa.y, eka.z+eqa.z, eka.w+eqa.w,
                   ekb.x+eqb.x, ekb.y+eqb.y, ekb.z+eqb.z, ekb.w+eqb.w};
    float lp[8] = {0.f,0.f,0.f,0.f,0.f,0.f,0.f,0.f};
    #pragma unroll
    for (int i = 0; i < 8; ++i){
      int hb = 4*q + 16*i;
      float4 w1;
      w1 = smW1[hb+0]; float hv0 = fmaxf(fmaf(w1.x, rx, fmaf(w1.y, ry, fmaf(w1.z, rz, w1.w))), 0.f);
      w1 = smW1[hb+1]; float hv1 = fmaxf(fmaf(w1.x, rx, fmaf(w1.y, ry, fmaf(w1.z, rz, w1.w))), 0.f);
      w1 = smW1[hb+2]; float hv2 = fmaxf(fmaf(w1.x, rx, fmaf(w1.y, ry, fmaf(w1.z, rz, w1.w))), 0.f);
      w1 = smW1[hb+3]; float hv3 = fmaxf(fmaf(w1.x, rx, fmaf(w1.y, ry, fmaf(w1.z, rz, w1.w))), 0.f);
      #pragma unroll
      for (int g = 0; g < 8; ++g){
        float4 a4 = *(const float4*)&wsA[g*128 + hb];
        lp[g] = fmaf(a4.x, hv0, lp[g]);
        lp[g] = fmaf(a4.y, hv1, lp[g]);
        lp[g] = fmaf(a4.z, hv2, lp[g]);
        lp[g] = fmaf(a4.w, hv3, lp[g]);
      }
    }
    #pragma unroll
    for (int g = 0; g < 8; ++g){
      lp[g] += __shfl_xor(lp[g], 1);
      lp[g] += __shfl_xor(lp[g], 2);
      lp[g] = fmaxf(lp[g] + ee[g], 0.f);
    }
    float lo0 = 0.f, lo1 = 0.f;
    #pragma unroll
    for (int g = 0; g < 8; ++g){
      lo0 = fmaf(wsWE2[(2*q+0)*8 + g], lp[g], lo0);
      lo1 = fmaf(wsWE2[(2*q+1)*8 + g], lp[g], lo1);
    }
    float m0 = lo0, m1 = lo1;
    #pragma unroll
    for (int msk = 4; msk <= 32; msk <<= 1){
      m0 = fmaxf(m0, __shfl_xor(m0, msk));
      m1 = fmaxf(m1, __shfl_xor(m1, msk));
    }
    float e0 = __expf(lo0 - m0), e1 = __expf(lo1 - m1);
    float s0 = e0, s1 = e1;
    #pragma unroll
    for (int msk = 4; msk <= 32; msk <<= 1){
      s0 += __shfl_xor(s0, msk);
      s1 += __shfl_xor(s1, msk);
    }
    smw[wv][k][2*q+0] = e0 / s0;
    smw[wv][k][2*q+1] = e1 / s1;
  }

  // ---- phase C (wave-local): H[g][h] = sum_k w[g,k]*relu(W1[h].r_k) ----
  {
    int g3 = lane >> 3, hh = lane & 7;
    float4 H4[4];
    #pragma unroll
    for (int ii = 0; ii < 4; ++ii) H4[ii] = make_float4(0.f,0.f,0.f,0.f);
    for (int kk = 0; kk < 16; ++kk){
      float4 r4 = smP[wv][kk];
      float wg  = smw[wv][kk][g3];
      #pragma unroll
      for (int ii = 0; ii < 4; ++ii){
        int hb = 4*hh + 32*ii;
        float4 w1;
        w1 = smW1[hb+0]; float hv0 = fmaxf(fmaf(w1.x, r4.x, fmaf(w1.y, r4.y, fmaf(w1.z, r4.z, w1.w))), 0.f);
        w1 = smW1[hb+1]; float hv1 = fmaxf(fmaf(w1.x, r4.x, fmaf(w1.y, r4.y, fmaf(w1.z, r4.z, w1.w))), 0.f);
        w1 = smW1[hb+2]; float hv2 = fmaxf(fmaf(w1.x, r4.x, fmaf(w1.y, r4.y, fmaf(w1.z, r4.z, w1.w))), 0.f);
        w1 = smW1[hb+3]; float hv3 = fmaxf(fmaf(w1.x, r4.x, fmaf(w1.y, r4.y, fmaf(w1.z, r4.z, w1.w))), 0.f);
        H4[ii].x = fmaf(wg, hv0, H4[ii].x);
        H4[ii].y = fmaf(wg, hv1, H4[ii].y);
        H4[ii].z = fmaf(wg, hv2, H4[ii].z);
        H4[ii].w = fmaf(wg, hv3, H4[ii].w);
      }
    }
    #pragma unroll
    for (int ii = 0; ii < 4; ++ii)
      *(float4*)&smH[wv][g3][4*hh + 32*ii] = H4[ii];
  }
  __syncthreads();   // all waves' smH/smw/smJ visible block-wide

  // ---- phase D (block-wide, t<128): outv for all 4 points; pe_w2 rows read once ----
  if (t < 128){
    int c = t, g = c >> 4;
    float acc[4] = {0.f, 0.f, 0.f, 0.f};
    for (int i = 0; i < 32; ++i){
      float4 pw = *(const float4*)&pe_w2[c*128 + 4*i];
      #pragma unroll
      for (int pt = 0; pt < 4; ++pt){
        float4 h4 = *(const float4*)&smH[pt][g][4*i];
        acc[pt] = fmaf(pw.x, h4.x, acc[pt]);
        acc[pt] = fmaf(pw.y, h4.y, acc[pt]);
        acc[pt] = fmaf(pw.z, h4.z, acc[pt]);
        acc[pt] = fmaf(pw.w, h4.w, acc[pt]);
      }
    }
    #pragma unroll
    for (int pt = 0; pt < 4; ++pt){
      #pragma unroll
      for (int kk = 0; kk < 16; ++kk){
        int jj = smJ[pt][kk];
        float wgk = smw[pt][kk][g];
        acc[pt] = fmaf(wgk, vfT[((size_t)b*NPTS + jj)*CH + c], acc[pt]);
      }
      smOutv[pt][c] = acc[pt];
    }
  }
  __syncthreads();

  // ---- phase E (t<128): out[o][n0..n0+3] = bno(wo @ outv), float4 store ----
  if (t < 128){
    int o = t;
    float so = bno_g[o] / sqrtf(bno_v[o] + EPSN);
    float bo = bno_b[o] - bno_m[o] * so;
    float fa[4] = {0.f, 0.f, 0.f, 0.f};
    for (int i = 0; i < 32; ++i){
      float4 pw = *(const float4*)&wo[o*128 + 4*i];
      #pragma unroll
      for (int pt = 0; pt < 4; ++pt){
        float4 h4 = *(const float4*)&smOutv[pt][4*i];
        fa[pt] = fmaf(pw.x, h4.x, fa[pt]);
        fa[pt] = fmaf(pw.y, h4.y, fa[pt]);
        fa[pt] = fmaf(pw.z, h4.z, fa[pt]);
        fa[pt] = fmaf(pw.w, h4.w, fa[pt]);
      }
    }
    float4 st;
    st.x = fmaf(so, fa[0], bo);
    st.y = fmaf(so, fa[1], bo);
    st.z = fmaf(so, fa[2], bo);
    st.w = fmaf(so, fa[3], bo);
    *(float4*)&out[((size_t)b*CH + o)*NPTS + n0] = st;
  }
}

extern "C" void kernel_launch(void* const* d_in, const int* in_sizes, int n_in,
                              void* d_out, int out_size, void* d_ws, size_t ws_size,
                              hipStream_t stream){
  const float* x     = (const float*)d_in[0];
  const float* xyz   = (const float*)d_in[1];
  const float* wq    = (const float*)d_in[2];
  const float* bnq_g = (const float*)d_in[3];
  const float* bnq_b = (const float*)d_in[4];
  const float* bnq_m = (const float*)d_in[5];
  const float* bnq_v = (const float*)d_in[6];
  const float* wk    = (const float*)d_in[7];
  const float* bnk_g = (const float*)d_in[8];
  const float* bnk_b = (const float*)d_in[9];
  const float* bnk_m = (const float*)d_in[10];
  const float* bnk_v = (const float*)d_in[11];
  const float* wv    = (const float*)d_in[12];
  const float* pe_w1 = (const float*)d_in[13];
  const float* pe_g  = (const float*)d_in[14];
  const float* pe_b  = (const float*)d_in[15];
  const float* pe_m  = (const float*)d_in[16];
  const float* pe_v  = (const float*)d_in[17];
  const float* pe_w2 = (const float*)d_in[18];
  const float* we_w1 = (const float*)d_in[19];
  const float* we_g  = (const float*)d_in[20];
  const float* we_b  = (const float*)d_in[21];
  const float* we_m  = (const float*)d_in[22];
  const float* we_v  = (const float*)d_in[23];
  const float* we_w2 = (const float*)d_in[24];
  const float* wo    = (const float*)d_in[25];
  const float* bno_g = (const float*)d_in[26];
  const float* bno_b = (const float*)d_in[27];
  const float* bno_m = (const float*)d_in[28];
  const float* bno_v = (const float*)d_in[29];

  char* ws = (char*)d_ws;
  float*  wsA   = (float*)(ws + WS_A);
  float4* wsPW1 = (float4*)(ws + WS_PW1);
  float*  wsWE2 = (float*)(ws + WS_WE2);
  float4* pts   = (float4*)(ws + WS_PTS);
  float*  eqT   = (float*)(ws + WS_EQ);
  float*  ekT   = (float*)(ws + WS_EK);
  int*    idxw  = (int*)(ws + WS_IDX);
  float*  vfT   = (float*)(ws + WS_VFT);
  float*  outp  = (float*)d_out;

  k0_precomp<<<dim3(1), dim3(256), 0, stream>>>(we_w1, pe_w2, pe_w1, we_g, we_v,
                                                pe_g, pe_b, pe_m, pe_v, we_w2,
                                                wsA, wsPW1, wsWE2);
  k1_pts<<<dim3(64), dim3(256), 0, stream>>>(xyz, pts);
  k2_proj<<<dim3(BATCH*(NPTS/K2PTS)*3), dim3(256), 0, stream>>>(x, wq, wk, wv,
                                               bnq_g, bnq_b, bnq_m, bnq_v,
                                               bnk_g, bnk_b, bnk_m, bnk_v,
                                               we_w1, we_g, we_b, we_m, we_v,
                                               eqT, ekT, vfT);
  k3_knn<<<dim3(BATCH*(NPTS/QPB)), dim3(256), 0, stream>>>(pts, idxw);
  k4_attn<<<dim3(BATCH*(NPTS/4)), dim3(256), 0, stream>>>(pts, eqT, ekT, idxw, vfT,
                                                wsA, wsPW1, wsWE2, pe_w2, wo,
                                                bno_g, bno_b, bno_m, bno_v, outp);
}

// Round 12
// 361.189 us; speedup vs baseline: 2.6792x; 1.0247x over previous
//
#include <hip/hip_runtime.h>
#include <math.h>

typedef unsigned int u32;
typedef unsigned long long u64;

#define BATCH 2
#define CH 128
#define NPTS 8192
#define KNB 16
#define GRP 8
#define EPSN 1e-5f

// ---- workspace layout (bytes), total ~10.8 MB ----
#define WS_A     0           // 8*128 f32   A' = s_g * (we_w1 @ pe_w2)
#define WS_PW1   4096        // 128 float4  folded pe_w1 + pe_bn (sx,sy,sz,bias)
#define WS_WE2   6144        // 64 f32      we_w2
#define WS_PTS   8192        // 16384 float4 {x,y,z,|p|^2}
#define WS_EQ    270336      // B*N*8 f32   t_g - s_g*eq
#define WS_EK    794624      // B*N*8 f32   s_g*ek
#define WS_IDX   1318912     // B*N*16 int
#define WS_VFT   2367488     // B*N*128 f32 v transposed (point-major)

__device__ __forceinline__ float d2f(float4 a, float4 b){
  #pragma clang fp contract(off)
  float dot = a.x*b.x + a.y*b.y + a.z*b.z;
  return (a.w + b.w) - 2.0f*dot;
}
__device__ __forceinline__ u64 shfl_xor_u64(u64 v, int m){
  int lo = __shfl_xor((int)(u32)v, m);
  int hi = __shfl_xor((int)(u32)(v >> 32), m);
  return (((u64)(u32)hi) << 32) | (u32)lo;
}
__device__ __forceinline__ int mbcnt64(u64 bm){
  return (int)__builtin_amdgcn_mbcnt_hi((u32)(bm >> 32),
          __builtin_amdgcn_mbcnt_lo((u32)(bm & 0xFFFFFFFFull), 0u));
}
__device__ __forceinline__ u32 mono32(float d2){
  u32 db = __float_as_uint(d2);
  return (db & 0x80000000u) ? ~db : (db | 0x80000000u);  // monotone float->uint
}

// ---------------- K0: tiny precompute ----------------
__global__ __launch_bounds__(256) void k0_precomp(
    const float* we_w1, const float* pe_w2, const float* pe_w1,
    const float* we_g, const float* we_v,
    const float* pe_g, const float* pe_b, const float* pe_m, const float* pe_v,
    const float* we_w2, float* wsA, float4* wsPW1, float* wsWE2){
  int t = threadIdx.x;
  for (int i = t; i < 1024; i += 256){
    int g = i >> 7, h = i & 127;
    float s = 0.f;
    for (int c = 0; c < 128; ++c) s = fmaf(we_w1[g*128+c], pe_w2[c*128+h], s);
    float sg = we_g[g] / sqrtf(we_v[g] + EPSN);
    wsA[i] = s * sg;
  }
  if (t < 128){
    float s = pe_g[t] / sqrtf(pe_v[t] + EPSN);
    float bb = pe_b[t] - pe_m[t] * s;
    wsPW1[t] = make_float4(s*pe_w1[t*3+0], s*pe_w1[t*3+1], s*pe_w1[t*3+2], bb);
  }
  if (t < 64) wsWE2[t] = we_w2[t];
}

// ---------------- K1: points + squared norms ----------------
__global__ __launch_bounds__(256) void k1_pts(const float* xyz, float4* pts){
  int id = blockIdx.x*256 + threadIdx.x;
  if (id >= BATCH*NPTS) return;
  int b = id >> 13, n = id & (NPTS-1);
  float x = xyz[(b*3+0)*NPTS + n];
  float y = xyz[(b*3+1)*NPTS + n];
  float z = xyz[(b*3+2)*NPTS + n];
  float sq;
  {
    #pragma clang fp contract(off)
    sq = (x*x + y*y) + z*z;
  }
  pts[id] = make_float4(x, y, z, sq);
}

// ---------------- K2: projections, mat-split grid, 32-pt tiles ----------------
#define K2PTS 32
__global__ __launch_bounds__(256) void k2_proj(
    const float* x, const float* wq, const float* wk, const float* wv,
    const float* bnq_g, const float* bnq_b, const float* bnq_m, const float* bnq_v,
    const float* bnk_g, const float* bnk_b, const float* bnk_m, const float* bnk_v,
    const float* we_w1,
    const float* we_g, const float* we_b, const float* we_m, const float* we_v,
    float* eqT, float* ekT, float* vfT){
  __shared__ __align__(16) float qk2[K2PTS][129];  // [point][channel], 16.5 KB
  __shared__ float bnS[128], bnB[128];
  int t = threadIdx.x;
  int mat = blockIdx.x % 3;
  int tmp = blockIdx.x / 3;
  int b   = tmp / (NPTS/K2PTS);
  int n0  = (tmp % (NPTS/K2PTS)) * K2PTS;
  int p = t & 31, og = t >> 5;          // og in 0..7, 16 output channels each
  const float* xp = x + (size_t)b*CH*NPTS + n0 + p;
  const float* W = (mat == 0) ? wq : ((mat == 1) ? wk : wv);
  if (mat < 2 && t < 128){
    const float* g_ = mat==0 ? bnq_g : bnk_g;
    const float* b_ = mat==0 ? bnq_b : bnk_b;
    const float* m_ = mat==0 ? bnq_m : bnk_m;
    const float* v_ = mat==0 ? bnq_v : bnk_v;
    float s = g_[t] / sqrtf(v_[t] + EPSN);
    bnS[t] = s;
    bnB[t] = b_[t] - m_[t] * s;
  }
  __syncthreads();
  float acc[16];
  #pragma unroll
  for (int ii = 0; ii < 16; ++ii) acc[ii] = 0.f;
  for (int dd = 0; dd < 32; ++dd){
    float x0 = xp[(size_t)(4*dd+0)*NPTS];
    float x1 = xp[(size_t)(4*dd+1)*NPTS];
    float x2 = xp[(size_t)(4*dd+2)*NPTS];
    float x3 = xp[(size_t)(4*dd+3)*NPTS];
    #pragma unroll
    for (int ii = 0; ii < 16; ++ii){
      int o = og*16 + ii;
      float4 wu = *(const float4*)&W[o*128 + 4*dd];
      acc[ii] = fmaf(wu.x, x0, acc[ii]);
      acc[ii] = fmaf(wu.y, x1, acc[ii]);
      acc[ii] = fmaf(wu.z, x2, acc[ii]);
      acc[ii] = fmaf(wu.w, x3, acc[ii]);
    }
  }
  #pragma unroll
  for (int ii = 0; ii < 16; ++ii){
    int o = og*16 + ii;
    float v = acc[ii];
    if (mat < 2) v = fmaxf(fmaf(bnS[o], v, bnB[o]), 0.f);
    qk2[p][o] = v;
  }
  __syncthreads();
  if (mat < 2){
    int g = t >> 5, pp = t & 31;
    float sg = we_g[g] / sqrtf(we_v[g] + EPSN);
    float tg = we_b[g] - we_m[g] * sg;
    float s = 0.f;
    for (int c4 = 0; c4 < 32; ++c4){
      float4 wv4 = *(const float4*)&we_w1[g*128 + 4*c4];
      float4 qv4 = *(const float4*)&qk2[pp][4*c4];
      s = fmaf(wv4.x, qv4.x, s);
      s = fmaf(wv4.y, qv4.y, s);
      s = fmaf(wv4.z, qv4.z, s);
      s = fmaf(wv4.w, qv4.w, s);
    }
    float val = (mat == 0) ? (tg - sg*s) : (sg*s);
    float* dst = (mat == 0) ? eqT : ekT;
    dst[(b*NPTS + n0 + pp)*8 + g] = val;
  } else {
    #pragma unroll
    for (int i = 0; i < 4; ++i){
      int f = t + 256*i;        // 0..1023 float4 units (32 pts x 32 float4)
      int pp = f >> 5, c4 = (f & 31)*4;
      float4 v = *(const float4*)&qk2[pp][c4];
      *(float4*)&vfT[((size_t)b*NPTS + n0 + pp)*CH + c4] = v;
    }
  }
}

// ---------------- K3: exact KNN, lane-min sampled threshold, reg-extraction ----------------
// T(q) = 16th-smallest of the 64 lane-minima (each lane: min over its 16 of the
// first 1024 candidates). Guarantee: pops are nondecreasing and remove >=1
// distinct lane (= distinct sampled point) per round -> >=16 full-set members
// <= T -> cnt >= 16 ALWAYS. E[cnt] = 8192*16/1024 = 128; CAPQ=288 (~3sigma)
// makes overflow-retry tails negligible (bisection kept as fallback).
#define QW   2     // queries per wave
#define QPB  8     // queries per block (4 waves x 2)
#define CAPQ 288   // candidate slots per query
__global__ __launch_bounds__(256) void k3_knn(const float4* pts, int* idxout){
  __shared__ u64 smBuf[4][QW][CAPQ];   // 18 KB, rows private per wave
  int t = threadIdx.x;
  int wv = t >> 6, lane = t & 63;
  int b  = blockIdx.x / (NPTS/QPB);
  int q0 = (blockIdx.x % (NPTS/QPB)) * QPB + wv*QW;
  const float4* P = pts + b*NPTS;

  // clear wave-private rows (give-up-path safety); QW*CAPQ/64 = 9 slots/lane
  #pragma unroll
  for (int s = 0; s < QW*CAPQ/64; ++s){
    int f = s*64 + lane;
    smBuf[wv][f / CAPQ][f % CAPQ] = ~0ull;
  }

  float4 qp[QW];
  #pragma unroll
  for (int i = 0; i < QW; ++i) qp[i] = P[q0 + i];

  // ---- sample phase: lane-min over 16 samples, then 16 wave-min pops ----
  float T[QW];
  #pragma unroll
  for (int i = 0; i < QW; ++i){
    float v = 3.402823466e38f;
    #pragma unroll
    for (int j = 0; j < 16; ++j){
      float4 c = P[lane + 64*j];
      v = fminf(v, d2f(qp[i], c));
    }
    float Tq = v;
    #pragma unroll
    for (int r = 0; r < 16; ++r){
      float m = v;
      #pragma unroll
      for (int msk = 1; msk <= 32; msk <<= 1) m = fminf(m, __shfl_xor(m, msk));
      if (v == m) v = 3.402823466e38f;   // pop all lanes at the min (bias up = safe)
      Tq = m;
    }
    T[i] = Tq;
  }

  // ---- collect sweeps: cnt>=16 guaranteed at initial T; bisect on overflow ----
  float Tlo[QW], Thi[QW]; int cnt[QW];
  #pragma unroll
  for (int i = 0; i < QW; ++i){ Tlo[i] = -3.0e38f; Thi[i] = 3.0e38f; cnt[i] = 0; }
  auto step = [&](float4 c, u32 m, int i){
    float d2 = d2f(qp[i], c);
    bool pred = d2 <= T[i];
    u64 bm = __ballot(pred);
    if (bm){                              // wave-uniform skip of empty groups
      int cc = __popcll(bm);
      if (pred && cnt[i] + cc <= CAPQ){
        int pos = cnt[i] + mbcnt64(bm);
        smBuf[wv][i][pos] = (((u64)mono32(d2)) << 32) | m;
      }
      cnt[i] += cc;
    }
  };
  bool anybad = true;
  for (int att = 0; att < 16 && anybad; ++att){
    #pragma unroll
    for (int i = 0; i < QW; ++i) cnt[i] = 0;
    for (int base = 0; base < NPTS; base += 256){
      float4 c0 = P[base       + lane];
      float4 c1 = P[base +  64 + lane];
      float4 c2 = P[base + 128 + lane];
      float4 c3 = P[base + 192 + lane];
      #pragma unroll
      for (int i = 0; i < QW; ++i){
        step(c0, (u32)(base       + lane), i);
        step(c1, (u32)(base +  64 + lane), i);
        step(c2, (u32)(base + 128 + lane), i);
        step(c3, (u32)(base + 192 + lane), i);
      }
    }
    anybad = false;
    #pragma unroll
    for (int i = 0; i < QW; ++i){
      if (cnt[i] > CAPQ){
        Thi[i] = T[i];
        T[i] = (Tlo[i] > -3.0e38f) ? 0.5f*(Tlo[i] + Thi[i])
                                   : ((T[i] > 0.f) ? T[i]*0.5f : T[i]*2.0f - 1.0f);
        anybad = true;
      } else if (cnt[i] < 16){   // only reachable after an overflow-shrink
        Tlo[i] = T[i];
        T[i] = 0.5f*(Tlo[i] + Thi[i]);
        anybad = true;
      }
    }
  }

  // ---- extraction: register-resident 16-min pops (keys unique via idx bits) ----
  for (int i = 0; i < QW; ++i){
    int cq = cnt[i] < CAPQ ? cnt[i] : CAPQ;
    int n = q0 + i;
    u64 v0 = (lane       < cq) ? smBuf[wv][i][lane      ] : ~0ull;
    u64 v1 = (lane +  64 < cq) ? smBuf[wv][i][lane +  64] : ~0ull;
    u64 v2 = (lane + 128 < cq) ? smBuf[wv][i][lane + 128] : ~0ull;
    u64 v3 = (lane + 192 < cq) ? smBuf[wv][i][lane + 192] : ~0ull;
    u64 v4 = (lane + 256 < cq) ? smBuf[wv][i][lane + 256] : ~0ull;
    // bubble network, ascending (v0 smallest)
    #define CE_(x,y) { if (y < x){ u64 tm_ = x; x = y; y = tm_; } }
    CE_(v0,v1) CE_(v1,v2) CE_(v2,v3) CE_(v3,v4)
    CE_(v0,v1) CE_(v1,v2) CE_(v2,v3)
    CE_(v0,v1) CE_(v1,v2)
    CE_(v0,v1)
    #undef CE_
    #pragma unroll
    for (int r = 0; r < 16; ++r){
      u64 gm = v0;
      #pragma unroll
      for (int msk = 1; msk <= 32; msk <<= 1){
        u64 o = shfl_xor_u64(gm, msk);
        gm = (o < gm) ? o : gm;
      }
      if (v0 == gm){ v0 = v1; v1 = v2; v2 = v3; v3 = v4; v4 = ~0ull; }
      if (lane == 0){
        int sel = (gm == ~0ull) ? n : (int)(gm & (u32)(NPTS-1));
        idxout[(b*NPTS + n)*16 + r] = sel;
      }
    }
  }
}

// ---------------- K4: fused attention, 1 wave/point, low-LDS ----------------
#define H2S 136
__global__ __launch_bounds__(256) void k4_attn(
    const float4* pts, const float* eqT, const float* ekT, const int* idxw,
    const float* vfT, const float* wsA, const float4* wsPW1, const float* wsWE2,
    const float* pe_w2, const float* wo,
    const float* bno_g, const float* bno_b, const float* bno_m, const float* bno_v,
    float* out){
  __shared__ __align__(16) float4 smW1[128];      // 2 KB
  __shared__ __align__(16) float4 smP[4][16];     // 1 KB  r-vectors per wave
  __shared__ int   smJ[4][16];                    // 256 B neighbor indices
  __shared__ float smw[4][16][8];                 // 2 KB  weights [k][g]
  __shared__ __align__(16) float smH[4][8][H2S];  // 17.4 KB
  __shared__ __align__(16) float smOutv[4][128];  // 2 KB
  int t = threadIdx.x;
  int wv = t >> 6, lane = t & 63;
  int b  = blockIdx.x >> 11;          // NPTS/4 = 2048 blocks per batch
  int n0 = (blockIdx.x & 2047) * 4;
  if (t < 128) smW1[t] = wsPW1[t];
  __syncthreads();

  int n = n0 + wv;
  int gq = b*NPTS + n;
  int k = lane >> 2, q = lane & 3;

  // ---- phase A (wave-local): logits + softmax weights ----
  {
    float4 pn  = pts[gq];
    float4 eqa = *(const float4*)&eqT[gq*8];
    float4 eqb = *(const float4*)&eqT[gq*8+4];
    int j = idxw[gq*16 + k] & (NPTS-1);
    int gj = b*NPTS + j;
    float4 pj  = pts[gj];
    float4 eka = *(const float4*)&ekT[gj*8];
    float4 ekb = *(const float4*)&ekT[gj*8+4];
    float rx = pj.x - pn.x, ry = pj.y - pn.y, rz = pj.z - pn.z;
    if (q == 0){
      smP[wv][k] = make_float4(rx, ry, rz, 0.f);
      smJ[wv][k] = j;
    }
    // ee added ONCE after the q-lane reduction
    float ee[8] = {eka.x+eqa.x, eka.y+eqa.y, eka.z+eqa.z, eka.w+eqa.w,
                   ekb.x+eqb.x, ekb.y+eqb.y, ekb.z+eqb.z, ekb.w+eqb.w};
    float lp[8] = {0.f,0.f,0.f,0.f,0.f,0.f,0.f,0.f};
    #pragma unroll
    for (int i = 0; i < 8; ++i){
      int hb = 4*q + 16*i;
      float4 w1;
      w1 = smW1[hb+0]; float hv0 = fmaxf(fmaf(w1.x, rx, fmaf(w1.y, ry, fmaf(w1.z, rz, w1.w))), 0.f);
      w1 = smW1[hb+1]; float hv1 = fmaxf(fmaf(w1.x, rx, fmaf(w1.y, ry, fmaf(w1.z, rz, w1.w))), 0.f);
      w1 = smW1[hb+2]; float hv2 = fmaxf(fmaf(w1.x, rx, fmaf(w1.y, ry, fmaf(w1.z, rz, w1.w))), 0.f);
      w1 = smW1[hb+3]; float hv3 = fmaxf(fmaf(w1.x, rx, fmaf(w1.y, ry, fmaf(w1.z, rz, w1.w))), 0.f);
      #pragma unroll
      for (int g = 0; g < 8; ++g){
        float4 a4 = *(const float4*)&wsA[g*128 + hb];
        lp[g] = fmaf(a4.x, hv0, lp[g]);
        lp[g] = fmaf(a4.y, hv1, lp[g]);
        lp[g] = fmaf(a4.z, hv2, lp[g]);
        lp[g] = fmaf(a4.w, hv3, lp[g]);
      }
    }
    #pragma unroll
    for (int g = 0; g < 8; ++g){
      lp[g] += __shfl_xor(lp[g], 1);
      lp[g] += __shfl_xor(lp[g], 2);
      lp[g] = fmaxf(lp[g] + ee[g], 0.f);
    }
    float lo0 = 0.f, lo1 = 0.f;
    #pragma unroll
    for (int g = 0; g < 8; ++g){
      lo0 = fmaf(wsWE2[(2*q+0)*8 + g], lp[g], lo0);
      lo1 = fmaf(wsWE2[(2*q+1)*8 + g], lp[g], lo1);
    }
    float m0 = lo0, m1 = lo1;
    #pragma unroll
    for (int msk = 4; msk <= 32; msk <<= 1){
      m0 = fmaxf(m0, __shfl_xor(m0, msk));
      m1 = fmaxf(m1, __shfl_xor(m1, msk));
    }
    float e0 = __expf(lo0 - m0), e1 = __expf(lo1 - m1);
    float s0 = e0, s1 = e1;
    #pragma unroll
    for (int msk = 4; msk <= 32; msk <<= 1){
      s0 += __shfl_xor(s0, msk);
      s1 += __shfl_xor(s1, msk);
    }
    smw[wv][k][2*q+0] = e0 / s0;
    smw[wv][k][2*q+1] = e1 / s1;
  }

  // ---- phase C (wave-local): H[g][h] = sum_k w[g,k]*relu(W1[h].r_k) ----
  {
    int g3 = lane >> 3, hh = lane & 7;
    float4 H4[4];
    #pragma unroll
    for (int ii = 0; ii < 4; ++ii) H4[ii] = make_float4(0.f,0.f,0.f,0.f);
    for (int kk = 0; kk < 16; ++kk){
      float4 r4 = smP[wv][kk];
      float wg  = smw[wv][kk][g3];
      #pragma unroll
      for (int ii = 0; ii < 4; ++ii){
        int hb = 4*hh + 32*ii;
        float4 w1;
        w1 = smW1[hb+0]; float hv0 = fmaxf(fmaf(w1.x, r4.x, fmaf(w1.y, r4.y, fmaf(w1.z, r4.z, w1.w))), 0.f);
        w1 = smW1[hb+1]; float hv1 = fmaxf(fmaf(w1.x, r4.x, fmaf(w1.y, r4.y, fmaf(w1.z, r4.z, w1.w))), 0.f);
        w1 = smW1[hb+2]; float hv2 = fmaxf(fmaf(w1.x, r4.x, fmaf(w1.y, r4.y, fmaf(w1.z, r4.z, w1.w))), 0.f);
        w1 = smW1[hb+3]; float hv3 = fmaxf(fmaf(w1.x, r4.x, fmaf(w1.y, r4.y, fmaf(w1.z, r4.z, w1.w))), 0.f);
        H4[ii].x = fmaf(wg, hv0, H4[ii].x);
        H4[ii].y = fmaf(wg, hv1, H4[ii].y);
        H4[ii].z = fmaf(wg, hv2, H4[ii].z);
        H4[ii].w = fmaf(wg, hv3, H4[ii].w);
      }
    }
    #pragma unroll
    for (int ii = 0; ii < 4; ++ii)
      *(float4*)&smH[wv][g3][4*hh + 32*ii] = H4[ii];
  }
  __syncthreads();   // all waves' smH/smw/smJ visible block-wide

  // ---- phase D (block-wide, t<128): outv for all 4 points; pe_w2 rows read once ----
  if (t < 128){
    int c = t, g = c >> 4;
    float acc[4] = {0.f, 0.f, 0.f, 0.f};
    for (int i = 0; i < 32; ++i){
      float4 pw = *(const float4*)&pe_w2[c*128 + 4*i];
      #pragma unroll
      for (int pt = 0; pt < 4; ++pt){
        float4 h4 = *(const float4*)&smH[pt][g][4*i];
        acc[pt] = fmaf(pw.x, h4.x, acc[pt]);
        acc[pt] = fmaf(pw.y, h4.y, acc[pt]);
        acc[pt] = fmaf(pw.z, h4.z, acc[pt]);
        acc[pt] = fmaf(pw.w, h4.w, acc[pt]);
      }
    }
    #pragma unroll
    for (int pt = 0; pt < 4; ++pt){
      #pragma unroll
      for (int kk = 0; kk < 16; ++kk){
        int jj = smJ[pt][kk];
        float wgk = smw[pt][kk][g];
        acc[pt] = fmaf(wgk, vfT[((size_t)b*NPTS + jj)*CH + c], acc[pt]);
      }
      smOutv[pt][c] = acc[pt];
    }
  }
  __syncthreads();

  // ---- phase E (t<128): out[o][n0..n0+3] = bno(wo @ outv), float4 store ----
  if (t < 128){
    int o = t;
    float so = bno_g[o] / sqrtf(bno_v[o] + EPSN);
    float bo = bno_b[o] - bno_m[o] * so;
    float fa[4] = {0.f, 0.f, 0.f, 0.f};
    for (int i = 0; i < 32; ++i){
      float4 pw = *(const float4*)&wo[o*128 + 4*i];
      #pragma unroll
      for (int pt = 0; pt < 4; ++pt){
        float4 h4 = *(const float4*)&smOutv[pt][4*i];
        fa[pt] = fmaf(pw.x, h4.x, fa[pt]);
        fa[pt] = fmaf(pw.y, h4.y, fa[pt]);
        fa[pt] = fmaf(pw.z, h4.z, fa[pt]);
        fa[pt] = fmaf(pw.w, h4.w, fa[pt]);
      }
    }
    float4 st;
    st.x = fmaf(so, fa[0], bo);
    st.y = fmaf(so, fa[1], bo);
    st.z = fmaf(so, fa[2], bo);
    st.w = fmaf(so, fa[3], bo);
    *(float4*)&out[((size_t)b*CH + o)*NPTS + n0] = st;
  }
}

extern "C" void kernel_launch(void* const* d_in, const int* in_sizes, int n_in,
                              void* d_out, int out_size, void* d_ws, size_t ws_size,
                              hipStream_t stream){
  const float* x     = (const float*)d_in[0];
  const float* xyz   = (const float*)d_in[1];
  const float* wq    = (const float*)d_in[2];
  const float* bnq_g = (const float*)d_in[3];
  const float* bnq_b = (const float*)d_in[4];
  const float* bnq_m = (const float*)d_in[5];
  const float* bnq_v = (const float*)d_in[6];
  const float* wk    = (const float*)d_in[7];
  const float* bnk_g = (const float*)d_in[8];
  const float* bnk_b = (const float*)d_in[9];
  const float* bnk_m = (const float*)d_in[10];
  const float* bnk_v = (const float*)d_in[11];
  const float* wv    = (const float*)d_in[12];
  const float* pe_w1 = (const float*)d_in[13];
  const float* pe_g  = (const float*)d_in[14];
  const float* pe_b  = (const float*)d_in[15];
  const float* pe_m  = (const float*)d_in[16];
  const float* pe_v  = (const float*)d_in[17];
  const float* pe_w2 = (const float*)d_in[18];
  const float* we_w1 = (const float*)d_in[19];
  const float* we_g  = (const float*)d_in[20];
  const float* we_b  = (const float*)d_in[21];
  const float* we_m  = (const float*)d_in[22];
  const float* we_v  = (const float*)d_in[23];
  const float* we_w2 = (const float*)d_in[24];
  const float* wo    = (const float*)d_in[25];
  const float* bno_g = (const float*)d_in[26];
  const float* bno_b = (const float*)d_in[27];
  const float* bno_m = (const float*)d_in[28];
  const float* bno_v = (const float*)d_in[29];

  char* ws = (char*)d_ws;
  float*  wsA   = (float*)(ws + WS_A);
  float4* wsPW1 = (float4*)(ws + WS_PW1);
  float*  wsWE2 = (float*)(ws + WS_WE2);
  float4* pts   = (float4*)(ws + WS_PTS);
  float*  eqT   = (float*)(ws + WS_EQ);
  float*  ekT   = (float*)(ws + WS_EK);
  int*    idxw  = (int*)(ws + WS_IDX);
  float*  vfT   = (float*)(ws + WS_VFT);
  float*  outp  = (float*)d_out;

  k0_precomp<<<dim3(1), dim3(256), 0, stream>>>(we_w1, pe_w2, pe_w1, we_g, we_v,
                                                pe_g, pe_b, pe_m, pe_v, we_w2,
                                                wsA, wsPW1, wsWE2);
  k1_pts<<<dim3(64), dim3(256), 0, stream>>>(xyz, pts);
  k2_proj<<<dim3(BATCH*(NPTS/K2PTS)*3), dim3(256), 0, stream>>>(x, wq, wk, wv,
                                               bnq_g, bnq_b, bnq_m, bnq_v,
                                               bnk_g, bnk_b, bnk_m, bnk_v,
                                               we_w1, we_g, we_b, we_m, we_v,
                                               eqT, ekT, vfT);
  k3_knn<<<dim3(BATCH*(NPTS/QPB)), dim3(256), 0, stream>>>(pts, idxw);
  k4_attn<<<dim3(BATCH*(NPTS/4)), dim3(256), 0, stream>>>(pts, eqT, ekT, idxw, vfT,
                                                wsA, wsPW1, wsWE2, pe_w2, wo,
                                                bno_g, bno_b, bno_m, bno_v, outp);
}

// Round 13
// 354.626 us; speedup vs baseline: 2.7288x; 1.0185x over previous
//
#include <hip/hip_runtime.h>
#include <math.h>

typedef unsigned int u32;
typedef unsigned long long u64;

#define BATCH 2
#define CH 128
#define NPTS 8192
#define KNB 16
#define GRP 8
#define EPSN 1e-5f

// ---- workspace layout (bytes), total ~10.8 MB ----
#define WS_A     0           // 8*128 f32   A' = s_g * (we_w1 @ pe_w2)
#define WS_PW1   4096        // 128 float4  folded pe_w1 + pe_bn (sx,sy,sz,bias)
#define WS_WE2   6144        // 64 f32      we_w2
#define WS_PTS   8192        // 16384 float4 {x,y,z,|p|^2}
#define WS_EQ    270336      // B*N*8 f32   t_g - s_g*eq
#define WS_EK    794624      // B*N*8 f32   s_g*ek
#define WS_IDX   1318912     // B*N*16 int
#define WS_VFT   2367488     // B*N*128 f32 v transposed (point-major)

__device__ __forceinline__ float d2f(float4 a, float4 b){
  #pragma clang fp contract(off)
  float dot = a.x*b.x + a.y*b.y + a.z*b.z;
  return (a.w + b.w) - 2.0f*dot;
}
__device__ __forceinline__ u64 shfl_xor_u64(u64 v, int m){
  int lo = __shfl_xor((int)(u32)v, m);
  int hi = __shfl_xor((int)(u32)(v >> 32), m);
  return (((u64)(u32)hi) << 32) | (u32)lo;
}
__device__ __forceinline__ int mbcnt64(u64 bm){
  return (int)__builtin_amdgcn_mbcnt_hi((u32)(bm >> 32),
          __builtin_amdgcn_mbcnt_lo((u32)(bm & 0xFFFFFFFFull), 0u));
}
__device__ __forceinline__ u32 mono32(float d2){
  u32 db = __float_as_uint(d2);
  return (db & 0x80000000u) ? ~db : (db | 0x80000000u);  // monotone float->uint
}

// ---------------- K0: tiny precompute ----------------
__global__ __launch_bounds__(256) void k0_precomp(
    const float* we_w1, const float* pe_w2, const float* pe_w1,
    const float* we_g, const float* we_v,
    const float* pe_g, const float* pe_b, const float* pe_m, const float* pe_v,
    const float* we_w2, float* wsA, float4* wsPW1, float* wsWE2){
  int t = threadIdx.x;
  for (int i = t; i < 1024; i += 256){
    int g = i >> 7, h = i & 127;
    float s = 0.f;
    for (int c = 0; c < 128; ++c) s = fmaf(we_w1[g*128+c], pe_w2[c*128+h], s);
    float sg = we_g[g] / sqrtf(we_v[g] + EPSN);
    wsA[i] = s * sg;
  }
  if (t < 128){
    float s = pe_g[t] / sqrtf(pe_v[t] + EPSN);
    float bb = pe_b[t] - pe_m[t] * s;
    wsPW1[t] = make_float4(s*pe_w1[t*3+0], s*pe_w1[t*3+1], s*pe_w1[t*3+2], bb);
  }
  if (t < 64) wsWE2[t] = we_w2[t];
}

// ---------------- K1: points + squared norms ----------------
__global__ __launch_bounds__(256) void k1_pts(const float* xyz, float4* pts){
  int id = blockIdx.x*256 + threadIdx.x;
  if (id >= BATCH*NPTS) return;
  int b = id >> 13, n = id & (NPTS-1);
  float x = xyz[(b*3+0)*NPTS + n];
  float y = xyz[(b*3+1)*NPTS + n];
  float z = xyz[(b*3+2)*NPTS + n];
  float sq;
  {
    #pragma clang fp contract(off)
    sq = (x*x + y*y) + z*z;
  }
  pts[id] = make_float4(x, y, z, sq);
}

// ---------------- K2: projections, mat-split grid, 32-pt tiles ----------------
#define K2PTS 32
__global__ __launch_bounds__(256) void k2_proj(
    const float* x, const float* wq, const float* wk, const float* wv,
    const float* bnq_g, const float* bnq_b, const float* bnq_m, const float* bnq_v,
    const float* bnk_g, const float* bnk_b, const float* bnk_m, const float* bnk_v,
    const float* we_w1,
    const float* we_g, const float* we_b, const float* we_m, const float* we_v,
    float* eqT, float* ekT, float* vfT){
  __shared__ __align__(16) float qk2[K2PTS][129];  // [point][channel], 16.5 KB
  __shared__ float bnS[128], bnB[128];
  int t = threadIdx.x;
  int mat = blockIdx.x % 3;
  int tmp = blockIdx.x / 3;
  int b   = tmp / (NPTS/K2PTS);
  int n0  = (tmp % (NPTS/K2PTS)) * K2PTS;
  int p = t & 31, og = t >> 5;          // og in 0..7, 16 output channels each
  const float* xp = x + (size_t)b*CH*NPTS + n0 + p;
  const float* W = (mat == 0) ? wq : ((mat == 1) ? wk : wv);
  if (mat < 2 && t < 128){
    const float* g_ = mat==0 ? bnq_g : bnk_g;
    const float* b_ = mat==0 ? bnq_b : bnk_b;
    const float* m_ = mat==0 ? bnq_m : bnk_m;
    const float* v_ = mat==0 ? bnq_v : bnk_v;
    float s = g_[t] / sqrtf(v_[t] + EPSN);
    bnS[t] = s;
    bnB[t] = b_[t] - m_[t] * s;
  }
  __syncthreads();
  float acc[16];
  #pragma unroll
  for (int ii = 0; ii < 16; ++ii) acc[ii] = 0.f;
  for (int dd = 0; dd < 32; ++dd){
    float x0 = xp[(size_t)(4*dd+0)*NPTS];
    float x1 = xp[(size_t)(4*dd+1)*NPTS];
    float x2 = xp[(size_t)(4*dd+2)*NPTS];
    float x3 = xp[(size_t)(4*dd+3)*NPTS];
    #pragma unroll
    for (int ii = 0; ii < 16; ++ii){
      int o = og*16 + ii;
      float4 wu = *(const float4*)&W[o*128 + 4*dd];
      acc[ii] = fmaf(wu.x, x0, acc[ii]);
      acc[ii] = fmaf(wu.y, x1, acc[ii]);
      acc[ii] = fmaf(wu.z, x2, acc[ii]);
      acc[ii] = fmaf(wu.w, x3, acc[ii]);
    }
  }
  #pragma unroll
  for (int ii = 0; ii < 16; ++ii){
    int o = og*16 + ii;
    float v = acc[ii];
    if (mat < 2) v = fmaxf(fmaf(bnS[o], v, bnB[o]), 0.f);
    qk2[p][o] = v;
  }
  __syncthreads();
  if (mat < 2){
    int g = t >> 5, pp = t & 31;
    float sg = we_g[g] / sqrtf(we_v[g] + EPSN);
    float tg = we_b[g] - we_m[g] * sg;
    float s = 0.f;
    for (int c4 = 0; c4 < 32; ++c4){
      float4 wv4 = *(const float4*)&we_w1[g*128 + 4*c4];
      float4 qv4 = *(const float4*)&qk2[pp][4*c4];
      s = fmaf(wv4.x, qv4.x, s);
      s = fmaf(wv4.y, qv4.y, s);
      s = fmaf(wv4.z, qv4.z, s);
      s = fmaf(wv4.w, qv4.w, s);
    }
    float val = (mat == 0) ? (tg - sg*s) : (sg*s);
    float* dst = (mat == 0) ? eqT : ekT;
    dst[(b*NPTS + n0 + pp)*8 + g] = val;
  } else {
    #pragma unroll
    for (int i = 0; i < 4; ++i){
      int f = t + 256*i;        // 0..1023 float4 units (32 pts x 32 float4)
      int pp = f >> 5, c4 = (f & 31)*4;
      float4 v = *(const float4*)&qk2[pp][c4];
      *(float4*)&vfT[((size_t)b*NPTS + n0 + pp)*CH + c4] = v;
    }
  }
}

// ---------------- K3: exact KNN, prefetched collect, interleaved reductions ----------------
// Same algorithm as the verified round-12 kernel (lane-min sampled T with
// guaranteed cnt>=16, ballot compaction, bisect-on-overflow, 16-min pops).
// Scheduling changes only: (a) next chunk's 4 loads prefetched before current
// chunk's branchy compute (L2 latency off critical path); (b) the two queries'
// shfl-reduction chains interleaved in sample + extraction phases (2x ILP).
#define QW   2     // queries per wave
#define QPB  8     // queries per block (4 waves x 2)
#define CAPQ 288   // candidate slots per query
__global__ __launch_bounds__(256) void k3_knn(const float4* pts, int* idxout){
  __shared__ u64 smBuf[4][QW][CAPQ];   // 18 KB, rows private per wave
  int t = threadIdx.x;
  int wv = t >> 6, lane = t & 63;
  int b  = blockIdx.x / (NPTS/QPB);
  int q0 = (blockIdx.x % (NPTS/QPB)) * QPB + wv*QW;
  const float4* P = pts + b*NPTS;

  // clear wave-private rows (give-up-path safety); QW*CAPQ/64 = 9 slots/lane
  #pragma unroll
  for (int s = 0; s < QW*CAPQ/64; ++s){
    int f = s*64 + lane;
    smBuf[wv][f / CAPQ][f % CAPQ] = ~0ull;
  }

  float4 qp[QW];
  #pragma unroll
  for (int i = 0; i < QW; ++i) qp[i] = P[q0 + i];

  // ---- sample phase: shared load stream, interleaved pop chains ----
  float T[QW];
  {
    float v0 = 3.402823466e38f, v1 = 3.402823466e38f;
    #pragma unroll
    for (int j = 0; j < 16; ++j){
      float4 c = P[lane + 64*j];
      v0 = fminf(v0, d2f(qp[0], c));
      v1 = fminf(v1, d2f(qp[1], c));
    }
    float t0 = v0, t1 = v1;
    #pragma unroll
    for (int r = 0; r < 16; ++r){
      float m0 = v0, m1 = v1;
      #pragma unroll
      for (int msk = 1; msk <= 32; msk <<= 1){
        m0 = fminf(m0, __shfl_xor(m0, msk));
        m1 = fminf(m1, __shfl_xor(m1, msk));
      }
      if (v0 == m0) v0 = 3.402823466e38f;  // pop (bias up = safe)
      if (v1 == m1) v1 = 3.402823466e38f;
      t0 = m0; t1 = m1;
    }
    T[0] = t0; T[1] = t1;
  }

  // ---- collect sweeps: prefetched chunks; cnt>=16 guaranteed; bisect on overflow ----
  float Tlo[QW], Thi[QW]; int cnt[QW];
  #pragma unroll
  for (int i = 0; i < QW; ++i){ Tlo[i] = -3.0e38f; Thi[i] = 3.0e38f; cnt[i] = 0; }
  auto step = [&](float4 c, u32 m, int i){
    float d2 = d2f(qp[i], c);
    bool pred = d2 <= T[i];
    u64 bm = __ballot(pred);
    if (bm){                              // wave-uniform skip of empty groups
      int cc = __popcll(bm);
      if (pred && cnt[i] + cc <= CAPQ){
        int pos = cnt[i] + mbcnt64(bm);
        smBuf[wv][i][pos] = (((u64)mono32(d2)) << 32) | m;
      }
      cnt[i] += cc;
    }
  };
  bool anybad = true;
  for (int att = 0; att < 16 && anybad; ++att){
    #pragma unroll
    for (int i = 0; i < QW; ++i) cnt[i] = 0;
    float4 c0 = P[lane], c1 = P[64 + lane], c2 = P[128 + lane], c3 = P[192 + lane];
    for (int base = 0; base < NPTS; base += 256){
      float4 e0 = c0, e1 = c1, e2 = c2, e3 = c3;
      int nb = base + 256;
      if (nb < NPTS){                     // prefetch next chunk over this one's compute
        c0 = P[nb       + lane];
        c1 = P[nb +  64 + lane];
        c2 = P[nb + 128 + lane];
        c3 = P[nb + 192 + lane];
      }
      #pragma unroll
      for (int i = 0; i < QW; ++i){
        step(e0, (u32)(base       + lane), i);
        step(e1, (u32)(base +  64 + lane), i);
        step(e2, (u32)(base + 128 + lane), i);
        step(e3, (u32)(base + 192 + lane), i);
      }
    }
    anybad = false;
    #pragma unroll
    for (int i = 0; i < QW; ++i){
      if (cnt[i] > CAPQ){
        Thi[i] = T[i];
        T[i] = (Tlo[i] > -3.0e38f) ? 0.5f*(Tlo[i] + Thi[i])
                                   : ((T[i] > 0.f) ? T[i]*0.5f : T[i]*2.0f - 1.0f);
        anybad = true;
      } else if (cnt[i] < 16){   // only reachable after an overflow-shrink
        Tlo[i] = T[i];
        T[i] = 0.5f*(Tlo[i] + Thi[i]);
        anybad = true;
      }
    }
  }

  // ---- extraction: register-resident, both queries' pop chains interleaved ----
  {
    int cq0 = cnt[0] < CAPQ ? cnt[0] : CAPQ;
    int cq1 = cnt[1] < CAPQ ? cnt[1] : CAPQ;
    u64 a0, a1, a2, a3, a4, b0, b1, b2, b3, b4;
    a0 = (lane       < cq0) ? smBuf[wv][0][lane      ] : ~0ull;
    a1 = (lane +  64 < cq0) ? smBuf[wv][0][lane +  64] : ~0ull;
    a2 = (lane + 128 < cq0) ? smBuf[wv][0][lane + 128] : ~0ull;
    a3 = (lane + 192 < cq0) ? smBuf[wv][0][lane + 192] : ~0ull;
    a4 = (lane + 256 < cq0) ? smBuf[wv][0][lane + 256] : ~0ull;
    b0 = (lane       < cq1) ? smBuf[wv][1][lane      ] : ~0ull;
    b1 = (lane +  64 < cq1) ? smBuf[wv][1][lane +  64] : ~0ull;
    b2 = (lane + 128 < cq1) ? smBuf[wv][1][lane + 128] : ~0ull;
    b3 = (lane + 192 < cq1) ? smBuf[wv][1][lane + 192] : ~0ull;
    b4 = (lane + 256 < cq1) ? smBuf[wv][1][lane + 256] : ~0ull;
    #define CE_(x,y) { if (y < x){ u64 tm_ = x; x = y; y = tm_; } }
    CE_(a0,a1) CE_(a1,a2) CE_(a2,a3) CE_(a3,a4)
    CE_(a0,a1) CE_(a1,a2) CE_(a2,a3)
    CE_(a0,a1) CE_(a1,a2)
    CE_(a0,a1)
    CE_(b0,b1) CE_(b1,b2) CE_(b2,b3) CE_(b3,b4)
    CE_(b0,b1) CE_(b1,b2) CE_(b2,b3)
    CE_(b0,b1) CE_(b1,b2)
    CE_(b0,b1)
    #undef CE_
    int nq0 = q0, nq1 = q0 + 1;
    #pragma unroll
    for (int r = 0; r < 16; ++r){
      u64 g0 = a0, g1 = b0;
      #pragma unroll
      for (int msk = 1; msk <= 32; msk <<= 1){
        u64 o0 = shfl_xor_u64(g0, msk);
        u64 o1 = shfl_xor_u64(g1, msk);
        g0 = (o0 < g0) ? o0 : g0;
        g1 = (o1 < g1) ? o1 : g1;
      }
      if (a0 == g0){ a0 = a1; a1 = a2; a2 = a3; a3 = a4; a4 = ~0ull; }
      if (b0 == g1){ b0 = b1; b1 = b2; b2 = b3; b3 = b4; b4 = ~0ull; }
      if (lane == 0){
        idxout[(b*NPTS + nq0)*16 + r] = (g0 == ~0ull) ? nq0 : (int)(g0 & (u32)(NPTS-1));
        idxout[(b*NPTS + nq1)*16 + r] = (g1 == ~0ull) ? nq1 : (int)(g1 & (u32)(NPTS-1));
      }
    }
  }
}

// ---------------- K4: fused attention, 1 wave/point, low-LDS ----------------
// __launch_bounds__(256,4): cap VGPR at 128 so occupancy isn't register-bound.
#define H2S 136
__global__ __launch_bounds__(256, 4) void k4_attn(
    const float4* pts, const float* eqT, const float* ekT, const int* idxw,
    const float* vfT, const float* wsA, const float4* wsPW1, const float* wsWE2,
    const float* pe_w2, const float* wo,
    const float* bno_g, const float* bno_b, const float* bno_m, const float* bno_v,
    float* out){
  __shared__ __align__(16) float4 smW1[128];      // 2 KB
  __shared__ __align__(16) float4 smP[4][16];     // 1 KB  r-vectors per wave
  __shared__ int   smJ[4][16];                    // 256 B neighbor indices
  __shared__ float smw[4][16][8];                 // 2 KB  weights [k][g]
  __shared__ __align__(16) float smH[4][8][H2S];  // 17.4 KB
  __shared__ __align__(16) float smOutv[4][128];  // 2 KB
  int t = threadIdx.x;
  int wv = t >> 6, lane = t & 63;
  int b  = blockIdx.x >> 11;          // NPTS/4 = 2048 blocks per batch
  int n0 = (blockIdx.x & 2047) * 4;
  if (t < 128) smW1[t] = wsPW1[t];
  __syncthreads();

  int n = n0 + wv;
  int gq = b*NPTS + n;
  int k = lane >> 2, q = lane & 3;

  // ---- phase A (wave-local): logits + softmax weights ----
  {
    float4 pn  = pts[gq];
    float4 eqa = *(const float4*)&eqT[gq*8];
    float4 eqb = *(const float4*)&eqT[gq*8+4];
    int j = idxw[gq*16 + k] & (NPTS-1);
    int gj = b*NPTS + j;
    float4 pj  = pts[gj];
    float4 eka = *(const float4*)&ekT[gj*8];
    float4 ekb = *(const float4*)&ekT[gj*8+4];
    float rx = pj.x - pn.x, ry = pj.y - pn.y, rz = pj.z - pn.z;
    if (q == 0){
      smP[wv][k] = make_float4(rx, ry, rz, 0.f);
      smJ[wv][k] = j;
    }
    // ee added ONCE after the q-lane reduction
    float ee[8] = {eka.x+eqa.x, eka.y+eqa.y, eka.z+eqa.z, eka.w+eqa.w,
                   ekb.x+eqb.x, ekb.y+eqb.y, ekb.z+eqb.z, ekb.w+eqb.w};
    float lp[8] = {0.f,0.f,0.f,0.f,0.f,0.f,0.f,0.f};
    #pragma unroll
    for (int i = 0; i < 8; ++i){
      int hb = 4*q + 16*i;
      float4 w1;
      w1 = smW1[hb+0]; float hv0 = fmaxf(fmaf(w1.x, rx, fmaf(w1.y, ry, fmaf(w1.z, rz, w1.w))), 0.f);
      w1 = smW1[hb+1]; float hv1 = fmaxf(fmaf(w1.x, rx, fmaf(w1.y, ry, fmaf(w1.z, rz, w1.w))), 0.f);
      w1 = smW1[hb+2]; float hv2 = fmaxf(fmaf(w1.x, rx, fmaf(w1.y, ry, fmaf(w1.z, rz, w1.w))), 0.f);
      w1 = smW1[hb+3]; float hv3 = fmaxf(fmaf(w1.x, rx, fmaf(w1.y, ry, fmaf(w1.z, rz, w1.w))), 0.f);
      #pragma unroll
      for (int g = 0; g < 8; ++g){
        float4 a4 = *(const float4*)&wsA[g*128 + hb];
        lp[g] = fmaf(a4.x, hv0, lp[g]);
        lp[g] = fmaf(a4.y, hv1, lp[g]);
        lp[g] = fmaf(a4.z, hv2, lp[g]);
        lp[g] = fmaf(a4.w, hv3, lp[g]);
      }
    }
    #pragma unroll
    for (int g = 0; g < 8; ++g){
      lp[g] += __shfl_xor(lp[g], 1);
      lp[g] += __shfl_xor(lp[g], 2);
      lp[g] = fmaxf(lp[g] + ee[g], 0.f);
    }
    float lo0 = 0.f, lo1 = 0.f;
    #pragma unroll
    for (int g = 0; g < 8; ++g){
      lo0 = fmaf(wsWE2[(2*q+0)*8 + g], lp[g], lo0);
      lo1 = fmaf(wsWE2[(2*q+1)*8 + g], lp[g], lo1);
    }
    float m0 = lo0, m1 = lo1;
    #pragma unroll
    for (int msk = 4; msk <= 32; msk <<= 1){
      m0 = fmaxf(m0, __shfl_xor(m0, msk));
      m1 = fmaxf(m1, __shfl_xor(m1, msk));
    }
    float e0 = __expf(lo0 - m0), e1 = __expf(lo1 - m1);
    float s0 = e0, s1 = e1;
    #pragma unroll
    for (int msk = 4; msk <= 32; msk <<= 1){
      s0 += __shfl_xor(s0, msk);
      s1 += __shfl_xor(s1, msk);
    }
    smw[wv][k][2*q+0] = e0 / s0;
    smw[wv][k][2*q+1] = e1 / s1;
  }

  // ---- phase C (wave-local): H[g][h] = sum_k w[g,k]*relu(W1[h].r_k) ----
  {
    int g3 = lane >> 3, hh = lane & 7;
    float4 H4[4];
    #pragma unroll
    for (int ii = 0; ii < 4; ++ii) H4[ii] = make_float4(0.f,0.f,0.f,0.f);
    for (int kk = 0; kk < 16; ++kk){
      float4 r4 = smP[wv][kk];
      float wg  = smw[wv][kk][g3];
      #pragma unroll
      for (int ii = 0; ii < 4; ++ii){
        int hb = 4*hh + 32*ii;
        float4 w1;
        w1 = smW1[hb+0]; float hv0 = fmaxf(fmaf(w1.x, r4.x, fmaf(w1.y, r4.y, fmaf(w1.z, r4.z, w1.w))), 0.f);
        w1 = smW1[hb+1]; float hv1 = fmaxf(fmaf(w1.x, r4.x, fmaf(w1.y, r4.y, fmaf(w1.z, r4.z, w1.w))), 0.f);
        w1 = smW1[hb+2]; float hv2 = fmaxf(fmaf(w1.x, r4.x, fmaf(w1.y, r4.y, fmaf(w1.z, r4.z, w1.w))), 0.f);
        w1 = smW1[hb+3]; float hv3 = fmaxf(fmaf(w1.x, r4.x, fmaf(w1.y, r4.y, fmaf(w1.z, r4.z, w1.w))), 0.f);
        H4[ii].x = fmaf(wg, hv0, H4[ii].x);
        H4[ii].y = fmaf(wg, hv1, H4[ii].y);
        H4[ii].z = fmaf(wg, hv2, H4[ii].z);
        H4[ii].w = fmaf(wg, hv3, H4[ii].w);
      }
    }
    #pragma unroll
    for (int ii = 0; ii < 4; ++ii)
      *(float4*)&smH[wv][g3][4*hh + 32*ii] = H4[ii];
  }
  __syncthreads();   // all waves' smH/smw/smJ visible block-wide

  // ---- phase D (block-wide, t<128): outv for all 4 points; pe_w2 rows read once ----
  if (t < 128){
    int c = t, g = c >> 4;
    float acc[4] = {0.f, 0.f, 0.f, 0.f};
    for (int i = 0; i < 32; ++i){
      float4 pw = *(const float4*)&pe_w2[c*128 + 4*i];
      #pragma unroll
      for (int pt = 0; pt < 4; ++pt){
        float4 h4 = *(const float4*)&smH[pt][g][4*i];
        acc[pt] = fmaf(pw.x, h4.x, acc[pt]);
        acc[pt] = fmaf(pw.y, h4.y, acc[pt]);
        acc[pt] = fmaf(pw.z, h4.z, acc[pt]);
        acc[pt] = fmaf(pw.w, h4.w, acc[pt]);
      }
    }
    #pragma unroll
    for (int pt = 0; pt < 4; ++pt){
      #pragma unroll
      for (int kk = 0; kk < 16; ++kk){
        int jj = smJ[pt][kk];
        float wgk = smw[pt][kk][g];
        acc[pt] = fmaf(wgk, vfT[((size_t)b*NPTS + jj)*CH + c], acc[pt]);
      }
      smOutv[pt][c] = acc[pt];
    }
  }
  __syncthreads();

  // ---- phase E (t<128): out[o][n0..n0+3] = bno(wo @ outv), float4 store ----
  if (t < 128){
    int o = t;
    float so = bno_g[o] / sqrtf(bno_v[o] + EPSN);
    float bo = bno_b[o] - bno_m[o] * so;
    float fa[4] = {0.f, 0.f, 0.f, 0.f};
    for (int i = 0; i < 32; ++i){
      float4 pw = *(const float4*)&wo[o*128 + 4*i];
      #pragma unroll
      for (int pt = 0; pt < 4; ++pt){
        float4 h4 = *(const float4*)&smOutv[pt][4*i];
        fa[pt] = fmaf(pw.x, h4.x, fa[pt]);
        fa[pt] = fmaf(pw.y, h4.y, fa[pt]);
        fa[pt] = fmaf(pw.z, h4.z, fa[pt]);
        fa[pt] = fmaf(pw.w, h4.w, fa[pt]);
      }
    }
    float4 st;
    st.x = fmaf(so, fa[0], bo);
    st.y = fmaf(so, fa[1], bo);
    st.z = fmaf(so, fa[2], bo);
    st.w = fmaf(so, fa[3], bo);
    *(float4*)&out[((size_t)b*CH + o)*NPTS + n0] = st;
  }
}

extern "C" void kernel_launch(void* const* d_in, const int* in_sizes, int n_in,
                              void* d_out, int out_size, void* d_ws, size_t ws_size,
                              hipStream_t stream){
  const float* x     = (const float*)d_in[0];
  const float* xyz   = (const float*)d_in[1];
  const float* wq    = (const float*)d_in[2];
  const float* bnq_g = (const float*)d_in[3];
  const float* bnq_b = (const float*)d_in[4];
  const float* bnq_m = (const float*)d_in[5];
  const float* bnq_v = (const float*)d_in[6];
  const float* wk    = (const float*)d_in[7];
  const float* bnk_g = (const float*)d_in[8];
  const float* bnk_b = (const float*)d_in[9];
  const float* bnk_m = (const float*)d_in[10];
  const float* bnk_v = (const float*)d_in[11];
  const float* wv    = (const float*)d_in[12];
  const float* pe_w1 = (const float*)d_in[13];
  const float* pe_g  = (const float*)d_in[14];
  const float* pe_b  = (const float*)d_in[15];
  const float* pe_m  = (const float*)d_in[16];
  const float* pe_v  = (const float*)d_in[17];
  const float* pe_w2 = (const float*)d_in[18];
  const float* we_w1 = (const float*)d_in[19];
  const float* we_g  = (const float*)d_in[20];
  const float* we_b  = (const float*)d_in[21];
  const float* we_m  = (const float*)d_in[22];
  const float* we_v  = (const float*)d_in[23];
  const float* we_w2 = (const float*)d_in[24];
  const float* wo    = (const float*)d_in[25];
  const float* bno_g = (const float*)d_in[26];
  const float* bno_b = (const float*)d_in[27];
  const float* bno_m = (const float*)d_in[28];
  const float* bno_v = (const float*)d_in[29];

  char* ws = (char*)d_ws;
  float*  wsA   = (float*)(ws + WS_A);
  float4* wsPW1 = (float4*)(ws + WS_PW1);
  float*  wsWE2 = (float*)(ws + WS_WE2);
  float4* pts   = (float4*)(ws + WS_PTS);
  float*  eqT   = (float*)(ws + WS_EQ);
  float*  ekT   = (float*)(ws + WS_EK);
  int*    idxw  = (int*)(ws + WS_IDX);
  float*  vfT   = (float*)(ws + WS_VFT);
  float*  outp  = (float*)d_out;

  k0_precomp<<<dim3(1), dim3(256), 0, stream>>>(we_w1, pe_w2, pe_w1, we_g, we_v,
                                                pe_g, pe_b, pe_m, pe_v, we_w2,
                                                wsA, wsPW1, wsWE2);
  k1_pts<<<dim3(64), dim3(256), 0, stream>>>(xyz, pts);
  k2_proj<<<dim3(BATCH*(NPTS/K2PTS)*3), dim3(256), 0, stream>>>(x, wq, wk, wv,
                                               bnq_g, bnq_b, bnq_m, bnq_v,
                                               bnk_g, bnk_b, bnk_m, bnk_v,
                                               we_w1, we_g, we_b, we_m, we_v,
                                               eqT, ekT, vfT);
  k3_knn<<<dim3(BATCH*(NPTS/QPB)), dim3(256), 0, stream>>>(pts, idxw);
  k4_attn<<<dim3(BATCH*(NPTS/4)), dim3(256), 0, stream>>>(pts, eqT, ekT, idxw, vfT,
                                                wsA, wsPW1, wsWE2, pe_w2, wo,
                                                bno_g, bno_b, bno_m, bno_v, outp);
}